// Round 3
// baseline (1954.029 us; speedup 1.0000x reference)
//
#include <hip/hip_runtime.h>
#include <math.h>

#define BATCH 1024
#define LABEL 128
#define LATENT 512
#define NTOT 1152  // 1024 + 128

// ---------------- conv1 (1->32, 5x5 SAME) + relu + 2x2 maxpool ----------------
// in [N,1,28,28] -> out PADDED [N,32,18,20] (2 zero pad top/left, rows 20 floats
// for 16B alignment) so conv2 can read rows directly from global with no LDS.
__global__ __launch_bounds__(256) void conv1_pool(const float* __restrict__ image,
                                                  const float* __restrict__ limg,
                                                  const float* __restrict__ wt,
                                                  const float* __restrict__ bias,
                                                  float* __restrict__ outp) {
    const int n = blockIdx.x;
    const float* in = (n < BATCH) ? (image + (size_t)n * 784)
                                  : (limg + (size_t)(n - BATCH) * 784);
    __shared__ float pin[32][32];     // padded 28+2+2
    __shared__ float wts[32 * 25];
    const int tid = threadIdx.x;
    for (int idx = tid; idx < 32 * 32; idx += 256) ((float*)pin)[idx] = 0.f;
    __syncthreads();
    for (int idx = tid; idx < 784; idx += 256) {
        int y = idx / 28, x = idx % 28;
        pin[y + 2][x + 2] = in[idx];
    }
    for (int idx = tid; idx < 800; idx += 256) wts[idx] = wt[idx];
    float* ob = outp + (size_t)n * 32 * 360;
    for (int idx = tid; idx < 32 * 360; idx += 256) ob[idx] = 0.f;
    __syncthreads();
    for (int o = tid; o < 32 * 196; o += 256) {
        int oc = o / 196, p = o % 196, py = p / 14, px = p % 14;
        float b = bias[oc];
        float m = -1e30f;
        #pragma unroll
        for (int dy = 0; dy < 2; ++dy)
        #pragma unroll
        for (int dx = 0; dx < 2; ++dx) {
            int cy = 2 * py + dy, cx = 2 * px + dx;
            float acc = b;
            #pragma unroll
            for (int ky = 0; ky < 5; ++ky)
            #pragma unroll
            for (int kx = 0; kx < 5; ++kx)
                acc += pin[cy + ky][cx + kx] * wts[oc * 25 + ky * 5 + kx];
            m = fmaxf(m, acc);
        }
        ob[oc * 360 + (py + 2) * 20 + (px + 2)] = fmaxf(m, 0.f);
    }
}

// ---------------- weight re-layout for conv2: w2[ic][oc][28] ----------------
__global__ __launch_bounds__(256) void w2prep(const float* __restrict__ w,
                                              float* __restrict__ w2) {
    int idx = blockIdx.x * 256 + threadIdx.x;   // 32*64*28 = 57344
    if (idx >= 32 * 64 * 28) return;
    int k = idx % 28, t = idx / 28;
    int oc = t % 64, ic = t / 64;
    w2[idx] = (k < 25) ? w[oc * 800 + ic * 25 + k] : 0.f;
}

// ---------------- conv2 (32->64, 5x5 SAME) + relu + 2x2 maxpool ----------------
// lane = oc (64), wave = pool quadrant (dy,dx). Rows read as wave-uniform
// global broadcasts (L1-resident, 1 transaction/load); weights via aligned
// float4 loads from pre-transposed w2. No LDS staging -> 12.5KB LDS/block,
// ~4.5 blocks/CU residency. launch_bounds(256,4) = 128 VGPR headroom so
// acc[49]+row[20]+wk[28] live entirely in registers.
template<int DX>
__device__ __forceinline__ void conv_ic(const float* __restrict__ prow,
                                        const float* __restrict__ wk,
                                        float* __restrict__ acc) {
    #pragma unroll
    for (int yp = 0; yp < 17; ++yp) {
        float row[20];
        const float4* rp = (const float4*)(prow + yp * 20);
        #pragma unroll
        for (int v = 0; v < 5; ++v) {
            float4 t = rp[v];
            row[4 * v + 0] = t.x; row[4 * v + 1] = t.y;
            row[4 * v + 2] = t.z; row[4 * v + 3] = t.w;
        }
        #pragma unroll
        for (int ky = 0; ky < 5; ++ky) {
            const int rem = yp - ky;            // = 2*py; compile-time after unroll
            if (rem < 0 || rem > 12 || (rem & 1)) continue;
            const int py = rem >> 1;
            #pragma unroll
            for (int kx = 0; kx < 5; ++kx) {
                float w = wk[ky * 5 + kx];
                #pragma unroll
                for (int px = 0; px < 7; ++px)
                    acc[py * 7 + px] = fmaf(row[2 * px + DX + kx], w, acc[py * 7 + px]);
            }
        }
    }
}

__global__ __launch_bounds__(256, 4) void conv2_pool(const float* __restrict__ in,
                                                     const float* __restrict__ w2,
                                                     const float* __restrict__ bias,
                                                     float* __restrict__ out) {
    const int n = blockIdx.x;
    __shared__ float maxbuf[64 * 49];
    const int tid = threadIdx.x;
    const int lane = tid & 63, q = tid >> 6;
    const int oc = lane, dy = q >> 1, dx = q & 1;
    float acc[49];
    {
        float b = bias[oc];
        #pragma unroll
        for (int p = 0; p < 49; ++p) acc[p] = b;
    }
    const float* base = in + (size_t)n * 32 * 360 + dy * 20;
    for (int ic = 0; ic < 32; ++ic) {
        float wk[28];
        const float4* wp = (const float4*)(w2 + ((size_t)ic * 64 + oc) * 28);
        #pragma unroll
        for (int v = 0; v < 7; ++v) {
            float4 t = wp[v];
            wk[4 * v + 0] = t.x; wk[4 * v + 1] = t.y;
            wk[4 * v + 2] = t.z; wk[4 * v + 3] = t.w;
        }
        const float* prow = base + ic * 360;
        if (dx == 0) conv_ic<0>(prow, wk, acc);
        else         conv_ic<1>(prow, wk, acc);
    }
    __syncthreads();
    for (int qq = 0; qq < 4; ++qq) {
        if (q == qq) {
            if (qq == 0) {
                #pragma unroll
                for (int p = 0; p < 49; ++p) maxbuf[oc * 49 + p] = acc[p];
            } else {
                #pragma unroll
                for (int p = 0; p < 49; ++p)
                    maxbuf[oc * 49 + p] = fmaxf(maxbuf[oc * 49 + p], acc[p]);
            }
        }
        __syncthreads();
    }
    for (int idx = tid; idx < 3136; idx += 256)
        out[(size_t)n * 3136 + idx] = fmaxf(maxbuf[idx], 0.f);
}

// ---------------- fc1 GEMM: [1152,3136] @ [512,3136]^T + b ----------------
// rows < 1024 -> lat ; rows >= 1024 -> rep = tanh(...)
__global__ __launch_bounds__(256) void fc1_gemm(const float* __restrict__ A,
                                                const float* __restrict__ B,
                                                const float* __restrict__ bias,
                                                float* __restrict__ lat,
                                                float* __restrict__ rep) {
    __shared__ float As[16][68];
    __shared__ float Bs[16][68];
    const int tid = threadIdx.x;
    const int n0 = blockIdx.x * 64, m0 = blockIdx.y * 64;
    const int lr = tid >> 2;           // 0..63
    const int lk = (tid & 3) * 4;      // 0,4,8,12
    const int ty = tid >> 4, tx = tid & 15;
    float c[4][4] = {};
    for (int k0 = 0; k0 < 3136; k0 += 16) {
        float4 a4 = *(const float4*)(A + (size_t)(n0 + lr) * 3136 + k0 + lk);
        float4 b4 = *(const float4*)(B + (size_t)(m0 + lr) * 3136 + k0 + lk);
        __syncthreads();
        As[lk + 0][lr] = a4.x; As[lk + 1][lr] = a4.y; As[lk + 2][lr] = a4.z; As[lk + 3][lr] = a4.w;
        Bs[lk + 0][lr] = b4.x; Bs[lk + 1][lr] = b4.y; Bs[lk + 2][lr] = b4.z; Bs[lk + 3][lr] = b4.w;
        __syncthreads();
        #pragma unroll
        for (int kk = 0; kk < 16; ++kk) {
            float av[4], bv[4];
            #pragma unroll
            for (int i = 0; i < 4; ++i) av[i] = As[kk][ty * 4 + i];
            #pragma unroll
            for (int j = 0; j < 4; ++j) bv[j] = Bs[kk][tx * 4 + j];
            #pragma unroll
            for (int i = 0; i < 4; ++i)
            #pragma unroll
            for (int j = 0; j < 4; ++j) c[i][j] += av[i] * bv[j];
        }
    }
    #pragma unroll
    for (int i = 0; i < 4; ++i)
    #pragma unroll
    for (int j = 0; j < 4; ++j) {
        int n = n0 + ty * 4 + i, m = m0 + tx * 4 + j;
        float v = c[i][j] + bias[m];
        if (n < 1024) lat[n * 512 + m] = v;
        else rep[(n - 1024) * 512 + m] = tanhf(v);
    }
}

// ---------------- label = softmax(lat @ fcn_w.T + fcn_b) ----------------
__global__ __launch_bounds__(128) void fcn_softmax(const float* __restrict__ lat,
                                                   const float* __restrict__ fw,
                                                   const float* __restrict__ fb,
                                                   float* __restrict__ out) {
    const int b = blockIdx.x;
    const int j = threadIdx.x;   // 0..127
    __shared__ float lrow[512];
    __shared__ float red[128];
    for (int i = j; i < 512; i += 128) lrow[i] = lat[b * 512 + i];
    __syncthreads();
    const float4* w4 = (const float4*)(fw + j * 512);
    float acc = fb[j];
    #pragma unroll 4
    for (int q = 0; q < 128; ++q) {
        float4 a = ((const float4*)lrow)[q];
        float4 w = w4[q];
        acc += a.x * w.x + a.y * w.y + a.z * w.z + a.w * w.w;
    }
    red[j] = acc;
    __syncthreads();
    for (int off = 64; off >= 1; off >>= 1) {
        if (j < off) red[j] = fmaxf(red[j], red[j + off]);
        __syncthreads();
    }
    float mx = red[0];
    __syncthreads();
    float ex = expf(acc - mx);
    red[j] = ex;
    __syncthreads();
    for (int off = 64; off >= 1; off >>= 1) {
        if (j < off) red[j] += red[j + off];
        __syncthreads();
    }
    out[b * 128 + j] = ex / red[0];
}

// ---------------- rho = mean(rep) ----------------
__global__ __launch_bounds__(256) void rho_kernel(const float* __restrict__ rep,
                                                  float* __restrict__ rho) {
    __shared__ float red[256];
    const int tid = threadIdx.x;
    float s = 0.f;
    for (int i = tid; i < LABEL * LATENT; i += 256) s += rep[i];
    red[tid] = s;
    __syncthreads();
    for (int off = 128; off >= 1; off >>= 1) {
        if (tid < off) red[tid] += red[tid + off];
        __syncthreads();
    }
    if (tid == 0) rho[0] = red[0] / (float)(LABEL * LATENT);
}

// ---------------- tT[i][k] = rep[k][i] - rho ----------------
__global__ __launch_bounds__(256) void t_kernel(const float* __restrict__ rep,
                                                const float* __restrict__ rho,
                                                float* __restrict__ tT) {
    int idx = blockIdx.x * 256 + threadIdx.x;   // 65536 total
    int i = idx / 128, k = idx % 128;
    tT[idx] = rep[k * 512 + i] - rho[0];
}

// ---------------- w[i][j] = dot(tT_i, tT_j)/128, zero diag ----------------
__global__ __launch_bounds__(256) void w_kernel(const float* __restrict__ tT,
                                                float* __restrict__ w) {
    int idx = blockIdx.x * 256 + threadIdx.x;   // 262144 total
    int i = idx >> 9, j = idx & 511;
    const float4* a = (const float4*)(tT + i * 128);
    const float4* b = (const float4*)(tT + j * 128);
    float acc = 0.f;
    #pragma unroll 8
    for (int q = 0; q < 32; ++q) {
        float4 av = a[q], bv = b[q];
        acc += av.x * bv.x + av.y * bv.y + av.z * bv.z + av.w * bv.w;
    }
    w[idx] = (i == j) ? 0.f : acc * (1.f / 128.f);
}

// ---------------- clustering + fused out = softmax(|min_s @ rep.T|) ----------------
// One block handles CB batch rows. 256 threads; thread owns columns 2*tid, 2*tid+1.
// w is exactly symmetric, so the energy matvec of iter k is the update matvec of
// iter k+1 -> one matvec per iteration. Synchronous Hopfield with symmetric W
// has period <= 2 (Goles), so stopping when s_k == s_{k-1} (fixed point) or
// s_k == s_{k-2} (2-cycle) is exactly equivalent to running all 512 iterations.
#define CB 4
__device__ __forceinline__ float sgnf(float x) {
    return (x > 0.f) ? 1.f : ((x < 0.f) ? -1.f : 0.f);
}

__global__ __launch_bounds__(256) void clustering(const float* __restrict__ lat,
                                                  const float* __restrict__ w,
                                                  const float* __restrict__ rep,
                                                  float* __restrict__ out) {
    const int tid = threadIdx.x;
    const int row0 = blockIdx.x * CB;
    __shared__ float buf[3][CB][512];
    __shared__ float mins[CB][512];
    __shared__ float red[256];
    __shared__ float part_e[4][CB];
    __shared__ int part_f[4];
    __shared__ float min_e[CB];
    __shared__ int copyf[CB];
    __shared__ int donef[CB];
    const int i0 = 2 * tid, i1 = 2 * tid + 1;
    const int wave = tid >> 6, lane = tid & 63;

    #pragma unroll
    for (int r = 0; r < CB; ++r) {
        buf[0][r][i0] = tanhf(lat[(row0 + r) * 512 + i0]);
        buf[0][r][i1] = tanhf(lat[(row0 + r) * 512 + i1]);
    }
    if (tid < CB) { min_e[tid] = INFINITY; donef[tid] = 0; }
    __syncthreads();

    // h_0 = s_0 @ w
    float h0[CB], h1[CB];
    #pragma unroll
    for (int r = 0; r < CB; ++r) { h0[r] = 0.f; h1[r] = 0.f; }
    #pragma unroll 4
    for (int j = 0; j < 512; ++j) {
        float2 wv = *(const float2*)(w + (size_t)j * 512 + i0);
        #pragma unroll
        for (int r = 0; r < CB; ++r) {
            float sj = buf[0][r][j];
            h0[r] += sj * wv.x;
            h1[r] += sj * wv.y;
        }
    }

    for (int k = 1; k <= 512; ++k) {
        const int nw = k % 3, pv = (k + 2) % 3, pp = (k + 1) % 3;
        float sn0[CB], sn1[CB];
        int eqbits = 0xFF;
        #pragma unroll
        for (int r = 0; r < CB; ++r) {
            float p0 = buf[pv][r][i0], p1 = buf[pv][r][i1];
            float q0 = buf[pp][r][i0], q1 = buf[pp][r][i1];
            sn0[r] = fabsf(p0) * sgnf(h0[r]);
            sn1[r] = fabsf(p1) * sgnf(h1[r]);
            if (!(sn0[r] == p0 && sn1[r] == p1)) eqbits &= ~(1 << r);
            if (!(sn0[r] == q0 && sn1[r] == q1)) eqbits &= ~(1 << (4 + r));
            buf[nw][r][i0] = sn0[r];
            buf[nw][r][i1] = sn1[r];
        }
        __syncthreads();
        // h_k = s_k @ w   (doubles as energy matvec)
        #pragma unroll
        for (int r = 0; r < CB; ++r) { h0[r] = 0.f; h1[r] = 0.f; }
        #pragma unroll 4
        for (int j = 0; j < 512; ++j) {
            float2 wv = *(const float2*)(w + (size_t)j * 512 + i0);
            #pragma unroll
            for (int r = 0; r < CB; ++r) {
                float sj = buf[nw][r][j];
                h0[r] += sj * wv.x;
                h1[r] += sj * wv.y;
            }
        }
        float ep[CB];
        #pragma unroll
        for (int r = 0; r < CB; ++r) ep[r] = sn0[r] * h0[r] + sn1[r] * h1[r];
        // butterfly reduce within wave (sum e, and flags)
        #pragma unroll
        for (int m = 32; m >= 1; m >>= 1) {
            #pragma unroll
            for (int r = 0; r < CB; ++r) ep[r] += __shfl_xor(ep[r], m, 64);
            eqbits &= __shfl_xor(eqbits, m, 64);
        }
        if (lane == 0) {
            #pragma unroll
            for (int r = 0; r < CB; ++r) part_e[wave][r] = ep[r];
            part_f[wave] = eqbits;
        }
        __syncthreads();
        if (tid < CB) {
            int r = tid;
            float e = -(part_e[0][r] + part_e[1][r] + part_e[2][r] + part_e[3][r]);
            int fl = part_f[0] & part_f[1] & part_f[2] & part_f[3];
            int better = e < min_e[r];
            if (better) min_e[r] = e;
            copyf[r] = better;
            int fixedp = (fl >> r) & 1;
            int cyc = (k >= 2) && ((fl >> (4 + r)) & 1);
            if (fixedp || cyc) donef[r] = 1;
        }
        __syncthreads();
        int alldone = 1;
        #pragma unroll
        for (int r = 0; r < CB; ++r) {
            if (copyf[r]) { mins[r][i0] = sn0[r]; mins[r][i1] = sn1[r]; }
            alldone &= donef[r];
        }
        if (alldone) break;
    }
    __syncthreads();

    // out[row] = softmax_j(|sum_i mins[i] * rep[j][i]|)
    const int j = tid & 127, half = tid >> 7;
    for (int r = 0; r < CB; ++r) {
        const float4* rr = (const float4*)(rep + (size_t)j * 512 + half * 256);
        const float4* ms = (const float4*)(&mins[r][half * 256]);
        float p = 0.f;
        #pragma unroll 8
        for (int q = 0; q < 64; ++q) {
            float4 rv = rr[q], mv = ms[q];
            p += rv.x * mv.x + rv.y * mv.y + rv.z * mv.z + rv.w * mv.w;
        }
        red[tid] = p;
        __syncthreads();
        float v = 0.f;
        if (tid < 128) { v = fabsf(red[tid] + red[tid + 128]); red[tid] = v; }
        __syncthreads();
        for (int off = 64; off >= 1; off >>= 1) {
            if (tid < off) red[tid] = fmaxf(red[tid], red[tid + off]);
            __syncthreads();
        }
        float mx = red[0];
        __syncthreads();
        float ex = 0.f;
        if (tid < 128) { ex = expf(v - mx); red[tid] = ex; }
        __syncthreads();
        for (int off = 64; off >= 1; off >>= 1) {
            if (tid < off) red[tid] += red[tid + off];
            __syncthreads();
        }
        if (tid < 128) out[(size_t)(row0 + r) * 128 + tid] = ex / red[0];
        __syncthreads();
    }
}

extern "C" void kernel_launch(void* const* d_in, const int* in_sizes, int n_in,
                              void* d_out, int out_size, void* d_ws, size_t ws_size,
                              hipStream_t stream) {
    const float* image = (const float*)d_in[0];
    const float* limg  = (const float*)d_in[1];
    const float* c1w   = (const float*)d_in[2];
    const float* c1b   = (const float*)d_in[3];
    const float* c2w   = (const float*)d_in[4];
    const float* c2b   = (const float*)d_in[5];
    const float* f1w   = (const float*)d_in[6];
    const float* f1b   = (const float*)d_in[7];
    const float* fnw   = (const float*)d_in[8];
    const float* fnb   = (const float*)d_in[9];
    float* out = (float*)d_out;   // [1024*128 out][1024*128 label]
    float* ws  = (float*)d_ws;

    float* out1p = ws;                            // 1152*32*360 = 13,271,040
    float* out2  = out1p + (size_t)NTOT * 32 * 360; // 1152*3136
    float* lat   = out2 + (size_t)NTOT * 3136;    // 1024*512
    float* rep   = lat + (size_t)BATCH * 512;     // 128*512
    float* tT    = rep + (size_t)LABEL * 512;     // 512*128
    float* wmat  = tT + (size_t)512 * 128;        // 512*512
    float* rho   = wmat + (size_t)512 * 512;      // 1 (+pad)
    float* w2    = rho + 16;                      // 32*64*28 = 57344

    hipLaunchKernelGGL(w2prep, dim3(224), dim3(256), 0, stream, c2w, w2);
    hipLaunchKernelGGL(conv1_pool, dim3(NTOT), dim3(256), 0, stream, image, limg, c1w, c1b, out1p);
    hipLaunchKernelGGL(conv2_pool, dim3(NTOT), dim3(256), 0, stream, out1p, w2, c2b, out2);
    hipLaunchKernelGGL(fc1_gemm, dim3(NTOT / 64, 512 / 64), dim3(256), 0, stream,
                       out2, f1w, f1b, lat, rep);
    hipLaunchKernelGGL(fcn_softmax, dim3(BATCH), dim3(128), 0, stream, lat, fnw, fnb,
                       out + (size_t)BATCH * LABEL);
    hipLaunchKernelGGL(rho_kernel, dim3(1), dim3(256), 0, stream, rep, rho);
    hipLaunchKernelGGL(t_kernel, dim3(256), dim3(256), 0, stream, rep, rho, tT);
    hipLaunchKernelGGL(w_kernel, dim3(1024), dim3(256), 0, stream, tT, wmat);
    hipLaunchKernelGGL(clustering, dim3(BATCH / CB), dim3(256), 0, stream, lat, wmat, rep, out);
}

// Round 4
// 1091.074 us; speedup vs baseline: 1.7909x; 1.7909x over previous
//
#include <hip/hip_runtime.h>
#include <math.h>

#define BATCH 1024
#define LABEL 128
#define LATENT 512
#define NTOT 1152  // 1024 + 128

// ---------------- conv1 (1->32, 5x5 SAME) + relu + 2x2 maxpool ----------------
// in [N,1,28,28] -> out PADDED [N,32,18,20] (2 zero pad top/left, rows 20 floats
// for 16B alignment) so conv2 can read rows directly from global.
__global__ __launch_bounds__(256) void conv1_pool(const float* __restrict__ image,
                                                  const float* __restrict__ limg,
                                                  const float* __restrict__ wt,
                                                  const float* __restrict__ bias,
                                                  float* __restrict__ outp) {
    const int n = blockIdx.x;
    const float* in = (n < BATCH) ? (image + (size_t)n * 784)
                                  : (limg + (size_t)(n - BATCH) * 784);
    __shared__ float pin[32][32];     // padded 28+2+2
    __shared__ float wts[32 * 25];
    const int tid = threadIdx.x;
    for (int idx = tid; idx < 32 * 32; idx += 256) ((float*)pin)[idx] = 0.f;
    __syncthreads();
    for (int idx = tid; idx < 784; idx += 256) {
        int y = idx / 28, x = idx % 28;
        pin[y + 2][x + 2] = in[idx];
    }
    for (int idx = tid; idx < 800; idx += 256) wts[idx] = wt[idx];
    float* ob = outp + (size_t)n * 32 * 360;
    for (int idx = tid; idx < 32 * 360; idx += 256) ob[idx] = 0.f;
    __syncthreads();
    for (int o = tid; o < 32 * 196; o += 256) {
        int oc = o / 196, p = o % 196, py = p / 14, px = p % 14;
        float b = bias[oc];
        float m = -1e30f;
        #pragma unroll
        for (int dy = 0; dy < 2; ++dy)
        #pragma unroll
        for (int dx = 0; dx < 2; ++dx) {
            int cy = 2 * py + dy, cx = 2 * px + dx;
            float acc = b;
            #pragma unroll
            for (int ky = 0; ky < 5; ++ky)
            #pragma unroll
            for (int kx = 0; kx < 5; ++kx)
                acc += pin[cy + ky][cx + kx] * wts[oc * 25 + ky * 5 + kx];
            m = fmaxf(m, acc);
        }
        ob[oc * 360 + (py + 2) * 20 + (px + 2)] = fmaxf(m, 0.f);
    }
}

// ---------------- weight re-layout for conv2: w3[ic][ky][oc][8] ----------------
__global__ __launch_bounds__(256) void w3prep(const float* __restrict__ w,
                                              float* __restrict__ w3) {
    int idx = blockIdx.x * 256 + threadIdx.x;   // 32*5*64*8 = 81920
    if (idx >= 32 * 5 * 64 * 8) return;
    int r = idx & 7, t = idx >> 3;
    int oc = t & 63; t >>= 6;
    int ky = t % 5, ic = t / 5;
    w3[idx] = (r < 5) ? w[oc * 800 + ic * 25 + ky * 5 + r] : 0.f;
}

// ---------------- conv2 (32->64, 5x5 SAME) + relu + 2x2 maxpool ----------------
// lane = oc (64), wave = pool quadrant (dy,dx). Input rows read as wave-uniform
// global loads from the padded layout (L1-broadcast, no LDS staging). Loops
// restructured ky-outer so only wk[8] is live -> ~80 live floats, no spills.
// NO min-waves launch hint (round-3 lesson: it forces VGPR=64 + scratch spill).
template<int DX>
__device__ __forceinline__ void conv_ky(const float* __restrict__ plane,
                                        const float* __restrict__ wk,
                                        float* __restrict__ acc) {
    // plane points at input row (dy) of this ic; rows are 20 floats.
    #pragma unroll
    for (int py = 0; py < 7; ++py) {
        float row[20];
        const float4* rp = (const float4*)(plane + 2 * py * 20);
        #pragma unroll
        for (int v = 0; v < 5; ++v) {
            float4 t = rp[v];
            row[4 * v + 0] = t.x; row[4 * v + 1] = t.y;
            row[4 * v + 2] = t.z; row[4 * v + 3] = t.w;
        }
        #pragma unroll
        for (int kx = 0; kx < 5; ++kx) {
            float w = wk[kx];
            #pragma unroll
            for (int px = 0; px < 7; ++px)
                acc[py * 7 + px] = fmaf(row[2 * px + DX + kx], w, acc[py * 7 + px]);
        }
    }
}

template<int DX>
__device__ __forceinline__ void conv_all(const float* __restrict__ base,
                                         const float* __restrict__ w3,
                                         int oc, float* __restrict__ acc) {
    for (int ic = 0; ic < 32; ++ic) {
        const float* plane = base + ic * 360;
        #pragma unroll
        for (int ky = 0; ky < 5; ++ky) {
            float wk[8];
            const float4* wp = (const float4*)(w3 + (((size_t)ic * 5 + ky) * 64 + oc) * 8);
            float4 t0 = wp[0], t1 = wp[1];
            wk[0] = t0.x; wk[1] = t0.y; wk[2] = t0.z; wk[3] = t0.w;
            wk[4] = t1.x; wk[5] = t1.y; wk[6] = t1.z; wk[7] = t1.w;
            conv_ky<DX>(plane + ky * 20, wk, acc);
        }
    }
}

__global__ __launch_bounds__(256) void conv2_pool(const float* __restrict__ in,
                                                  const float* __restrict__ w3,
                                                  const float* __restrict__ bias,
                                                  float* __restrict__ out) {
    const int n = blockIdx.x;
    __shared__ float maxbuf[64 * 49];
    const int tid = threadIdx.x;
    const int lane = tid & 63, q = tid >> 6;
    const int oc = lane;
    // wave-uniform quadrant indices: make them provably uniform for the compiler
    const int dyu = __builtin_amdgcn_readfirstlane(q >> 1);
    const int dxu = __builtin_amdgcn_readfirstlane(q & 1);
    float acc[49];
    {
        float b = bias[oc];
        #pragma unroll
        for (int p = 0; p < 49; ++p) acc[p] = b;
    }
    const float* base = in + (size_t)n * 32 * 360 + dyu * 20;
    if (dxu == 0) conv_all<0>(base, w3, oc, acc);
    else          conv_all<1>(base, w3, oc, acc);
    __syncthreads();
    for (int qq = 0; qq < 4; ++qq) {
        if (q == qq) {
            if (qq == 0) {
                #pragma unroll
                for (int p = 0; p < 49; ++p) maxbuf[oc * 49 + p] = acc[p];
            } else {
                #pragma unroll
                for (int p = 0; p < 49; ++p)
                    maxbuf[oc * 49 + p] = fmaxf(maxbuf[oc * 49 + p], acc[p]);
            }
        }
        __syncthreads();
    }
    for (int idx = tid; idx < 3136; idx += 256)
        out[(size_t)n * 3136 + idx] = fmaxf(maxbuf[idx], 0.f);
}

// ---------------- fc1 GEMM: [1152,3136] @ [512,3136]^T + b ----------------
// rows < 1024 -> lat ; rows >= 1024 -> rep = tanh(...)
__global__ __launch_bounds__(256) void fc1_gemm(const float* __restrict__ A,
                                                const float* __restrict__ B,
                                                const float* __restrict__ bias,
                                                float* __restrict__ lat,
                                                float* __restrict__ rep) {
    __shared__ float As[16][68];
    __shared__ float Bs[16][68];
    const int tid = threadIdx.x;
    const int n0 = blockIdx.x * 64, m0 = blockIdx.y * 64;
    const int lr = tid >> 2;           // 0..63
    const int lk = (tid & 3) * 4;      // 0,4,8,12
    const int ty = tid >> 4, tx = tid & 15;
    float c[4][4] = {};
    for (int k0 = 0; k0 < 3136; k0 += 16) {
        float4 a4 = *(const float4*)(A + (size_t)(n0 + lr) * 3136 + k0 + lk);
        float4 b4 = *(const float4*)(B + (size_t)(m0 + lr) * 3136 + k0 + lk);
        __syncthreads();
        As[lk + 0][lr] = a4.x; As[lk + 1][lr] = a4.y; As[lk + 2][lr] = a4.z; As[lk + 3][lr] = a4.w;
        Bs[lk + 0][lr] = b4.x; Bs[lk + 1][lr] = b4.y; Bs[lk + 2][lr] = b4.z; Bs[lk + 3][lr] = b4.w;
        __syncthreads();
        #pragma unroll
        for (int kk = 0; kk < 16; ++kk) {
            float av[4], bv[4];
            #pragma unroll
            for (int i = 0; i < 4; ++i) av[i] = As[kk][ty * 4 + i];
            #pragma unroll
            for (int j = 0; j < 4; ++j) bv[j] = Bs[kk][tx * 4 + j];
            #pragma unroll
            for (int i = 0; i < 4; ++i)
            #pragma unroll
            for (int j = 0; j < 4; ++j) c[i][j] += av[i] * bv[j];
        }
    }
    #pragma unroll
    for (int i = 0; i < 4; ++i)
    #pragma unroll
    for (int j = 0; j < 4; ++j) {
        int n = n0 + ty * 4 + i, m = m0 + tx * 4 + j;
        float v = c[i][j] + bias[m];
        if (n < 1024) lat[n * 512 + m] = v;
        else rep[(n - 1024) * 512 + m] = tanhf(v);
    }
}

// ---------------- label = softmax(lat @ fcn_w.T + fcn_b) ----------------
__global__ __launch_bounds__(128) void fcn_softmax(const float* __restrict__ lat,
                                                   const float* __restrict__ fw,
                                                   const float* __restrict__ fb,
                                                   float* __restrict__ out) {
    const int b = blockIdx.x;
    const int j = threadIdx.x;   // 0..127
    __shared__ float lrow[512];
    __shared__ float red[128];
    for (int i = j; i < 512; i += 128) lrow[i] = lat[b * 512 + i];
    __syncthreads();
    const float4* w4 = (const float4*)(fw + j * 512);
    float acc = fb[j];
    #pragma unroll 4
    for (int q = 0; q < 128; ++q) {
        float4 a = ((const float4*)lrow)[q];
        float4 w = w4[q];
        acc += a.x * w.x + a.y * w.y + a.z * w.z + a.w * w.w;
    }
    red[j] = acc;
    __syncthreads();
    for (int off = 64; off >= 1; off >>= 1) {
        if (j < off) red[j] = fmaxf(red[j], red[j + off]);
        __syncthreads();
    }
    float mx = red[0];
    __syncthreads();
    float ex = expf(acc - mx);
    red[j] = ex;
    __syncthreads();
    for (int off = 64; off >= 1; off >>= 1) {
        if (j < off) red[j] += red[j + off];
        __syncthreads();
    }
    out[b * 128 + j] = ex / red[0];
}

// ---------------- rho = mean(rep) ----------------
__global__ __launch_bounds__(256) void rho_kernel(const float* __restrict__ rep,
                                                  float* __restrict__ rho) {
    __shared__ float red[256];
    const int tid = threadIdx.x;
    float s = 0.f;
    for (int i = tid; i < LABEL * LATENT; i += 256) s += rep[i];
    red[tid] = s;
    __syncthreads();
    for (int off = 128; off >= 1; off >>= 1) {
        if (tid < off) red[tid] += red[tid + off];
        __syncthreads();
    }
    if (tid == 0) rho[0] = red[0] / (float)(LABEL * LATENT);
}

// ---------------- tT[i][k] = rep[k][i] - rho ----------------
__global__ __launch_bounds__(256) void t_kernel(const float* __restrict__ rep,
                                                const float* __restrict__ rho,
                                                float* __restrict__ tT) {
    int idx = blockIdx.x * 256 + threadIdx.x;   // 65536 total
    int i = idx / 128, k = idx % 128;
    tT[idx] = rep[k * 512 + i] - rho[0];
}

// ---------------- w[i][j] = dot(tT_i, tT_j)/128, zero diag ----------------
__global__ __launch_bounds__(256) void w_kernel(const float* __restrict__ tT,
                                                float* __restrict__ w) {
    int idx = blockIdx.x * 256 + threadIdx.x;   // 262144 total
    int i = idx >> 9, j = idx & 511;
    const float4* a = (const float4*)(tT + i * 128);
    const float4* b = (const float4*)(tT + j * 128);
    float acc = 0.f;
    #pragma unroll 8
    for (int q = 0; q < 32; ++q) {
        float4 av = a[q], bv = b[q];
        acc += av.x * bv.x + av.y * bv.y + av.z * bv.z + av.w * bv.w;
    }
    w[idx] = (i == j) ? 0.f : acc * (1.f / 128.f);
}

// ---------------- clustering + fused out = softmax(|min_s @ rep.T|) ----------------
// One block handles CB batch rows. 256 threads; thread owns columns 2*tid, 2*tid+1.
// w is exactly symmetric, so the energy matvec of iter k is the update matvec of
// iter k+1 -> one matvec per iteration. Synchronous Hopfield with symmetric W
// has period <= 2 (Goles), so stopping when s_k == s_{k-1} (fixed point) or
// s_k == s_{k-2} (2-cycle) is exactly equivalent to running all 512 iterations.
#define CB 4
__device__ __forceinline__ float sgnf(float x) {
    return (x > 0.f) ? 1.f : ((x < 0.f) ? -1.f : 0.f);
}

__global__ __launch_bounds__(256) void clustering(const float* __restrict__ lat,
                                                  const float* __restrict__ w,
                                                  const float* __restrict__ rep,
                                                  float* __restrict__ out) {
    const int tid = threadIdx.x;
    const int row0 = blockIdx.x * CB;
    __shared__ float buf[3][CB][512];
    __shared__ float mins[CB][512];
    __shared__ float red[256];
    __shared__ float part_e[4][CB];
    __shared__ int part_f[4];
    __shared__ float min_e[CB];
    __shared__ int copyf[CB];
    __shared__ int donef[CB];
    const int i0 = 2 * tid, i1 = 2 * tid + 1;
    const int wave = tid >> 6, lane = tid & 63;

    #pragma unroll
    for (int r = 0; r < CB; ++r) {
        buf[0][r][i0] = tanhf(lat[(row0 + r) * 512 + i0]);
        buf[0][r][i1] = tanhf(lat[(row0 + r) * 512 + i1]);
    }
    if (tid < CB) { min_e[tid] = INFINITY; donef[tid] = 0; }
    __syncthreads();

    // h_0 = s_0 @ w
    float h0[CB], h1[CB];
    #pragma unroll
    for (int r = 0; r < CB; ++r) { h0[r] = 0.f; h1[r] = 0.f; }
    #pragma unroll 4
    for (int j = 0; j < 512; ++j) {
        float2 wv = *(const float2*)(w + (size_t)j * 512 + i0);
        #pragma unroll
        for (int r = 0; r < CB; ++r) {
            float sj = buf[0][r][j];
            h0[r] += sj * wv.x;
            h1[r] += sj * wv.y;
        }
    }

    for (int k = 1; k <= 512; ++k) {
        const int nw = k % 3, pv = (k + 2) % 3, pp = (k + 1) % 3;
        float sn0[CB], sn1[CB];
        int eqbits = 0xFF;
        #pragma unroll
        for (int r = 0; r < CB; ++r) {
            float p0 = buf[pv][r][i0], p1 = buf[pv][r][i1];
            float q0 = buf[pp][r][i0], q1 = buf[pp][r][i1];
            sn0[r] = fabsf(p0) * sgnf(h0[r]);
            sn1[r] = fabsf(p1) * sgnf(h1[r]);
            if (!(sn0[r] == p0 && sn1[r] == p1)) eqbits &= ~(1 << r);
            if (!(sn0[r] == q0 && sn1[r] == q1)) eqbits &= ~(1 << (4 + r));
            buf[nw][r][i0] = sn0[r];
            buf[nw][r][i1] = sn1[r];
        }
        __syncthreads();
        // h_k = s_k @ w   (doubles as energy matvec)
        #pragma unroll
        for (int r = 0; r < CB; ++r) { h0[r] = 0.f; h1[r] = 0.f; }
        #pragma unroll 4
        for (int j = 0; j < 512; ++j) {
            float2 wv = *(const float2*)(w + (size_t)j * 512 + i0);
            #pragma unroll
            for (int r = 0; r < CB; ++r) {
                float sj = buf[nw][r][j];
                h0[r] += sj * wv.x;
                h1[r] += sj * wv.y;
            }
        }
        float ep[CB];
        #pragma unroll
        for (int r = 0; r < CB; ++r) ep[r] = sn0[r] * h0[r] + sn1[r] * h1[r];
        // butterfly reduce within wave (sum e, and flags)
        #pragma unroll
        for (int m = 32; m >= 1; m >>= 1) {
            #pragma unroll
            for (int r = 0; r < CB; ++r) ep[r] += __shfl_xor(ep[r], m, 64);
            eqbits &= __shfl_xor(eqbits, m, 64);
        }
        if (lane == 0) {
            #pragma unroll
            for (int r = 0; r < CB; ++r) part_e[wave][r] = ep[r];
            part_f[wave] = eqbits;
        }
        __syncthreads();
        if (tid < CB) {
            int r = tid;
            float e = -(part_e[0][r] + part_e[1][r] + part_e[2][r] + part_e[3][r]);
            int fl = part_f[0] & part_f[1] & part_f[2] & part_f[3];
            int better = e < min_e[r];
            if (better) min_e[r] = e;
            copyf[r] = better;
            int fixedp = (fl >> r) & 1;
            int cyc = (k >= 2) && ((fl >> (4 + r)) & 1);
            if (fixedp || cyc) donef[r] = 1;
        }
        __syncthreads();
        int alldone = 1;
        #pragma unroll
        for (int r = 0; r < CB; ++r) {
            if (copyf[r]) { mins[r][i0] = sn0[r]; mins[r][i1] = sn1[r]; }
            alldone &= donef[r];
        }
        if (alldone) break;
    }
    __syncthreads();

    // out[row] = softmax_j(|sum_i mins[i] * rep[j][i]|)
    const int j = tid & 127, half = tid >> 7;
    for (int r = 0; r < CB; ++r) {
        const float4* rr = (const float4*)(rep + (size_t)j * 512 + half * 256);
        const float4* ms = (const float4*)(&mins[r][half * 256]);
        float p = 0.f;
        #pragma unroll 8
        for (int q = 0; q < 64; ++q) {
            float4 rv = rr[q], mv = ms[q];
            p += rv.x * mv.x + rv.y * mv.y + rv.z * mv.z + rv.w * mv.w;
        }
        red[tid] = p;
        __syncthreads();
        float v = 0.f;
        if (tid < 128) { v = fabsf(red[tid] + red[tid + 128]); red[tid] = v; }
        __syncthreads();
        for (int off = 64; off >= 1; off >>= 1) {
            if (tid < off) red[tid] = fmaxf(red[tid], red[tid + off]);
            __syncthreads();
        }
        float mx = red[0];
        __syncthreads();
        float ex = 0.f;
        if (tid < 128) { ex = expf(v - mx); red[tid] = ex; }
        __syncthreads();
        for (int off = 64; off >= 1; off >>= 1) {
            if (tid < off) red[tid] += red[tid + off];
            __syncthreads();
        }
        if (tid < 128) out[(size_t)(row0 + r) * 128 + tid] = ex / red[0];
        __syncthreads();
    }
}

extern "C" void kernel_launch(void* const* d_in, const int* in_sizes, int n_in,
                              void* d_out, int out_size, void* d_ws, size_t ws_size,
                              hipStream_t stream) {
    const float* image = (const float*)d_in[0];
    const float* limg  = (const float*)d_in[1];
    const float* c1w   = (const float*)d_in[2];
    const float* c1b   = (const float*)d_in[3];
    const float* c2w   = (const float*)d_in[4];
    const float* c2b   = (const float*)d_in[5];
    const float* f1w   = (const float*)d_in[6];
    const float* f1b   = (const float*)d_in[7];
    const float* fnw   = (const float*)d_in[8];
    const float* fnb   = (const float*)d_in[9];
    float* out = (float*)d_out;   // [1024*128 out][1024*128 label]
    float* ws  = (float*)d_ws;

    float* out1p = ws;                              // 1152*32*360 = 13,271,040
    float* out2  = out1p + (size_t)NTOT * 32 * 360; // 1152*3136
    float* lat   = out2 + (size_t)NTOT * 3136;      // 1024*512
    float* rep   = lat + (size_t)BATCH * 512;       // 128*512
    float* tT    = rep + (size_t)LABEL * 512;       // 512*128
    float* wmat  = tT + (size_t)512 * 128;          // 512*512
    float* rho   = wmat + (size_t)512 * 512;        // 1 (+pad)
    float* w3    = rho + 16;                        // 32*5*64*8 = 81920

    hipLaunchKernelGGL(w3prep, dim3(320), dim3(256), 0, stream, c2w, w3);
    hipLaunchKernelGGL(conv1_pool, dim3(NTOT), dim3(256), 0, stream, image, limg, c1w, c1b, out1p);
    hipLaunchKernelGGL(conv2_pool, dim3(NTOT), dim3(256), 0, stream, out1p, w3, c2b, out2);
    hipLaunchKernelGGL(fc1_gemm, dim3(NTOT / 64, 512 / 64), dim3(256), 0, stream,
                       out2, f1w, f1b, lat, rep);
    hipLaunchKernelGGL(fcn_softmax, dim3(BATCH), dim3(128), 0, stream, lat, fnw, fnb,
                       out + (size_t)BATCH * LABEL);
    hipLaunchKernelGGL(rho_kernel, dim3(1), dim3(256), 0, stream, rep, rho);
    hipLaunchKernelGGL(t_kernel, dim3(256), dim3(256), 0, stream, rep, rho, tT);
    hipLaunchKernelGGL(w_kernel, dim3(1024), dim3(256), 0, stream, tT, wmat);
    hipLaunchKernelGGL(clustering, dim3(BATCH / CB), dim3(256), 0, stream, lat, wmat, rep, out);
}

// Round 5
// 911.355 us; speedup vs baseline: 2.1441x; 1.1972x over previous
//
#include <hip/hip_runtime.h>
#include <math.h>

#define BATCH 1024
#define LABEL 128
#define LATENT 512
#define NTOT 1152  // 1024 + 128

// ---------------- conv1 (1->32, 5x5 SAME) + relu + 2x2 maxpool ----------------
// in [N,1,28,28] -> out compact [N,32,14,14]
__global__ __launch_bounds__(256) void conv1_pool(const float* __restrict__ image,
                                                  const float* __restrict__ limg,
                                                  const float* __restrict__ wt,
                                                  const float* __restrict__ bias,
                                                  float* __restrict__ out) {
    const int n = blockIdx.x;
    const float* in = (n < BATCH) ? (image + (size_t)n * 784)
                                  : (limg + (size_t)(n - BATCH) * 784);
    __shared__ float pin[32][32];     // padded 28+2+2
    __shared__ float wts[32 * 25];
    const int tid = threadIdx.x;
    for (int idx = tid; idx < 32 * 32; idx += 256) ((float*)pin)[idx] = 0.f;
    __syncthreads();
    for (int idx = tid; idx < 784; idx += 256) {
        int y = idx / 28, x = idx % 28;
        pin[y + 2][x + 2] = in[idx];
    }
    for (int idx = tid; idx < 800; idx += 256) wts[idx] = wt[idx];
    __syncthreads();
    for (int o = tid; o < 32 * 196; o += 256) {
        int oc = o / 196, p = o % 196, py = p / 14, px = p % 14;
        float b = bias[oc];
        float m = -1e30f;
        #pragma unroll
        for (int dy = 0; dy < 2; ++dy)
        #pragma unroll
        for (int dx = 0; dx < 2; ++dx) {
            int cy = 2 * py + dy, cx = 2 * px + dx;
            float acc = b;
            #pragma unroll
            for (int ky = 0; ky < 5; ++ky)
            #pragma unroll
            for (int kx = 0; kx < 5; ++kx)
                acc += pin[cy + ky][cx + kx] * wts[oc * 25 + ky * 5 + kx];
            m = fmaxf(m, acc);
        }
        out[(size_t)n * 6272 + o] = fmaxf(m, 0.f);
    }
}

// ---------------- weight re-layout for conv2: w2[ic][oc][28] ----------------
__global__ __launch_bounds__(256) void w2prep(const float* __restrict__ w,
                                              float* __restrict__ w2) {
    int idx = blockIdx.x * 256 + threadIdx.x;   // 32*64*28 = 57344
    if (idx >= 32 * 64 * 28) return;
    int k = idx % 28, t = idx / 28;
    int oc = t % 64, ic = t / 64;
    w2[idx] = (k < 25) ? w[oc * 800 + ic * 25 + k] : 0.f;
}

// ---------------- conv2 (32->64, 5x5 SAME) + relu + 2x2 maxpool ----------------
// Round-2 structure (proven fastest): lane = oc (64), wave = pool quadrant
// (dy,dx); LDS-staged input, 17-row sweep per ic; weights via aligned float4
// from pre-transposed w2. NEW: input staged in TWO ic-halves (16 ch each) so
// LDS = 23K pin + 12.5K maxbuf = 35.6KB -> 4 blocks/CU (was 58.9KB -> 2).
// Plain launch_bounds (r3 lesson: min-waves hint causes spills; r4 lesson:
// ky-outer restructure causes AGPR shuffling + 2x row re-reads).
template<int DX>
__device__ __forceinline__ void conv_ic(const float* __restrict__ prow,
                                        const float* __restrict__ wk,
                                        float* __restrict__ acc) {
    #pragma unroll
    for (int yp = 0; yp < 17; ++yp) {
        float row[20];
        const float4* rp = (const float4*)(prow + yp * 20);
        #pragma unroll
        for (int v = 0; v < 5; ++v) {
            float4 t = rp[v];
            row[4 * v + 0] = t.x; row[4 * v + 1] = t.y;
            row[4 * v + 2] = t.z; row[4 * v + 3] = t.w;
        }
        #pragma unroll
        for (int ky = 0; ky < 5; ++ky) {
            const int rem = yp - ky;            // = 2*py; compile-time after unroll
            if (rem < 0 || rem > 12 || (rem & 1)) continue;
            const int py = rem >> 1;
            #pragma unroll
            for (int kx = 0; kx < 5; ++kx) {
                float w = wk[ky * 5 + kx];
                #pragma unroll
                for (int px = 0; px < 7; ++px)
                    acc[py * 7 + px] = fmaf(row[2 * px + DX + kx], w, acc[py * 7 + px]);
            }
        }
    }
}

__global__ __launch_bounds__(256) void conv2_pool(const float* __restrict__ in,
                                                  const float* __restrict__ w2,
                                                  const float* __restrict__ bias,
                                                  float* __restrict__ out) {
    const int n = blockIdx.x;
    __shared__ float pin[16 * 360];     // 16 ic, rows padded to 20 floats
    __shared__ float maxbuf[64 * 49];
    const int tid = threadIdx.x;
    for (int idx = tid; idx < 16 * 360; idx += 256) pin[idx] = 0.f;

    const int lane = tid & 63, q = tid >> 6;
    const int oc = lane, dy = q >> 1, dx = q & 1;
    float acc[49];
    {
        float b = bias[oc];
        #pragma unroll
        for (int p = 0; p < 49; ++p) acc[p] = b;
    }
    for (int hf = 0; hf < 2; ++hf) {
        __syncthreads();   // prev compute done (and zero-init visible on hf=0)
        for (int idx = tid; idx < 16 * 196; idx += 256) {
            int ic = idx / 196, r = idx % 196, y = r / 14, x = r % 14;
            pin[ic * 360 + (y + 2) * 20 + (x + 2)] =
                in[(size_t)n * 6272 + (hf * 16 + ic) * 196 + r];
        }
        __syncthreads();
        for (int ic = 0; ic < 16; ++ic) {
            float wk[28];
            const float4* wp = (const float4*)(w2 + ((size_t)(hf * 16 + ic) * 64 + oc) * 28);
            #pragma unroll
            for (int v = 0; v < 7; ++v) {
                float4 t = wp[v];
                wk[4 * v + 0] = t.x; wk[4 * v + 1] = t.y;
                wk[4 * v + 2] = t.z; wk[4 * v + 3] = t.w;
            }
            const float* prow = pin + ic * 360 + dy * 20;
            if (dx == 0) conv_ic<0>(prow, wk, acc);   // wave-uniform branch
            else         conv_ic<1>(prow, wk, acc);
        }
    }
    __syncthreads();
    for (int qq = 0; qq < 4; ++qq) {
        if (q == qq) {
            if (qq == 0) {
                #pragma unroll
                for (int p = 0; p < 49; ++p) maxbuf[oc * 49 + p] = acc[p];
            } else {
                #pragma unroll
                for (int p = 0; p < 49; ++p)
                    maxbuf[oc * 49 + p] = fmaxf(maxbuf[oc * 49 + p], acc[p]);
            }
        }
        __syncthreads();
    }
    for (int idx = tid; idx < 3136; idx += 256)
        out[(size_t)n * 3136 + idx] = fmaxf(maxbuf[idx], 0.f);
}

// ---------------- fc1 GEMM: [1152,3136] @ [512,3136]^T + b ----------------
// rows < 1024 -> lat ; rows >= 1024 -> rep = tanh(...)
__global__ __launch_bounds__(256) void fc1_gemm(const float* __restrict__ A,
                                                const float* __restrict__ B,
                                                const float* __restrict__ bias,
                                                float* __restrict__ lat,
                                                float* __restrict__ rep) {
    __shared__ float As[16][68];
    __shared__ float Bs[16][68];
    const int tid = threadIdx.x;
    const int n0 = blockIdx.x * 64, m0 = blockIdx.y * 64;
    const int lr = tid >> 2;           // 0..63
    const int lk = (tid & 3) * 4;      // 0,4,8,12
    const int ty = tid >> 4, tx = tid & 15;
    float c[4][4] = {};
    for (int k0 = 0; k0 < 3136; k0 += 16) {
        float4 a4 = *(const float4*)(A + (size_t)(n0 + lr) * 3136 + k0 + lk);
        float4 b4 = *(const float4*)(B + (size_t)(m0 + lr) * 3136 + k0 + lk);
        __syncthreads();
        As[lk + 0][lr] = a4.x; As[lk + 1][lr] = a4.y; As[lk + 2][lr] = a4.z; As[lk + 3][lr] = a4.w;
        Bs[lk + 0][lr] = b4.x; Bs[lk + 1][lr] = b4.y; Bs[lk + 2][lr] = b4.z; Bs[lk + 3][lr] = b4.w;
        __syncthreads();
        #pragma unroll
        for (int kk = 0; kk < 16; ++kk) {
            float av[4], bv[4];
            #pragma unroll
            for (int i = 0; i < 4; ++i) av[i] = As[kk][ty * 4 + i];
            #pragma unroll
            for (int j = 0; j < 4; ++j) bv[j] = Bs[kk][tx * 4 + j];
            #pragma unroll
            for (int i = 0; i < 4; ++i)
            #pragma unroll
            for (int j = 0; j < 4; ++j) c[i][j] += av[i] * bv[j];
        }
    }
    #pragma unroll
    for (int i = 0; i < 4; ++i)
    #pragma unroll
    for (int j = 0; j < 4; ++j) {
        int n = n0 + ty * 4 + i, m = m0 + tx * 4 + j;
        float v = c[i][j] + bias[m];
        if (n < 1024) lat[n * 512 + m] = v;
        else rep[(n - 1024) * 512 + m] = tanhf(v);
    }
}

// ---------------- label = softmax(lat @ fcn_w.T + fcn_b) ----------------
__global__ __launch_bounds__(128) void fcn_softmax(const float* __restrict__ lat,
                                                   const float* __restrict__ fw,
                                                   const float* __restrict__ fb,
                                                   float* __restrict__ out) {
    const int b = blockIdx.x;
    const int j = threadIdx.x;   // 0..127
    __shared__ float lrow[512];
    __shared__ float red[128];
    for (int i = j; i < 512; i += 128) lrow[i] = lat[b * 512 + i];
    __syncthreads();
    const float4* w4 = (const float4*)(fw + j * 512);
    float acc = fb[j];
    #pragma unroll 4
    for (int q = 0; q < 128; ++q) {
        float4 a = ((const float4*)lrow)[q];
        float4 w = w4[q];
        acc += a.x * w.x + a.y * w.y + a.z * w.z + a.w * w.w;
    }
    red[j] = acc;
    __syncthreads();
    for (int off = 64; off >= 1; off >>= 1) {
        if (j < off) red[j] = fmaxf(red[j], red[j + off]);
        __syncthreads();
    }
    float mx = red[0];
    __syncthreads();
    float ex = expf(acc - mx);
    red[j] = ex;
    __syncthreads();
    for (int off = 64; off >= 1; off >>= 1) {
        if (j < off) red[j] += red[j + off];
        __syncthreads();
    }
    out[b * 128 + j] = ex / red[0];
}

// ---------------- rho = mean(rep) ----------------
__global__ __launch_bounds__(256) void rho_kernel(const float* __restrict__ rep,
                                                  float* __restrict__ rho) {
    __shared__ float red[256];
    const int tid = threadIdx.x;
    float s = 0.f;
    for (int i = tid; i < LABEL * LATENT; i += 256) s += rep[i];
    red[tid] = s;
    __syncthreads();
    for (int off = 128; off >= 1; off >>= 1) {
        if (tid < off) red[tid] += red[tid + off];
        __syncthreads();
    }
    if (tid == 0) rho[0] = red[0] / (float)(LABEL * LATENT);
}

// ---------------- tT[i][k] = rep[k][i] - rho ----------------
__global__ __launch_bounds__(256) void t_kernel(const float* __restrict__ rep,
                                                const float* __restrict__ rho,
                                                float* __restrict__ tT) {
    int idx = blockIdx.x * 256 + threadIdx.x;   // 65536 total
    int i = idx / 128, k = idx % 128;
    tT[idx] = rep[k * 512 + i] - rho[0];
}

// ---------------- w[i][j] = dot(tT_i, tT_j)/128, zero diag ----------------
__global__ __launch_bounds__(256) void w_kernel(const float* __restrict__ tT,
                                                float* __restrict__ w) {
    int idx = blockIdx.x * 256 + threadIdx.x;   // 262144 total
    int i = idx >> 9, j = idx & 511;
    const float4* a = (const float4*)(tT + i * 128);
    const float4* b = (const float4*)(tT + j * 128);
    float acc = 0.f;
    #pragma unroll 8
    for (int q = 0; q < 32; ++q) {
        float4 av = a[q], bv = b[q];
        acc += av.x * bv.x + av.y * bv.y + av.z * bv.z + av.w * bv.w;
    }
    w[idx] = (i == j) ? 0.f : acc * (1.f / 128.f);
}

// ---------------- clustering + fused out = softmax(|min_s @ rep.T|) ----------------
// One block handles CB batch rows. 256 threads; thread owns columns 2*tid, 2*tid+1.
// w is exactly symmetric, so the energy matvec of iter k is the update matvec of
// iter k+1 -> one matvec per iteration. Synchronous Hopfield with symmetric W
// has period <= 2 (Goles), so stopping when s_k == s_{k-1} (fixed point) or
// s_k == s_{k-2} (2-cycle) is exactly equivalent to running all 512 iterations.
#define CB 4
__device__ __forceinline__ float sgnf(float x) {
    return (x > 0.f) ? 1.f : ((x < 0.f) ? -1.f : 0.f);
}

__global__ __launch_bounds__(256) void clustering(const float* __restrict__ lat,
                                                  const float* __restrict__ w,
                                                  const float* __restrict__ rep,
                                                  float* __restrict__ out) {
    const int tid = threadIdx.x;
    const int row0 = blockIdx.x * CB;
    __shared__ float buf[3][CB][512];
    __shared__ float mins[CB][512];
    __shared__ float red[256];
    __shared__ float part_e[4][CB];
    __shared__ int part_f[4];
    __shared__ float min_e[CB];
    __shared__ int copyf[CB];
    __shared__ int donef[CB];
    const int i0 = 2 * tid, i1 = 2 * tid + 1;
    const int wave = tid >> 6, lane = tid & 63;

    #pragma unroll
    for (int r = 0; r < CB; ++r) {
        buf[0][r][i0] = tanhf(lat[(row0 + r) * 512 + i0]);
        buf[0][r][i1] = tanhf(lat[(row0 + r) * 512 + i1]);
    }
    if (tid < CB) { min_e[tid] = INFINITY; donef[tid] = 0; }
    __syncthreads();

    // h_0 = s_0 @ w
    float h0[CB], h1[CB];
    #pragma unroll
    for (int r = 0; r < CB; ++r) { h0[r] = 0.f; h1[r] = 0.f; }
    #pragma unroll 4
    for (int j = 0; j < 512; ++j) {
        float2 wv = *(const float2*)(w + (size_t)j * 512 + i0);
        #pragma unroll
        for (int r = 0; r < CB; ++r) {
            float sj = buf[0][r][j];
            h0[r] += sj * wv.x;
            h1[r] += sj * wv.y;
        }
    }

    for (int k = 1; k <= 512; ++k) {
        const int nw = k % 3, pv = (k + 2) % 3, pp = (k + 1) % 3;
        float sn0[CB], sn1[CB];
        int eqbits = 0xFF;
        #pragma unroll
        for (int r = 0; r < CB; ++r) {
            float p0 = buf[pv][r][i0], p1 = buf[pv][r][i1];
            float q0 = buf[pp][r][i0], q1 = buf[pp][r][i1];
            sn0[r] = fabsf(p0) * sgnf(h0[r]);
            sn1[r] = fabsf(p1) * sgnf(h1[r]);
            if (!(sn0[r] == p0 && sn1[r] == p1)) eqbits &= ~(1 << r);
            if (!(sn0[r] == q0 && sn1[r] == q1)) eqbits &= ~(1 << (4 + r));
            buf[nw][r][i0] = sn0[r];
            buf[nw][r][i1] = sn1[r];
        }
        __syncthreads();
        // h_k = s_k @ w   (doubles as energy matvec)
        #pragma unroll
        for (int r = 0; r < CB; ++r) { h0[r] = 0.f; h1[r] = 0.f; }
        #pragma unroll 4
        for (int j = 0; j < 512; ++j) {
            float2 wv = *(const float2*)(w + (size_t)j * 512 + i0);
            #pragma unroll
            for (int r = 0; r < CB; ++r) {
                float sj = buf[nw][r][j];
                h0[r] += sj * wv.x;
                h1[r] += sj * wv.y;
            }
        }
        float ep[CB];
        #pragma unroll
        for (int r = 0; r < CB; ++r) ep[r] = sn0[r] * h0[r] + sn1[r] * h1[r];
        // butterfly reduce within wave (sum e, and flags)
        #pragma unroll
        for (int m = 32; m >= 1; m >>= 1) {
            #pragma unroll
            for (int r = 0; r < CB; ++r) ep[r] += __shfl_xor(ep[r], m, 64);
            eqbits &= __shfl_xor(eqbits, m, 64);
        }
        if (lane == 0) {
            #pragma unroll
            for (int r = 0; r < CB; ++r) part_e[wave][r] = ep[r];
            part_f[wave] = eqbits;
        }
        __syncthreads();
        if (tid < CB) {
            int r = tid;
            float e = -(part_e[0][r] + part_e[1][r] + part_e[2][r] + part_e[3][r]);
            int fl = part_f[0] & part_f[1] & part_f[2] & part_f[3];
            int better = e < min_e[r];
            if (better) min_e[r] = e;
            copyf[r] = better;
            int fixedp = (fl >> r) & 1;
            int cyc = (k >= 2) && ((fl >> (4 + r)) & 1);
            if (fixedp || cyc) donef[r] = 1;
        }
        __syncthreads();
        int alldone = 1;
        #pragma unroll
        for (int r = 0; r < CB; ++r) {
            if (copyf[r]) { mins[r][i0] = sn0[r]; mins[r][i1] = sn1[r]; }
            alldone &= donef[r];
        }
        if (alldone) break;
    }
    __syncthreads();

    // out[row] = softmax_j(|sum_i mins[i] * rep[j][i]|)
    const int j = tid & 127, half = tid >> 7;
    for (int r = 0; r < CB; ++r) {
        const float4* rr = (const float4*)(rep + (size_t)j * 512 + half * 256);
        const float4* ms = (const float4*)(&mins[r][half * 256]);
        float p = 0.f;
        #pragma unroll 8
        for (int q = 0; q < 64; ++q) {
            float4 rv = rr[q], mv = ms[q];
            p += rv.x * mv.x + rv.y * mv.y + rv.z * mv.z + rv.w * mv.w;
        }
        red[tid] = p;
        __syncthreads();
        float v = 0.f;
        if (tid < 128) { v = fabsf(red[tid] + red[tid + 128]); red[tid] = v; }
        __syncthreads();
        for (int off = 64; off >= 1; off >>= 1) {
            if (tid < off) red[tid] = fmaxf(red[tid], red[tid + off]);
            __syncthreads();
        }
        float mx = red[0];
        __syncthreads();
        float ex = 0.f;
        if (tid < 128) { ex = expf(v - mx); red[tid] = ex; }
        __syncthreads();
        for (int off = 64; off >= 1; off >>= 1) {
            if (tid < off) red[tid] += red[tid + off];
            __syncthreads();
        }
        if (tid < 128) out[(size_t)(row0 + r) * 128 + tid] = ex / red[0];
        __syncthreads();
    }
}

extern "C" void kernel_launch(void* const* d_in, const int* in_sizes, int n_in,
                              void* d_out, int out_size, void* d_ws, size_t ws_size,
                              hipStream_t stream) {
    const float* image = (const float*)d_in[0];
    const float* limg  = (const float*)d_in[1];
    const float* c1w   = (const float*)d_in[2];
    const float* c1b   = (const float*)d_in[3];
    const float* c2w   = (const float*)d_in[4];
    const float* c2b   = (const float*)d_in[5];
    const float* f1w   = (const float*)d_in[6];
    const float* f1b   = (const float*)d_in[7];
    const float* fnw   = (const float*)d_in[8];
    const float* fnb   = (const float*)d_in[9];
    float* out = (float*)d_out;   // [1024*128 out][1024*128 label]
    float* ws  = (float*)d_ws;

    float* out1 = ws;                          // 1152*6272
    float* out2 = out1 + (size_t)NTOT * 6272;  // 1152*3136
    float* lat  = out2 + (size_t)NTOT * 3136;  // 1024*512
    float* rep  = lat + (size_t)BATCH * 512;   // 128*512
    float* tT   = rep + (size_t)LABEL * 512;   // 512*128
    float* wmat = tT + (size_t)512 * 128;      // 512*512
    float* rho  = wmat + (size_t)512 * 512;    // 1 (+pad)
    float* w2   = rho + 16;                    // 32*64*28 = 57344

    hipLaunchKernelGGL(w2prep, dim3(224), dim3(256), 0, stream, c2w, w2);
    hipLaunchKernelGGL(conv1_pool, dim3(NTOT), dim3(256), 0, stream, image, limg, c1w, c1b, out1);
    hipLaunchKernelGGL(conv2_pool, dim3(NTOT), dim3(256), 0, stream, out1, w2, c2b, out2);
    hipLaunchKernelGGL(fc1_gemm, dim3(NTOT / 64, 512 / 64), dim3(256), 0, stream,
                       out2, f1w, f1b, lat, rep);
    hipLaunchKernelGGL(fcn_softmax, dim3(BATCH), dim3(128), 0, stream, lat, fnw, fnb,
                       out + (size_t)BATCH * LABEL);
    hipLaunchKernelGGL(rho_kernel, dim3(1), dim3(256), 0, stream, rep, rho);
    hipLaunchKernelGGL(t_kernel, dim3(256), dim3(256), 0, stream, rep, rho, tT);
    hipLaunchKernelGGL(w_kernel, dim3(1024), dim3(256), 0, stream, tT, wmat);
    hipLaunchKernelGGL(clustering, dim3(BATCH / CB), dim3(256), 0, stream, lat, wmat, rep, out);
}

// Round 6
// 820.070 us; speedup vs baseline: 2.3828x; 1.1113x over previous
//
#include <hip/hip_runtime.h>
#include <math.h>

#define BATCH 1024
#define LABEL 128
#define LATENT 512
#define NTOT 1152  // 1024 + 128

// ---------------- conv1 (1->32, 5x5 SAME) + relu + 2x2 maxpool ----------------
__global__ __launch_bounds__(256) void conv1_pool(const float* __restrict__ image,
                                                  const float* __restrict__ limg,
                                                  const float* __restrict__ wt,
                                                  const float* __restrict__ bias,
                                                  float* __restrict__ out) {
    const int n = blockIdx.x;
    const float* in = (n < BATCH) ? (image + (size_t)n * 784)
                                  : (limg + (size_t)(n - BATCH) * 784);
    __shared__ float pin[32][32];
    __shared__ float wts[32 * 25];
    const int tid = threadIdx.x;
    for (int idx = tid; idx < 32 * 32; idx += 256) ((float*)pin)[idx] = 0.f;
    __syncthreads();
    for (int idx = tid; idx < 784; idx += 256) {
        int y = idx / 28, x = idx % 28;
        pin[y + 2][x + 2] = in[idx];
    }
    for (int idx = tid; idx < 800; idx += 256) wts[idx] = wt[idx];
    __syncthreads();
    for (int o = tid; o < 32 * 196; o += 256) {
        int oc = o / 196, p = o % 196, py = p / 14, px = p % 14;
        float b = bias[oc];
        float m = -1e30f;
        #pragma unroll
        for (int dy = 0; dy < 2; ++dy)
        #pragma unroll
        for (int dx = 0; dx < 2; ++dx) {
            int cy = 2 * py + dy, cx = 2 * px + dx;
            float acc = b;
            #pragma unroll
            for (int ky = 0; ky < 5; ++ky)
            #pragma unroll
            for (int kx = 0; kx < 5; ++kx)
                acc += pin[cy + ky][cx + kx] * wts[oc * 25 + ky * 5 + kx];
            m = fmaxf(m, acc);
        }
        out[(size_t)n * 6272 + o] = fmaxf(m, 0.f);
    }
}

// ---------------- weight re-layout for conv2: w2[ic][oc][28] ----------------
__global__ __launch_bounds__(256) void w2prep(const float* __restrict__ w,
                                              float* __restrict__ w2) {
    int idx = blockIdx.x * 256 + threadIdx.x;
    if (idx >= 32 * 64 * 28) return;
    int k = idx % 28, t = idx / 28;
    int oc = t % 64, ic = t / 64;
    w2[idx] = (k < 25) ? w[oc * 800 + ic * 25 + k] : 0.f;
}

// ---------------- conv2: round-5 proven structure, UNCHANGED ----------------
template<int DX>
__device__ __forceinline__ void conv_ic(const float* __restrict__ prow,
                                        const float* __restrict__ wk,
                                        float* __restrict__ acc) {
    #pragma unroll
    for (int yp = 0; yp < 17; ++yp) {
        float row[20];
        const float4* rp = (const float4*)(prow + yp * 20);
        #pragma unroll
        for (int v = 0; v < 5; ++v) {
            float4 t = rp[v];
            row[4 * v + 0] = t.x; row[4 * v + 1] = t.y;
            row[4 * v + 2] = t.z; row[4 * v + 3] = t.w;
        }
        #pragma unroll
        for (int ky = 0; ky < 5; ++ky) {
            const int rem = yp - ky;
            if (rem < 0 || rem > 12 || (rem & 1)) continue;
            const int py = rem >> 1;
            #pragma unroll
            for (int kx = 0; kx < 5; ++kx) {
                float w = wk[ky * 5 + kx];
                #pragma unroll
                for (int px = 0; px < 7; ++px)
                    acc[py * 7 + px] = fmaf(row[2 * px + DX + kx], w, acc[py * 7 + px]);
            }
        }
    }
}

__global__ __launch_bounds__(256) void conv2_pool(const float* __restrict__ in,
                                                  const float* __restrict__ w2,
                                                  const float* __restrict__ bias,
                                                  float* __restrict__ out) {
    const int n = blockIdx.x;
    __shared__ float pin[16 * 360];
    __shared__ float maxbuf[64 * 49];
    const int tid = threadIdx.x;
    for (int idx = tid; idx < 16 * 360; idx += 256) pin[idx] = 0.f;

    const int lane = tid & 63, q = tid >> 6;
    const int oc = lane, dy = q >> 1, dx = q & 1;
    float acc[49];
    {
        float b = bias[oc];
        #pragma unroll
        for (int p = 0; p < 49; ++p) acc[p] = b;
    }
    for (int hf = 0; hf < 2; ++hf) {
        __syncthreads();
        for (int idx = tid; idx < 16 * 196; idx += 256) {
            int ic = idx / 196, r = idx % 196, y = r / 14, x = r % 14;
            pin[ic * 360 + (y + 2) * 20 + (x + 2)] =
                in[(size_t)n * 6272 + (hf * 16 + ic) * 196 + r];
        }
        __syncthreads();
        for (int ic = 0; ic < 16; ++ic) {
            float wk[28];
            const float4* wp = (const float4*)(w2 + ((size_t)(hf * 16 + ic) * 64 + oc) * 28);
            #pragma unroll
            for (int v = 0; v < 7; ++v) {
                float4 t = wp[v];
                wk[4 * v + 0] = t.x; wk[4 * v + 1] = t.y;
                wk[4 * v + 2] = t.z; wk[4 * v + 3] = t.w;
            }
            const float* prow = pin + ic * 360 + dy * 20;
            if (dx == 0) conv_ic<0>(prow, wk, acc);
            else         conv_ic<1>(prow, wk, acc);
        }
    }
    __syncthreads();
    for (int qq = 0; qq < 4; ++qq) {
        if (q == qq) {
            if (qq == 0) {
                #pragma unroll
                for (int p = 0; p < 49; ++p) maxbuf[oc * 49 + p] = acc[p];
            } else {
                #pragma unroll
                for (int p = 0; p < 49; ++p)
                    maxbuf[oc * 49 + p] = fmaxf(maxbuf[oc * 49 + p], acc[p]);
            }
        }
        __syncthreads();
    }
    for (int idx = tid; idx < 3136; idx += 256)
        out[(size_t)n * 3136 + idx] = fmaxf(maxbuf[idx], 0.f);
}

// ---------------- fc1 GEMM split-K: partials, no bias ----------------
// 3136 = 7 x 448. grid (18, 8, 7) -> 1008 blocks (was 144: half the chip idle).
// part[kz][n][m], deterministic (no atomics); epilogue sums + bias + tanh.
__global__ __launch_bounds__(256) void fc1_gemm(const float* __restrict__ A,
                                                const float* __restrict__ B,
                                                float* __restrict__ part) {
    __shared__ float As[16][68];
    __shared__ float Bs[16][68];
    const int tid = threadIdx.x;
    const int n0 = blockIdx.x * 64, m0 = blockIdx.y * 64;
    const int koff = blockIdx.z * 448;
    const int lr = tid >> 2;
    const int lk = (tid & 3) * 4;
    const int ty = tid >> 4, tx = tid & 15;
    float c[4][4] = {};
    for (int k0 = koff; k0 < koff + 448; k0 += 16) {
        float4 a4 = *(const float4*)(A + (size_t)(n0 + lr) * 3136 + k0 + lk);
        float4 b4 = *(const float4*)(B + (size_t)(m0 + lr) * 3136 + k0 + lk);
        __syncthreads();
        As[lk + 0][lr] = a4.x; As[lk + 1][lr] = a4.y; As[lk + 2][lr] = a4.z; As[lk + 3][lr] = a4.w;
        Bs[lk + 0][lr] = b4.x; Bs[lk + 1][lr] = b4.y; Bs[lk + 2][lr] = b4.z; Bs[lk + 3][lr] = b4.w;
        __syncthreads();
        #pragma unroll
        for (int kk = 0; kk < 16; ++kk) {
            float av[4], bv[4];
            #pragma unroll
            for (int i = 0; i < 4; ++i) av[i] = As[kk][ty * 4 + i];
            #pragma unroll
            for (int j = 0; j < 4; ++j) bv[j] = Bs[kk][tx * 4 + j];
            #pragma unroll
            for (int i = 0; i < 4; ++i)
            #pragma unroll
            for (int j = 0; j < 4; ++j) c[i][j] += av[i] * bv[j];
        }
    }
    float* pb = part + (size_t)blockIdx.z * NTOT * 512;
    #pragma unroll
    for (int i = 0; i < 4; ++i)
    #pragma unroll
    for (int j = 0; j < 4; ++j) {
        int n = n0 + ty * 4 + i, m = m0 + tx * 4 + j;
        pb[(size_t)n * 512 + m] = c[i][j];
    }
}

__global__ __launch_bounds__(256) void fc1_reduce(const float* __restrict__ part,
                                                  const float* __restrict__ bias,
                                                  float* __restrict__ lat,
                                                  float* __restrict__ rep) {
    int idx = blockIdx.x * 256 + threadIdx.x;   // 1152*512 = 589824
    int m = idx & 511;
    float v = bias[m];
    #pragma unroll
    for (int kz = 0; kz < 7; ++kz) v += part[(size_t)kz * NTOT * 512 + idx];
    if (idx < BATCH * 512) lat[idx] = v;
    else rep[idx - BATCH * 512] = tanhf(v);
}

// ---------------- label = softmax(lat @ fcn_w.T + fcn_b) ----------------
__global__ __launch_bounds__(128) void fcn_softmax(const float* __restrict__ lat,
                                                   const float* __restrict__ fw,
                                                   const float* __restrict__ fb,
                                                   float* __restrict__ out) {
    const int b = blockIdx.x;
    const int j = threadIdx.x;
    __shared__ float lrow[512];
    __shared__ float red[128];
    for (int i = j; i < 512; i += 128) lrow[i] = lat[b * 512 + i];
    __syncthreads();
    const float4* w4 = (const float4*)(fw + j * 512);
    float acc = fb[j];
    #pragma unroll 4
    for (int q = 0; q < 128; ++q) {
        float4 a = ((const float4*)lrow)[q];
        float4 w = w4[q];
        acc += a.x * w.x + a.y * w.y + a.z * w.z + a.w * w.w;
    }
    red[j] = acc;
    __syncthreads();
    for (int off = 64; off >= 1; off >>= 1) {
        if (j < off) red[j] = fmaxf(red[j], red[j + off]);
        __syncthreads();
    }
    float mx = red[0];
    __syncthreads();
    float ex = expf(acc - mx);
    red[j] = ex;
    __syncthreads();
    for (int off = 64; off >= 1; off >>= 1) {
        if (j < off) red[j] += red[j + off];
        __syncthreads();
    }
    out[b * 128 + j] = ex / red[0];
}

// ---------------- rho = mean(rep) ----------------
__global__ __launch_bounds__(256) void rho_kernel(const float* __restrict__ rep,
                                                  float* __restrict__ rho) {
    __shared__ float red[256];
    const int tid = threadIdx.x;
    float s = 0.f;
    for (int i = tid; i < LABEL * LATENT; i += 256) s += rep[i];
    red[tid] = s;
    __syncthreads();
    for (int off = 128; off >= 1; off >>= 1) {
        if (tid < off) red[tid] += red[tid + off];
        __syncthreads();
    }
    if (tid == 0) rho[0] = red[0] / (float)(LABEL * LATENT);
}

// ---------------- tT[i][k] = rep[k][i] - rho ----------------
__global__ __launch_bounds__(256) void t_kernel(const float* __restrict__ rep,
                                                const float* __restrict__ rho,
                                                float* __restrict__ tT) {
    int idx = blockIdx.x * 256 + threadIdx.x;
    int i = idx / 128, k = idx % 128;
    tT[idx] = rep[k * 512 + i] - rho[0];
}

// ---------------- w[i][j] = dot(tT_i, tT_j)/128, zero diag ----------------
__global__ __launch_bounds__(256) void w_kernel(const float* __restrict__ tT,
                                                float* __restrict__ w) {
    int idx = blockIdx.x * 256 + threadIdx.x;
    int i = idx >> 9, j = idx & 511;
    const float4* a = (const float4*)(tT + i * 128);
    const float4* b = (const float4*)(tT + j * 128);
    float acc = 0.f;
    #pragma unroll 8
    for (int q = 0; q < 32; ++q) {
        float4 av = a[q], bv = b[q];
        acc += av.x * bv.x + av.y * bv.y + av.z * bv.z + av.w * bv.w;
    }
    w[idx] = (i == j) ? 0.f : acc * (1.f / 128.f);
}

// ---------------- clustering v2: incremental Hopfield + fused softmax ----------------
// After iter 1, s magnitudes are frozen (s_j = +-m_j); only signs flip, and flips
// decay fast. Maintain h = W*s in registers; per iteration update h only for the
// flipped columns via a per-row LDS flip list (h += delta_j * w[j,:]). Exact
// algebra. Fixed point <=> empty flip list; 2-cycle via s_{k-2} register compare.
// Early exit is exact (synchronous Hopfield, symmetric zero-diag W: period <= 2).
#define CB 4
__device__ __forceinline__ float sgnf(float x) {
    return (x > 0.f) ? 1.f : ((x < 0.f) ? -1.f : 0.f);
}

__global__ __launch_bounds__(256) void clustering(const float* __restrict__ lat,
                                                  const float* __restrict__ w,
                                                  const float* __restrict__ rep,
                                                  float* __restrict__ out) {
    const int tid = threadIdx.x;
    const int row0 = blockIdx.x * CB;
    __shared__ float sbuf[CB][512];      // only for the initial full matvec
    __shared__ float mins[CB][512];
    __shared__ float red[256];
    __shared__ float part_e[4][CB];
    __shared__ int part_c[4];
    __shared__ float min_e[CB];
    __shared__ int copyf[CB];
    __shared__ int donef[CB];
    __shared__ int cnt[CB];
    __shared__ int jidx[CB][512];
    __shared__ float jdel[CB][512];
    const int i0 = 2 * tid, i1 = 2 * tid + 1;
    const int wave = tid >> 6, lane = tid & 63;

    // registers: sm1 = s_{k-1}, sm2 = s_{k-2}, h = W*sm1
    float sm10[CB], sm11[CB], sm20[CB], sm21[CB], h0[CB], h1[CB];
    #pragma unroll
    for (int r = 0; r < CB; ++r) {
        float a = tanhf(lat[(row0 + r) * 512 + i0]);
        float b = tanhf(lat[(row0 + r) * 512 + i1]);
        sm10[r] = a; sm11[r] = b;
        sm20[r] = a; sm21[r] = b;     // unused until k>=2
        sbuf[r][i0] = a; sbuf[r][i1] = b;
        h0[r] = 0.f; h1[r] = 0.f;
    }
    if (tid < CB) { min_e[tid] = INFINITY; donef[tid] = 0; cnt[tid] = 0; }
    __syncthreads();

    // h = W * s0  (full matvec, once)
    #pragma unroll 4
    for (int j = 0; j < 512; ++j) {
        float2 wv = *(const float2*)(w + (size_t)j * 512 + i0);
        #pragma unroll
        for (int r = 0; r < CB; ++r) {
            float sj = sbuf[r][j];
            h0[r] = fmaf(sj, wv.x, h0[r]);
            h1[r] = fmaf(sj, wv.y, h1[r]);
        }
    }

    for (int k = 1; k <= 512; ++k) {
        float sn0[CB], sn1[CB];
        int cy = 0xF;
        #pragma unroll
        for (int r = 0; r < CB; ++r) {
            int dn = donef[r];
            if (dn) {
                sn0[r] = sm10[r]; sn1[r] = sm11[r];   // frozen
            } else {
                sn0[r] = fabsf(sm10[r]) * sgnf(h0[r]);
                sn1[r] = fabsf(sm11[r]) * sgnf(h1[r]);
                if (!(sn0[r] == sm20[r] && sn1[r] == sm21[r])) cy &= ~(1 << r);
                if (sn0[r] != sm10[r]) {
                    int p = atomicAdd(&cnt[r], 1);
                    jidx[r][p] = i0; jdel[r][p] = sn0[r] - sm10[r];
                }
                if (sn1[r] != sm11[r]) {
                    int p = atomicAdd(&cnt[r], 1);
                    jidx[r][p] = i1; jdel[r][p] = sn1[r] - sm11[r];
                }
            }
        }
        #pragma unroll
        for (int m = 32; m >= 1; m >>= 1) cy &= __shfl_xor(cy, m, 64);
        if (lane == 0) part_c[wave] = cy;
        __syncthreads();   // lists complete

        // h += W * delta (only flipped columns)
        #pragma unroll
        for (int r = 0; r < CB; ++r) {
            const int c = cnt[r];
            for (int t = 0; t < c; ++t) {
                const int j = jidx[r][t];
                const float d = jdel[r][t];
                const float2 wv = *(const float2*)(w + (size_t)j * 512 + i0);
                h0[r] = fmaf(d, wv.x, h0[r]);
                h1[r] = fmaf(d, wv.y, h1[r]);
            }
        }
        float ep[CB];
        #pragma unroll
        for (int r = 0; r < CB; ++r) ep[r] = sn0[r] * h0[r] + sn1[r] * h1[r];
        #pragma unroll
        for (int m = 32; m >= 1; m >>= 1) {
            #pragma unroll
            for (int r = 0; r < CB; ++r) ep[r] += __shfl_xor(ep[r], m, 64);
        }
        if (lane == 0) {
            #pragma unroll
            for (int r = 0; r < CB; ++r) part_e[wave][r] = ep[r];
        }
        __syncthreads();   // part_e / part_c ready, list consumption done

        if (tid < CB) {
            int r = tid;
            if (!donef[r]) {
                float e = -(part_e[0][r] + part_e[1][r] + part_e[2][r] + part_e[3][r]);
                int better = e < min_e[r];
                if (better) min_e[r] = e;
                copyf[r] = better;
                int fl = part_c[0] & part_c[1] & part_c[2] & part_c[3];
                int fixedp = (cnt[r] == 0);
                int cyc = (k >= 2) && ((fl >> r) & 1);
                if (fixedp || cyc) donef[r] = 1;
            } else {
                copyf[r] = 0;
            }
            cnt[r] = 0;
        }
        __syncthreads();   // decisions visible; safe to append next iter

        int alldone = 1;
        #pragma unroll
        for (int r = 0; r < CB; ++r) {
            if (copyf[r]) { mins[r][i0] = sn0[r]; mins[r][i1] = sn1[r]; }
            alldone &= donef[r];
            sm20[r] = sm10[r]; sm21[r] = sm11[r];
            sm10[r] = sn0[r];  sm11[r] = sn1[r];
        }
        if (alldone) break;
    }
    __syncthreads();

    // out[row] = softmax_j(|sum_i mins[i] * rep[j][i]|)
    const int j = tid & 127, half = tid >> 7;
    for (int r = 0; r < CB; ++r) {
        const float4* rr = (const float4*)(rep + (size_t)j * 512 + half * 256);
        const float4* ms = (const float4*)(&mins[r][half * 256]);
        float p = 0.f;
        #pragma unroll 8
        for (int q = 0; q < 64; ++q) {
            float4 rv = rr[q], mv = ms[q];
            p += rv.x * mv.x + rv.y * mv.y + rv.z * mv.z + rv.w * mv.w;
        }
        red[tid] = p;
        __syncthreads();
        float v = 0.f;
        if (tid < 128) { v = fabsf(red[tid] + red[tid + 128]); red[tid] = v; }
        __syncthreads();
        for (int off = 64; off >= 1; off >>= 1) {
            if (tid < off) red[tid] = fmaxf(red[tid], red[tid + off]);
            __syncthreads();
        }
        float mx = red[0];
        __syncthreads();
        float ex = 0.f;
        if (tid < 128) { ex = expf(v - mx); red[tid] = ex; }
        __syncthreads();
        for (int off = 64; off >= 1; off >>= 1) {
            if (tid < off) red[tid] += red[tid + off];
            __syncthreads();
        }
        if (tid < 128) out[(size_t)(row0 + r) * 128 + tid] = ex / red[0];
        __syncthreads();
    }
}

extern "C" void kernel_launch(void* const* d_in, const int* in_sizes, int n_in,
                              void* d_out, int out_size, void* d_ws, size_t ws_size,
                              hipStream_t stream) {
    const float* image = (const float*)d_in[0];
    const float* limg  = (const float*)d_in[1];
    const float* c1w   = (const float*)d_in[2];
    const float* c1b   = (const float*)d_in[3];
    const float* c2w   = (const float*)d_in[4];
    const float* c2b   = (const float*)d_in[5];
    const float* f1w   = (const float*)d_in[6];
    const float* f1b   = (const float*)d_in[7];
    const float* fnw   = (const float*)d_in[8];
    const float* fnb   = (const float*)d_in[9];
    float* out = (float*)d_out;
    float* ws  = (float*)d_ws;

    float* out1 = ws;                          // 1152*6272
    float* out2 = out1 + (size_t)NTOT * 6272;  // 1152*3136
    float* lat  = out2 + (size_t)NTOT * 3136;  // 1024*512
    float* rep  = lat + (size_t)BATCH * 512;   // 128*512
    float* tT   = rep + (size_t)LABEL * 512;   // 512*128
    float* wmat = tT + (size_t)512 * 128;      // 512*512
    float* rho  = wmat + (size_t)512 * 512;    // 1 (+pad)
    float* w2   = rho + 16;                    // 32*64*28
    float* part = w2 + (size_t)32 * 64 * 28;   // 7*1152*512 = 4,128,768

    hipLaunchKernelGGL(w2prep, dim3(224), dim3(256), 0, stream, c2w, w2);
    hipLaunchKernelGGL(conv1_pool, dim3(NTOT), dim3(256), 0, stream, image, limg, c1w, c1b, out1);
    hipLaunchKernelGGL(conv2_pool, dim3(NTOT), dim3(256), 0, stream, out1, w2, c2b, out2);
    hipLaunchKernelGGL(fc1_gemm, dim3(NTOT / 64, 512 / 64, 7), dim3(256), 0, stream,
                       out2, f1w, part);
    hipLaunchKernelGGL(fc1_reduce, dim3(NTOT * 512 / 256), dim3(256), 0, stream,
                       part, f1b, lat, rep);
    hipLaunchKernelGGL(fcn_softmax, dim3(BATCH), dim3(128), 0, stream, lat, fnw, fnb,
                       out + (size_t)BATCH * LABEL);
    hipLaunchKernelGGL(rho_kernel, dim3(1), dim3(256), 0, stream, rep, rho);
    hipLaunchKernelGGL(t_kernel, dim3(256), dim3(256), 0, stream, rep, rho, tT);
    hipLaunchKernelGGL(w_kernel, dim3(1024), dim3(256), 0, stream, tT, wmat);
    hipLaunchKernelGGL(clustering, dim3(BATCH / CB), dim3(256), 0, stream, lat, wmat, rep, out);
}

// Round 7
// 552.698 us; speedup vs baseline: 3.5354x; 1.4838x over previous
//
#include <hip/hip_runtime.h>
#include <hip/hip_bf16.h>
#include <math.h>

#define BATCH 1024
#define LABEL 128
#define LATENT 512
#define NTOT 1152  // 1024 + 128

typedef short short8 __attribute__((ext_vector_type(8)));
typedef float f32x16 __attribute__((ext_vector_type(16)));

__device__ __forceinline__ unsigned short f2bf(float f) {
    __hip_bfloat16 h = __float2bfloat16(f);
    return *(unsigned short*)&h;
}
__device__ __forceinline__ float bf2f(unsigned short u) {
    __hip_bfloat16 h; *(unsigned short*)&h = u;
    return __bfloat162float(h);
}

// ---------------- conv1 (1->32, 5x5 SAME) + relu + 2x2 maxpool ----------------
// out: channel-last PADDED fp32 plane o1p[n][18*20][32] (2-halo zeroed) so conv2
// can stage it directly in the MFMA channel-minor layout.
__global__ __launch_bounds__(256) void conv1_pool(const float* __restrict__ image,
                                                  const float* __restrict__ limg,
                                                  const float* __restrict__ wt,
                                                  const float* __restrict__ bias,
                                                  float* __restrict__ o1p) {
    const int n = blockIdx.x;
    const float* in = (n < BATCH) ? (image + (size_t)n * 784)
                                  : (limg + (size_t)(n - BATCH) * 784);
    __shared__ float pin[32][32];
    __shared__ float wts[32 * 25];
    const int tid = threadIdx.x;
    float* ob = o1p + (size_t)n * 11520;
    // zero whole padded plane (halo), vectorized
    float4 z4 = {0.f, 0.f, 0.f, 0.f};
    for (int i = tid; i < 2880; i += 256) ((float4*)ob)[i] = z4;
    for (int idx = tid; idx < 32 * 32; idx += 256) ((float*)pin)[idx] = 0.f;
    __syncthreads();
    for (int idx = tid; idx < 784; idx += 256) {
        int y = idx / 28, x = idx % 28;
        pin[y + 2][x + 2] = in[idx];
    }
    for (int idx = tid; idx < 800; idx += 256) wts[idx] = wt[idx];
    __syncthreads();
    // oc fixed per thread (tid&31): weights live in registers
    const int oc = tid & 31;
    float wk[25];
    #pragma unroll
    for (int k = 0; k < 25; ++k) wk[k] = wts[oc * 25 + k];
    float b = bias[oc];
    for (int o = tid; o < 6272; o += 256) {
        int p = o >> 5, py = p / 14, px = p % 14;
        float win[6][6];
        #pragma unroll
        for (int r = 0; r < 6; ++r)
        #pragma unroll
        for (int c = 0; c < 6; ++c)
            win[r][c] = pin[2 * py + r][2 * px + c];
        float a00 = b, a01 = b, a10 = b, a11 = b;
        #pragma unroll
        for (int ky = 0; ky < 5; ++ky)
        #pragma unroll
        for (int kx = 0; kx < 5; ++kx) {
            float w = wk[ky * 5 + kx];
            a00 = fmaf(win[ky][kx], w, a00);
            a01 = fmaf(win[ky][kx + 1], w, a01);
            a10 = fmaf(win[ky + 1][kx], w, a10);
            a11 = fmaf(win[ky + 1][kx + 1], w, a11);
        }
        float m = fmaxf(fmaxf(a00, a01), fmaxf(a10, a11));
        ob[((py + 2) * 20 + (px + 2)) * 32 + oc] = fmaxf(m, 0.f);
    }
}

// ---------------- B fragment prep: bf16x3 split, MFMA B-operand order ----------
// Bf[s][ocT][plane][lane][8] bf16; k = 16s + 8*(lane>>5) + j; tap=k>>5, ic=k&31.
__global__ __launch_bounds__(256) void bprep(const float* __restrict__ w,
                                             unsigned short* __restrict__ Bf) {
    int idx = blockIdx.x * 256 + threadIdx.x;   // 50*2*64*8 = 51200
    if (idx >= 51200) return;
    int j = idx & 7, lane = (idx >> 3) & 63, ocT = (idx >> 9) & 1, s = idx >> 10;
    int q = lane >> 5, nn = lane & 31;
    int k = 16 * s + 8 * q + j;
    int tap = k >> 5, ic = k & 31;
    int oc = 32 * ocT + nn;
    float v = w[oc * 800 + ic * 25 + tap];
    unsigned short b1 = f2bf(v);
    float r1 = v - bf2f(b1);
    unsigned short b2 = f2bf(r1);
    unsigned short b3 = f2bf(r1 - bf2f(b2));
    size_t base = ((size_t)(s * 2 + ocT) * 3) * 512 + lane * 8 + j;
    Bf[base] = b1; Bf[base + 512] = b2; Bf[base + 1024] = b3;
}

// ---------------- conv2 via MFMA implicit GEMM (bf16x3, 6 products) -----------
// Block = 1 image, 128 threads = 2 waves (wave = oc-tile of 32).
// M = 224 (7 tiles of 32 positions, 196 valid), K = 800 (50 steps of 16),
// A-frag: m=lane&31, k=(lane>>5)*8+j -> 8 consecutive channels at one pixel
// (channel-minor LDS layout => every frag load is one aligned ds_read_b128).
// Epilogue: x-pool in-lane (rows 2j/2j+1 share a lane), y-pool via LDS.
__global__ __launch_bounds__(128) void conv2_mfma(const float* __restrict__ in,
                                                  const unsigned short* __restrict__ Bf,
                                                  const float* __restrict__ bias,
                                                  float* __restrict__ out) {
    const int n = blockIdx.x;
    __shared__ unsigned short pl[3 * 11520 + 8];   // 3 bf16 planes, 69KB
    const int tid = threadIdx.x;
    const int lane = tid & 63, wv = tid >> 6;      // wv = oc-tile

    // ---- stage: fp32 padded plane -> 3 bf16 split planes in LDS ----
    const float2* src = (const float2*)(in + (size_t)n * 11520);
    unsigned int* d32 = (unsigned int*)pl;
    for (int i = tid; i < 5760; i += 128) {
        float2 v = src[i];
        unsigned short xa1 = f2bf(v.x); float xr = v.x - bf2f(xa1);
        unsigned short xa2 = f2bf(xr);  unsigned short xa3 = f2bf(xr - bf2f(xa2));
        unsigned short ya1 = f2bf(v.y); float yr = v.y - bf2f(ya1);
        unsigned short ya2 = f2bf(yr);  unsigned short ya3 = f2bf(yr - bf2f(ya2));
        d32[i]         = (unsigned int)xa1 | ((unsigned int)ya1 << 16);
        d32[5760 + i]  = (unsigned int)xa2 | ((unsigned int)ya2 << 16);
        d32[11520 + i] = (unsigned int)xa3 | ((unsigned int)ya3 << 16);
    }
    __syncthreads();

    const int m_ = lane & 31, q = lane >> 5;
    int pixb[7];
    #pragma unroll
    for (int t = 0; t < 7; ++t) {
        int m = 32 * t + m_;
        int y = m / 14; if (y > 13) y = 13;
        int x = m - 14 * y; if (x > 13) x = 13;   // pad lanes clamped (finite reads)
        pixb[t] = (y * 20 + x) * 32;
    }
    f32x16 acc[7];
    {
        float bs = bias[32 * wv + m_];
        #pragma unroll
        for (int t = 0; t < 7; ++t)
        #pragma unroll
        for (int r = 0; r < 16; ++r) acc[t][r] = bs;
    }

    for (int s = 0; s < 50; ++s) {
        const unsigned short* bp = Bf + ((size_t)(s * 2 + wv) * 3) * 512 + lane * 8;
        short8 b1 = *(const short8*)(bp);
        short8 b2 = *(const short8*)(bp + 512);
        short8 b3 = *(const short8*)(bp + 1024);
        int kb = 16 * s + 8 * q;
        int tap = kb >> 5, ic0 = kb & 31;
        int ky = (tap * 13) >> 6;       // exact /5 for tap<25
        int kx = tap - ky * 5;
        int koff = (ky * 20 + kx) * 32 + ic0;
        short8 a1[7], a2[7], a3[7];
        #pragma unroll
        for (int t = 0; t < 7; ++t) {
            const unsigned short* ap = pl + pixb[t] + koff;
            a1[t] = *(const short8*)(ap);
            a2[t] = *(const short8*)(ap + 11520);
            a3[t] = *(const short8*)(ap + 23040);
        }
        #pragma unroll
        for (int t = 0; t < 7; ++t)
            acc[t] = __builtin_amdgcn_mfma_f32_32x32x16_bf16(a1[t], b1, acc[t], 0, 0, 0);
        #pragma unroll
        for (int t = 0; t < 7; ++t)
            acc[t] = __builtin_amdgcn_mfma_f32_32x32x16_bf16(a1[t], b2, acc[t], 0, 0, 0);
        #pragma unroll
        for (int t = 0; t < 7; ++t)
            acc[t] = __builtin_amdgcn_mfma_f32_32x32x16_bf16(a2[t], b1, acc[t], 0, 0, 0);
        #pragma unroll
        for (int t = 0; t < 7; ++t)
            acc[t] = __builtin_amdgcn_mfma_f32_32x32x16_bf16(a2[t], b2, acc[t], 0, 0, 0);
        #pragma unroll
        for (int t = 0; t < 7; ++t)
            acc[t] = __builtin_amdgcn_mfma_f32_32x32x16_bf16(a1[t], b3, acc[t], 0, 0, 0);
        #pragma unroll
        for (int t = 0; t < 7; ++t)
            acc[t] = __builtin_amdgcn_mfma_f32_32x32x16_bf16(a3[t], b1, acc[t], 0, 0, 0);
    }
    __syncthreads();

    // ---- epilogue: x-max in-lane -> hx[y][px][oc] -> y-max + relu -> out ----
    float* hx = (float*)pl;   // 14*7*64 f32 = 25KB, aliases planes (post-sync)
    const int oc = 32 * wv + m_;
    #pragma unroll
    for (int t = 0; t < 7; ++t)
    #pragma unroll
    for (int e = 0; e < 8; ++e) {
        const int reg = 2 * e;
        const int r = (reg & 3) + 8 * (reg >> 2) + 4 * q;
        const int m = 32 * t + r;            // even, uniform per half-wave
        if (m < 196) {
            float xm = fmaxf(acc[t][reg], acc[t][reg + 1]);
            int y = (m * 2341) >> 15;        // /14
            int px = (m - 14 * y) >> 1;
            hx[(y * 7 + px) * 64 + oc] = xm;
        }
    }
    __syncthreads();
    for (int idx = tid; idx < 3136; idx += 128) {
        int oc2 = (idx * 2675) >> 17;        // /49
        int p = idx - 49 * oc2;
        int py = (p * 9363) >> 16;           // /7
        int px = p - 7 * py;
        float v = fmaxf(hx[(2 * py * 7 + px) * 64 + oc2],
                        hx[((2 * py + 1) * 7 + px) * 64 + oc2]);
        out[(size_t)n * 3136 + idx] = fmaxf(v, 0.f);
    }
}

// ---------------- fc1 GEMM split-K (r6 proven) ----------------
__global__ __launch_bounds__(256) void fc1_gemm(const float* __restrict__ A,
                                                const float* __restrict__ B,
                                                float* __restrict__ part) {
    __shared__ float As[16][68];
    __shared__ float Bs[16][68];
    const int tid = threadIdx.x;
    const int n0 = blockIdx.x * 64, m0 = blockIdx.y * 64;
    const int koff = blockIdx.z * 448;
    const int lr = tid >> 2;
    const int lk = (tid & 3) * 4;
    const int ty = tid >> 4, tx = tid & 15;
    float c[4][4] = {};
    for (int k0 = koff; k0 < koff + 448; k0 += 16) {
        float4 a4 = *(const float4*)(A + (size_t)(n0 + lr) * 3136 + k0 + lk);
        float4 b4 = *(const float4*)(B + (size_t)(m0 + lr) * 3136 + k0 + lk);
        __syncthreads();
        As[lk + 0][lr] = a4.x; As[lk + 1][lr] = a4.y; As[lk + 2][lr] = a4.z; As[lk + 3][lr] = a4.w;
        Bs[lk + 0][lr] = b4.x; Bs[lk + 1][lr] = b4.y; Bs[lk + 2][lr] = b4.z; Bs[lk + 3][lr] = b4.w;
        __syncthreads();
        #pragma unroll
        for (int kk = 0; kk < 16; ++kk) {
            float av[4], bv[4];
            #pragma unroll
            for (int i = 0; i < 4; ++i) av[i] = As[kk][ty * 4 + i];
            #pragma unroll
            for (int j = 0; j < 4; ++j) bv[j] = Bs[kk][tx * 4 + j];
            #pragma unroll
            for (int i = 0; i < 4; ++i)
            #pragma unroll
            for (int j = 0; j < 4; ++j) c[i][j] += av[i] * bv[j];
        }
    }
    float* pb = part + (size_t)blockIdx.z * NTOT * 512;
    #pragma unroll
    for (int i = 0; i < 4; ++i)
    #pragma unroll
    for (int j = 0; j < 4; ++j) {
        int n = n0 + ty * 4 + i, m = m0 + tx * 4 + j;
        pb[(size_t)n * 512 + m] = c[i][j];
    }
}

__global__ __launch_bounds__(256) void fc1_reduce(const float* __restrict__ part,
                                                  const float* __restrict__ bias,
                                                  float* __restrict__ lat,
                                                  float* __restrict__ rep) {
    int idx = blockIdx.x * 256 + threadIdx.x;
    int m = idx & 511;
    float v = bias[m];
    #pragma unroll
    for (int kz = 0; kz < 7; ++kz) v += part[(size_t)kz * NTOT * 512 + idx];
    if (idx < BATCH * 512) lat[idx] = v;
    else rep[idx - BATCH * 512] = tanhf(v);
}

// ---------------- label = softmax(lat @ fcn_w.T + fcn_b) ----------------
__global__ __launch_bounds__(128) void fcn_softmax(const float* __restrict__ lat,
                                                   const float* __restrict__ fw,
                                                   const float* __restrict__ fb,
                                                   float* __restrict__ out) {
    const int b = blockIdx.x;
    const int j = threadIdx.x;
    __shared__ float lrow[512];
    __shared__ float red[128];
    for (int i = j; i < 512; i += 128) lrow[i] = lat[b * 512 + i];
    __syncthreads();
    const float4* w4 = (const float4*)(fw + j * 512);
    float acc = fb[j];
    #pragma unroll 4
    for (int qq = 0; qq < 128; ++qq) {
        float4 a = ((const float4*)lrow)[qq];
        float4 w = w4[qq];
        acc += a.x * w.x + a.y * w.y + a.z * w.z + a.w * w.w;
    }
    red[j] = acc;
    __syncthreads();
    for (int off = 64; off >= 1; off >>= 1) {
        if (j < off) red[j] = fmaxf(red[j], red[j + off]);
        __syncthreads();
    }
    float mx = red[0];
    __syncthreads();
    float ex = expf(acc - mx);
    red[j] = ex;
    __syncthreads();
    for (int off = 64; off >= 1; off >>= 1) {
        if (j < off) red[j] += red[j + off];
        __syncthreads();
    }
    out[b * 128 + j] = ex / red[0];
}

// ---------------- rho / t / w ----------------
__global__ __launch_bounds__(256) void rho_kernel(const float* __restrict__ rep,
                                                  float* __restrict__ rho) {
    __shared__ float red[256];
    const int tid = threadIdx.x;
    float s = 0.f;
    for (int i = tid; i < LABEL * LATENT; i += 256) s += rep[i];
    red[tid] = s;
    __syncthreads();
    for (int off = 128; off >= 1; off >>= 1) {
        if (tid < off) red[tid] += red[tid + off];
        __syncthreads();
    }
    if (tid == 0) rho[0] = red[0] / (float)(LABEL * LATENT);
}

__global__ __launch_bounds__(256) void t_kernel(const float* __restrict__ rep,
                                                const float* __restrict__ rho,
                                                float* __restrict__ tT) {
    int idx = blockIdx.x * 256 + threadIdx.x;
    int i = idx / 128, k = idx % 128;
    tT[idx] = rep[k * 512 + i] - rho[0];
}

__global__ __launch_bounds__(256) void w_kernel(const float* __restrict__ tT,
                                                float* __restrict__ w) {
    int idx = blockIdx.x * 256 + threadIdx.x;
    int i = idx >> 9, j = idx & 511;
    const float4* a = (const float4*)(tT + i * 128);
    const float4* b = (const float4*)(tT + j * 128);
    float acc = 0.f;
    #pragma unroll 8
    for (int q = 0; q < 32; ++q) {
        float4 av = a[q], bv = b[q];
        acc += av.x * bv.x + av.y * bv.y + av.z * bv.z + av.w * bv.w;
    }
    w[idx] = (i == j) ? 0.f : acc * (1.f / 128.f);
}

// ---------------- clustering v2 (r6 proven): incremental Hopfield --------------
#define CB 4
__device__ __forceinline__ float sgnf(float x) {
    return (x > 0.f) ? 1.f : ((x < 0.f) ? -1.f : 0.f);
}

__global__ __launch_bounds__(256) void clustering(const float* __restrict__ lat,
                                                  const float* __restrict__ w,
                                                  const float* __restrict__ rep,
                                                  float* __restrict__ out) {
    const int tid = threadIdx.x;
    const int row0 = blockIdx.x * CB;
    __shared__ float sbuf[CB][512];
    __shared__ float mins[CB][512];
    __shared__ float red[256];
    __shared__ float part_e[4][CB];
    __shared__ int part_c[4];
    __shared__ float min_e[CB];
    __shared__ int copyf[CB];
    __shared__ int donef[CB];
    __shared__ int cnt[CB];
    __shared__ int jidx[CB][512];
    __shared__ float jdel[CB][512];
    const int i0 = 2 * tid, i1 = 2 * tid + 1;
    const int wave = tid >> 6, lane = tid & 63;

    float sm10[CB], sm11[CB], sm20[CB], sm21[CB], h0[CB], h1[CB];
    #pragma unroll
    for (int r = 0; r < CB; ++r) {
        float a = tanhf(lat[(row0 + r) * 512 + i0]);
        float b = tanhf(lat[(row0 + r) * 512 + i1]);
        sm10[r] = a; sm11[r] = b;
        sm20[r] = a; sm21[r] = b;
        sbuf[r][i0] = a; sbuf[r][i1] = b;
        h0[r] = 0.f; h1[r] = 0.f;
    }
    if (tid < CB) { min_e[tid] = INFINITY; donef[tid] = 0; cnt[tid] = 0; }
    __syncthreads();

    #pragma unroll 4
    for (int j = 0; j < 512; ++j) {
        float2 wvv = *(const float2*)(w + (size_t)j * 512 + i0);
        #pragma unroll
        for (int r = 0; r < CB; ++r) {
            float sj = sbuf[r][j];
            h0[r] = fmaf(sj, wvv.x, h0[r]);
            h1[r] = fmaf(sj, wvv.y, h1[r]);
        }
    }

    for (int k = 1; k <= 512; ++k) {
        float sn0[CB], sn1[CB];
        int cy = 0xF;
        #pragma unroll
        for (int r = 0; r < CB; ++r) {
            int dn = donef[r];
            if (dn) {
                sn0[r] = sm10[r]; sn1[r] = sm11[r];
            } else {
                sn0[r] = fabsf(sm10[r]) * sgnf(h0[r]);
                sn1[r] = fabsf(sm11[r]) * sgnf(h1[r]);
                if (!(sn0[r] == sm20[r] && sn1[r] == sm21[r])) cy &= ~(1 << r);
                if (sn0[r] != sm10[r]) {
                    int p = atomicAdd(&cnt[r], 1);
                    jidx[r][p] = i0; jdel[r][p] = sn0[r] - sm10[r];
                }
                if (sn1[r] != sm11[r]) {
                    int p = atomicAdd(&cnt[r], 1);
                    jidx[r][p] = i1; jdel[r][p] = sn1[r] - sm11[r];
                }
            }
        }
        #pragma unroll
        for (int m = 32; m >= 1; m >>= 1) cy &= __shfl_xor(cy, m, 64);
        if (lane == 0) part_c[wave] = cy;
        __syncthreads();

        #pragma unroll
        for (int r = 0; r < CB; ++r) {
            const int c = cnt[r];
            for (int t = 0; t < c; ++t) {
                const int j = jidx[r][t];
                const float d = jdel[r][t];
                const float2 wvv = *(const float2*)(w + (size_t)j * 512 + i0);
                h0[r] = fmaf(d, wvv.x, h0[r]);
                h1[r] = fmaf(d, wvv.y, h1[r]);
            }
        }
        float ep[CB];
        #pragma unroll
        for (int r = 0; r < CB; ++r) ep[r] = sn0[r] * h0[r] + sn1[r] * h1[r];
        #pragma unroll
        for (int m = 32; m >= 1; m >>= 1) {
            #pragma unroll
            for (int r = 0; r < CB; ++r) ep[r] += __shfl_xor(ep[r], m, 64);
        }
        if (lane == 0) {
            #pragma unroll
            for (int r = 0; r < CB; ++r) part_e[wave][r] = ep[r];
        }
        __syncthreads();

        if (tid < CB) {
            int r = tid;
            if (!donef[r]) {
                float e = -(part_e[0][r] + part_e[1][r] + part_e[2][r] + part_e[3][r]);
                int better = e < min_e[r];
                if (better) min_e[r] = e;
                copyf[r] = better;
                int fl = part_c[0] & part_c[1] & part_c[2] & part_c[3];
                int fixedp = (cnt[r] == 0);
                int cyc = (k >= 2) && ((fl >> r) & 1);
                if (fixedp || cyc) donef[r] = 1;
            } else {
                copyf[r] = 0;
            }
            cnt[r] = 0;
        }
        __syncthreads();

        int alldone = 1;
        #pragma unroll
        for (int r = 0; r < CB; ++r) {
            if (copyf[r]) { mins[r][i0] = sn0[r]; mins[r][i1] = sn1[r]; }
            alldone &= donef[r];
            sm20[r] = sm10[r]; sm21[r] = sm11[r];
            sm10[r] = sn0[r];  sm11[r] = sn1[r];
        }
        if (alldone) break;
    }
    __syncthreads();

    const int j = tid & 127, half = tid >> 7;
    for (int r = 0; r < CB; ++r) {
        const float4* rr = (const float4*)(rep + (size_t)j * 512 + half * 256);
        const float4* ms = (const float4*)(&mins[r][half * 256]);
        float p = 0.f;
        #pragma unroll 8
        for (int q = 0; q < 64; ++q) {
            float4 rv = rr[q], mv = ms[q];
            p += rv.x * mv.x + rv.y * mv.y + rv.z * mv.z + rv.w * mv.w;
        }
        red[tid] = p;
        __syncthreads();
        float v = 0.f;
        if (tid < 128) { v = fabsf(red[tid] + red[tid + 128]); red[tid] = v; }
        __syncthreads();
        for (int off = 64; off >= 1; off >>= 1) {
            if (tid < off) red[tid] = fmaxf(red[tid], red[tid + off]);
            __syncthreads();
        }
        float mx = red[0];
        __syncthreads();
        float ex = 0.f;
        if (tid < 128) { ex = expf(v - mx); red[tid] = ex; }
        __syncthreads();
        for (int off = 64; off >= 1; off >>= 1) {
            if (tid < off) red[tid] += red[tid + off];
            __syncthreads();
        }
        if (tid < 128) out[(size_t)(row0 + r) * 128 + tid] = ex / red[0];
        __syncthreads();
    }
}

extern "C" void kernel_launch(void* const* d_in, const int* in_sizes, int n_in,
                              void* d_out, int out_size, void* d_ws, size_t ws_size,
                              hipStream_t stream) {
    const float* image = (const float*)d_in[0];
    const float* limg  = (const float*)d_in[1];
    const float* c1w   = (const float*)d_in[2];
    const float* c1b   = (const float*)d_in[3];
    const float* c2w   = (const float*)d_in[4];
    const float* c2b   = (const float*)d_in[5];
    const float* f1w   = (const float*)d_in[6];
    const float* f1b   = (const float*)d_in[7];
    const float* fnw   = (const float*)d_in[8];
    const float* fnb   = (const float*)d_in[9];
    float* out = (float*)d_out;
    float* ws  = (float*)d_ws;

    float* o1p  = ws;                           // 1152*11520 = 13,271,040 f
    float* out2 = o1p + (size_t)NTOT * 11520;   // 1152*3136
    float* lat  = out2 + (size_t)NTOT * 3136;   // 1024*512
    float* rep  = lat + (size_t)BATCH * 512;    // 128*512
    float* tT   = rep + (size_t)LABEL * 512;    // 512*128
    float* wmat = tT + (size_t)512 * 128;       // 512*512
    float* rho  = wmat + (size_t)512 * 512;     // 1 (+pad)
    unsigned short* Bfrag = (unsigned short*)(rho + 16);  // 153,600 bf16
    float* part = o1p;                          // alias: o1p dead after conv2

    hipLaunchKernelGGL(bprep, dim3(200), dim3(256), 0, stream, c2w, Bfrag);
    hipLaunchKernelGGL(conv1_pool, dim3(NTOT), dim3(256), 0, stream, image, limg, c1w, c1b, o1p);
    hipLaunchKernelGGL(conv2_mfma, dim3(NTOT), dim3(128), 0, stream, o1p, Bfrag, c2b, out2);
    hipLaunchKernelGGL(fc1_gemm, dim3(NTOT / 64, 512 / 64, 7), dim3(256), 0, stream,
                       out2, f1w, part);
    hipLaunchKernelGGL(fc1_reduce, dim3(NTOT * 512 / 256), dim3(256), 0, stream,
                       part, f1b, lat, rep);
    hipLaunchKernelGGL(fcn_softmax, dim3(BATCH), dim3(128), 0, stream, lat, fnw, fnb,
                       out + (size_t)BATCH * LABEL);
    hipLaunchKernelGGL(rho_kernel, dim3(1), dim3(256), 0, stream, rep, rho);
    hipLaunchKernelGGL(t_kernel, dim3(256), dim3(256), 0, stream, rep, rho, tT);
    hipLaunchKernelGGL(w_kernel, dim3(1024), dim3(256), 0, stream, tT, wmat);
    hipLaunchKernelGGL(clustering, dim3(BATCH / CB), dim3(256), 0, stream, lat, wmat, rep, out);
}

// Round 8
// 518.941 us; speedup vs baseline: 3.7654x; 1.0651x over previous
//
#include <hip/hip_runtime.h>
#include <hip/hip_bf16.h>
#include <math.h>

#define BATCH 1024
#define LABEL 128
#define LATENT 512
#define NTOT 1152  // 1024 + 128

typedef short short8 __attribute__((ext_vector_type(8)));
typedef float f32x16 __attribute__((ext_vector_type(16)));

__device__ __forceinline__ unsigned short f2bf(float f) {
    __hip_bfloat16 h = __float2bfloat16(f);
    return *(unsigned short*)&h;
}
__device__ __forceinline__ float bf2f(unsigned short u) {
    __hip_bfloat16 h; *(unsigned short*)&h = u;
    return __bfloat162float(h);
}

// ---------------- conv1 (1->32, 5x5 SAME) + relu + 2x2 maxpool ----------------
// out: channel-last PADDED fp32 plane o1p[n][18*20][32] (2-halo zeroed).
__global__ __launch_bounds__(256) void conv1_pool(const float* __restrict__ image,
                                                  const float* __restrict__ limg,
                                                  const float* __restrict__ wt,
                                                  const float* __restrict__ bias,
                                                  float* __restrict__ o1p) {
    const int n = blockIdx.x;
    const float* in = (n < BATCH) ? (image + (size_t)n * 784)
                                  : (limg + (size_t)(n - BATCH) * 784);
    __shared__ float pin[32][32];
    __shared__ float wts[32 * 25];
    const int tid = threadIdx.x;
    float* ob = o1p + (size_t)n * 11520;
    float4 z4 = {0.f, 0.f, 0.f, 0.f};
    for (int i = tid; i < 2880; i += 256) ((float4*)ob)[i] = z4;
    for (int idx = tid; idx < 32 * 32; idx += 256) ((float*)pin)[idx] = 0.f;
    __syncthreads();
    for (int idx = tid; idx < 784; idx += 256) {
        int y = idx / 28, x = idx % 28;
        pin[y + 2][x + 2] = in[idx];
    }
    for (int idx = tid; idx < 800; idx += 256) wts[idx] = wt[idx];
    __syncthreads();
    const int oc = tid & 31;
    float wk[25];
    #pragma unroll
    for (int k = 0; k < 25; ++k) wk[k] = wts[oc * 25 + k];
    float b = bias[oc];
    for (int o = tid; o < 6272; o += 256) {
        int p = o >> 5, py = p / 14, px = p % 14;
        float win[6][6];
        #pragma unroll
        for (int r = 0; r < 6; ++r)
        #pragma unroll
        for (int c = 0; c < 6; ++c)
            win[r][c] = pin[2 * py + r][2 * px + c];
        float a00 = b, a01 = b, a10 = b, a11 = b;
        #pragma unroll
        for (int ky = 0; ky < 5; ++ky)
        #pragma unroll
        for (int kx = 0; kx < 5; ++kx) {
            float w = wk[ky * 5 + kx];
            a00 = fmaf(win[ky][kx], w, a00);
            a01 = fmaf(win[ky][kx + 1], w, a01);
            a10 = fmaf(win[ky + 1][kx], w, a10);
            a11 = fmaf(win[ky + 1][kx + 1], w, a11);
        }
        float m = fmaxf(fmaxf(a00, a01), fmaxf(a10, a11));
        ob[((py + 2) * 20 + (px + 2)) * 32 + oc] = fmaxf(m, 0.f);
    }
}

// ---------------- B fragment prep for conv2 (unchanged, r7 proven) ------------
__global__ __launch_bounds__(256) void bprep(const float* __restrict__ w,
                                             unsigned short* __restrict__ Bf) {
    int idx = blockIdx.x * 256 + threadIdx.x;   // 50*2*64*8 = 51200
    if (idx >= 51200) return;
    int j = idx & 7, lane = (idx >> 3) & 63, ocT = (idx >> 9) & 1, s = idx >> 10;
    int q = lane >> 5, nn = lane & 31;
    int k = 16 * s + 8 * q + j;
    int tap = k >> 5, ic = k & 31;
    int oc = 32 * ocT + nn;
    float v = w[oc * 800 + ic * 25 + tap];
    unsigned short b1 = f2bf(v);
    float r1 = v - bf2f(b1);
    unsigned short b2 = f2bf(r1);
    unsigned short b3 = f2bf(r1 - bf2f(b2));
    size_t base = ((size_t)(s * 2 + ocT) * 3) * 512 + lane * 8 + j;
    Bf[base] = b1; Bf[base + 512] = b2; Bf[base + 1024] = b3;
}

// ---------------- f1w prep: bf16x3 planes Bw3[pl][512][3136] ------------------
#define BSTR ((size_t)512 * 3136)
#define ASTR ((size_t)NTOT * 3136)
__global__ __launch_bounds__(256) void wprep(const float* __restrict__ w,
                                             unsigned short* __restrict__ B3) {
    int idx = blockIdx.x * 256 + threadIdx.x;   // 512*3136
    if (idx >= 512 * 3136) return;
    float v = w[idx];
    unsigned short b1 = f2bf(v);
    float r1 = v - bf2f(b1);
    unsigned short b2 = f2bf(r1);
    unsigned short b3 = f2bf(r1 - bf2f(b2));
    B3[idx] = b1; B3[BSTR + idx] = b2; B3[2 * BSTR + idx] = b3;
}

// ---------------- conv2 via MFMA (bf16x3), v2: swizzle + 4 waves --------------
// 256 thr = 4 waves: ocT = wv&1, kh = wv>>1 (K split 25+25 steps, LDS merge).
// LDS channel-groups (16B) XOR-swizzled by pixel: slot = g ^ (p&3) -> A-frag
// b128 reads spread uniformly over all 32 banks (was 2 bank-quads, 2x serial).
// Epilogue hx stride 65 (was 64: 32-way conflicted y-pool reads).
// Output: 3 bf16 split planes (feeds fc1_mfma directly).
__global__ __launch_bounds__(256) void conv2_mfma(const float* __restrict__ in,
                                                  const unsigned short* __restrict__ Bf,
                                                  const float* __restrict__ bias,
                                                  unsigned short* __restrict__ out3) {
    const int n = blockIdx.x;
    __shared__ unsigned short pl[3 * 11520 + 8];   // 69.1KB; reused as accbuf/hx
    const int tid = threadIdx.x;
    const int lane = tid & 63, wv = tid >> 6;
    const int ocT = wv & 1, kh = wv >> 1;

    // ---- stage fp32 plane -> 3 swizzled bf16 planes ----
    const float2* src = (const float2*)(in + (size_t)n * 11520);
    unsigned int* d32 = (unsigned int*)pl;
    for (int i = tid; i < 5760; i += 256) {
        float2 v = src[i];
        int pp = i >> 4, cc = i & 15;
        int j = (pp << 4) + ((((cc >> 2) ^ (pp & 3)) << 2) | (cc & 3));
        unsigned short xa1 = f2bf(v.x); float xr = v.x - bf2f(xa1);
        unsigned short xa2 = f2bf(xr);  unsigned short xa3 = f2bf(xr - bf2f(xa2));
        unsigned short ya1 = f2bf(v.y); float yr = v.y - bf2f(ya1);
        unsigned short ya2 = f2bf(yr);  unsigned short ya3 = f2bf(yr - bf2f(ya2));
        d32[j]         = (unsigned int)xa1 | ((unsigned int)ya1 << 16);
        d32[5760 + j]  = (unsigned int)xa2 | ((unsigned int)ya2 << 16);
        d32[11520 + j] = (unsigned int)xa3 | ((unsigned int)ya3 << 16);
    }
    __syncthreads();

    const int m_ = lane & 31, q = lane >> 5;
    int pix[7];
    #pragma unroll
    for (int t = 0; t < 7; ++t) {
        int m = 32 * t + m_;
        int y = m / 14; if (y > 13) y = 13;
        int x = m - 14 * y; if (x > 13) x = 13;
        pix[t] = y * 20 + x;
    }
    f32x16 acc[7];
    {
        float bs = (kh == 0) ? bias[32 * ocT + m_] : 0.f;   // bias added once
        #pragma unroll
        for (int t = 0; t < 7; ++t)
        #pragma unroll
        for (int r = 0; r < 16; ++r) acc[t][r] = bs;
    }

    for (int s = kh * 25; s < kh * 25 + 25; ++s) {
        const unsigned short* bp = Bf + ((size_t)(s * 2 + ocT) * 3) * 512 + lane * 8;
        short8 b1 = *(const short8*)(bp);
        short8 b2 = *(const short8*)(bp + 512);
        short8 b3 = *(const short8*)(bp + 1024);
        int kb = 16 * s + 8 * q;
        int tap = kb >> 5, ic0 = kb & 31, g = ic0 >> 3;
        int ky = (tap * 13) >> 6;       // exact /5 for tap<25
        int kx = tap - ky * 5;
        int pq = ky * 20 + kx;
        short8 a1[7], a2[7], a3[7];
        #pragma unroll
        for (int t = 0; t < 7; ++t) {
            int pt = pix[t] + pq;
            const unsigned short* ap = pl + (pt << 5) + ((g ^ (pt & 3)) << 3);
            a1[t] = *(const short8*)(ap);
            a2[t] = *(const short8*)(ap + 11520);
            a3[t] = *(const short8*)(ap + 23040);
        }
        #pragma unroll
        for (int t = 0; t < 7; ++t)
            acc[t] = __builtin_amdgcn_mfma_f32_32x32x16_bf16(a1[t], b1, acc[t], 0, 0, 0);
        #pragma unroll
        for (int t = 0; t < 7; ++t)
            acc[t] = __builtin_amdgcn_mfma_f32_32x32x16_bf16(a1[t], b2, acc[t], 0, 0, 0);
        #pragma unroll
        for (int t = 0; t < 7; ++t)
            acc[t] = __builtin_amdgcn_mfma_f32_32x32x16_bf16(a2[t], b1, acc[t], 0, 0, 0);
        #pragma unroll
        for (int t = 0; t < 7; ++t)
            acc[t] = __builtin_amdgcn_mfma_f32_32x32x16_bf16(a2[t], b2, acc[t], 0, 0, 0);
        #pragma unroll
        for (int t = 0; t < 7; ++t)
            acc[t] = __builtin_amdgcn_mfma_f32_32x32x16_bf16(a1[t], b3, acc[t], 0, 0, 0);
        #pragma unroll
        for (int t = 0; t < 7; ++t)
            acc[t] = __builtin_amdgcn_mfma_f32_32x32x16_bf16(a3[t], b1, acc[t], 0, 0, 0);
    }
    __syncthreads();

    // ---- merge K halves through LDS ----
    float* accbuf = (float*)pl;    // 2*7*16*64 f32 = 57.3KB
    if (kh == 0) {
        #pragma unroll
        for (int t = 0; t < 7; ++t)
        #pragma unroll
        for (int r = 0; r < 16; ++r)
            accbuf[((ocT * 7 + t) * 16 + r) * 64 + lane] = acc[t][r];
    }
    __syncthreads();
    if (kh == 1) {
        #pragma unroll
        for (int t = 0; t < 7; ++t)
        #pragma unroll
        for (int r = 0; r < 16; ++r)
            acc[t][r] += accbuf[((ocT * 7 + t) * 16 + r) * 64 + lane];
    }
    __syncthreads();

    // ---- x-pool in-lane (kh=1 waves) -> hx[y][px][oc], stride 65 ----
    float* hx = (float*)pl;        // 97*65+64 f32 ~ 25.5KB (aliases accbuf, post-sync)
    if (kh == 1) {
        const int oc = 32 * ocT + m_;
        #pragma unroll
        for (int t = 0; t < 7; ++t)
        #pragma unroll
        for (int e = 0; e < 8; ++e) {
            const int reg = 2 * e;
            const int r = (reg & 3) + 8 * (reg >> 2) + 4 * q;
            const int m = 32 * t + r;
            if (m < 196) {
                float xm = fmaxf(acc[t][reg], acc[t][reg + 1]);
                int y = (m * 2341) >> 15;        // /14
                int px = (m - 14 * y) >> 1;
                hx[(y * 7 + px) * 65 + oc] = xm;
            }
        }
    }
    __syncthreads();

    // ---- y-pool + relu + bf16x3 store ----
    const size_t OSTR = ASTR;
    for (int idx = tid; idx < 3136; idx += 256) {
        int oc2 = (idx * 2675) >> 17;        // /49
        int p = idx - 49 * oc2;
        int py = (p * 9363) >> 16;           // /7
        int px = p - 7 * py;
        float v = fmaxf(hx[(2 * py * 7 + px) * 65 + oc2],
                        hx[((2 * py + 1) * 7 + px) * 65 + oc2]);
        v = fmaxf(v, 0.f);
        unsigned short b1 = f2bf(v);
        float r1 = v - bf2f(b1);
        unsigned short b2 = f2bf(r1);
        unsigned short b3 = f2bf(r1 - bf2f(b2));
        size_t o = (size_t)n * 3136 + idx;
        out3[o] = b1; out3[OSTR + o] = b2; out3[2 * OSTR + o] = b3;
    }
}

// ---------------- fc1 via MFMA (bf16x3, 6 products), split-K=7 ----------------
// C[n][m] = A[n][k] B[m][k]; block tile 64n x 64m, BK=32, 4 waves = quadrants.
// LDS rows XOR-swizzled (slot = g ^ (row&3)) -> conflict-free b128 frag reads.
__global__ __launch_bounds__(256) void fc1_mfma(const unsigned short* __restrict__ A3,
                                                const unsigned short* __restrict__ B3,
                                                float* __restrict__ part) {
    __shared__ unsigned short As[3][2048];
    __shared__ unsigned short Bs[3][2048];
    const int tid = threadIdx.x;
    const int n0 = blockIdx.x * 64, m0 = blockIdx.y * 64;
    const int koff = blockIdx.z * 448;
    const int lr = tid >> 2, g = tid & 3;
    const int slot = ((g ^ (lr & 3)) << 3);
    const int lane = tid & 63, wv = tid >> 6;
    const int nq = wv & 1, mq = wv >> 1;
    const int q = lane >> 5, l31 = lane & 31;
    const int rA = 32 * nq + l31, rB = 32 * mq + l31;
    f32x16 acc;
    #pragma unroll
    for (int r = 0; r < 16; ++r) acc[r] = 0.f;

    for (int bk = 0; bk < 448; bk += 32) {
        const size_t ka = (size_t)(koff + bk + (g << 3));
        short8 av[3], bv[3];
        #pragma unroll
        for (int p = 0; p < 3; ++p) {
            av[p] = *(const short8*)(A3 + p * ASTR + (size_t)(n0 + lr) * 3136 + ka);
            bv[p] = *(const short8*)(B3 + p * BSTR + (size_t)(m0 + lr) * 3136 + ka);
        }
        __syncthreads();
        #pragma unroll
        for (int p = 0; p < 3; ++p) {
            *(short8*)&As[p][(lr << 5) + slot] = av[p];
            *(short8*)&Bs[p][(lr << 5) + slot] = bv[p];
        }
        __syncthreads();
        #pragma unroll
        for (int s2 = 0; s2 < 32; s2 += 16) {
            const int gg = (s2 + (q << 3)) >> 3;
            const int sa = ((gg ^ (rA & 3)) << 3);
            const int sb = ((gg ^ (rB & 3)) << 3);
            short8 a1 = *(const short8*)&As[0][(rA << 5) + sa];
            short8 a2 = *(const short8*)&As[1][(rA << 5) + sa];
            short8 a3 = *(const short8*)&As[2][(rA << 5) + sa];
            short8 b1 = *(const short8*)&Bs[0][(rB << 5) + sb];
            short8 b2 = *(const short8*)&Bs[1][(rB << 5) + sb];
            short8 b3 = *(const short8*)&Bs[2][(rB << 5) + sb];
            acc = __builtin_amdgcn_mfma_f32_32x32x16_bf16(a1, b1, acc, 0, 0, 0);
            acc = __builtin_amdgcn_mfma_f32_32x32x16_bf16(a1, b2, acc, 0, 0, 0);
            acc = __builtin_amdgcn_mfma_f32_32x32x16_bf16(a2, b1, acc, 0, 0, 0);
            acc = __builtin_amdgcn_mfma_f32_32x32x16_bf16(a2, b2, acc, 0, 0, 0);
            acc = __builtin_amdgcn_mfma_f32_32x32x16_bf16(a1, b3, acc, 0, 0, 0);
            acc = __builtin_amdgcn_mfma_f32_32x32x16_bf16(a3, b1, acc, 0, 0, 0);
        }
    }
    float* pb = part + (size_t)blockIdx.z * NTOT * 512;
    #pragma unroll
    for (int reg = 0; reg < 16; ++reg) {
        int nn = n0 + 32 * nq + (reg & 3) + 8 * (reg >> 2) + 4 * q;
        int mm = m0 + 32 * mq + l31;
        pb[(size_t)nn * 512 + mm] = acc[reg];
    }
}

__global__ __launch_bounds__(256) void fc1_reduce(const float* __restrict__ part,
                                                  const float* __restrict__ bias,
                                                  float* __restrict__ lat,
                                                  float* __restrict__ rep) {
    int idx = blockIdx.x * 256 + threadIdx.x;
    int m = idx & 511;
    float v = bias[m];
    #pragma unroll
    for (int kz = 0; kz < 7; ++kz) v += part[(size_t)kz * NTOT * 512 + idx];
    if (idx < BATCH * 512) lat[idx] = v;
    else rep[idx - BATCH * 512] = tanhf(v);
}

// ---------------- label = softmax(lat @ fcn_w.T + fcn_b) ----------------
__global__ __launch_bounds__(128) void fcn_softmax(const float* __restrict__ lat,
                                                   const float* __restrict__ fw,
                                                   const float* __restrict__ fb,
                                                   float* __restrict__ out) {
    const int b = blockIdx.x;
    const int j = threadIdx.x;
    __shared__ float lrow[512];
    __shared__ float red[128];
    for (int i = j; i < 512; i += 128) lrow[i] = lat[b * 512 + i];
    __syncthreads();
    const float4* w4 = (const float4*)(fw + j * 512);
    float acc = fb[j];
    #pragma unroll 4
    for (int qq = 0; qq < 128; ++qq) {
        float4 a = ((const float4*)lrow)[qq];
        float4 w = w4[qq];
        acc += a.x * w.x + a.y * w.y + a.z * w.z + a.w * w.w;
    }
    red[j] = acc;
    __syncthreads();
    for (int off = 64; off >= 1; off >>= 1) {
        if (j < off) red[j] = fmaxf(red[j], red[j + off]);
        __syncthreads();
    }
    float mx = red[0];
    __syncthreads();
    float ex = expf(acc - mx);
    red[j] = ex;
    __syncthreads();
    for (int off = 64; off >= 1; off >>= 1) {
        if (j < off) red[j] += red[j + off];
        __syncthreads();
    }
    out[b * 128 + j] = ex / red[0];
}

// ---------------- rho / t / w ----------------
__global__ __launch_bounds__(256) void rho_kernel(const float* __restrict__ rep,
                                                  float* __restrict__ rho) {
    __shared__ float red[256];
    const int tid = threadIdx.x;
    float s = 0.f;
    for (int i = tid; i < LABEL * LATENT; i += 256) s += rep[i];
    red[tid] = s;
    __syncthreads();
    for (int off = 128; off >= 1; off >>= 1) {
        if (tid < off) red[tid] += red[tid + off];
        __syncthreads();
    }
    if (tid == 0) rho[0] = red[0] / (float)(LABEL * LATENT);
}

__global__ __launch_bounds__(256) void t_kernel(const float* __restrict__ rep,
                                                const float* __restrict__ rho,
                                                float* __restrict__ tT) {
    int idx = blockIdx.x * 256 + threadIdx.x;
    int i = idx / 128, k = idx % 128;
    tT[idx] = rep[k * 512 + i] - rho[0];
}

__global__ __launch_bounds__(256) void w_kernel(const float* __restrict__ tT,
                                                float* __restrict__ w) {
    int idx = blockIdx.x * 256 + threadIdx.x;
    int i = idx >> 9, j = idx & 511;
    const float4* a = (const float4*)(tT + i * 128);
    const float4* b = (const float4*)(tT + j * 128);
    float acc = 0.f;
    #pragma unroll 8
    for (int q = 0; q < 32; ++q) {
        float4 av = a[q], bv = b[q];
        acc += av.x * bv.x + av.y * bv.y + av.z * bv.z + av.w * bv.w;
    }
    w[idx] = (i == j) ? 0.f : acc * (1.f / 128.f);
}

// ---------------- clustering (r6 proven): incremental Hopfield ----------------
#define CB 4
__device__ __forceinline__ float sgnf(float x) {
    return (x > 0.f) ? 1.f : ((x < 0.f) ? -1.f : 0.f);
}

__global__ __launch_bounds__(256) void clustering(const float* __restrict__ lat,
                                                  const float* __restrict__ w,
                                                  const float* __restrict__ rep,
                                                  float* __restrict__ out) {
    const int tid = threadIdx.x;
    const int row0 = blockIdx.x * CB;
    __shared__ float sbuf[CB][512];
    __shared__ float mins[CB][512];
    __shared__ float red[256];
    __shared__ float part_e[4][CB];
    __shared__ int part_c[4];
    __shared__ float min_e[CB];
    __shared__ int copyf[CB];
    __shared__ int donef[CB];
    __shared__ int cnt[CB];
    __shared__ int jidx[CB][512];
    __shared__ float jdel[CB][512];
    const int i0 = 2 * tid, i1 = 2 * tid + 1;
    const int wave = tid >> 6, lane = tid & 63;

    float sm10[CB], sm11[CB], sm20[CB], sm21[CB], h0[CB], h1[CB];
    #pragma unroll
    for (int r = 0; r < CB; ++r) {
        float a = tanhf(lat[(row0 + r) * 512 + i0]);
        float b = tanhf(lat[(row0 + r) * 512 + i1]);
        sm10[r] = a; sm11[r] = b;
        sm20[r] = a; sm21[r] = b;
        sbuf[r][i0] = a; sbuf[r][i1] = b;
        h0[r] = 0.f; h1[r] = 0.f;
    }
    if (tid < CB) { min_e[tid] = INFINITY; donef[tid] = 0; cnt[tid] = 0; }
    __syncthreads();

    #pragma unroll 4
    for (int j = 0; j < 512; ++j) {
        float2 wvv = *(const float2*)(w + (size_t)j * 512 + i0);
        #pragma unroll
        for (int r = 0; r < CB; ++r) {
            float sj = sbuf[r][j];
            h0[r] = fmaf(sj, wvv.x, h0[r]);
            h1[r] = fmaf(sj, wvv.y, h1[r]);
        }
    }

    for (int k = 1; k <= 512; ++k) {
        float sn0[CB], sn1[CB];
        int cy = 0xF;
        #pragma unroll
        for (int r = 0; r < CB; ++r) {
            int dn = donef[r];
            if (dn) {
                sn0[r] = sm10[r]; sn1[r] = sm11[r];
            } else {
                sn0[r] = fabsf(sm10[r]) * sgnf(h0[r]);
                sn1[r] = fabsf(sm11[r]) * sgnf(h1[r]);
                if (!(sn0[r] == sm20[r] && sn1[r] == sm21[r])) cy &= ~(1 << r);
                if (sn0[r] != sm10[r]) {
                    int p = atomicAdd(&cnt[r], 1);
                    jidx[r][p] = i0; jdel[r][p] = sn0[r] - sm10[r];
                }
                if (sn1[r] != sm11[r]) {
                    int p = atomicAdd(&cnt[r], 1);
                    jidx[r][p] = i1; jdel[r][p] = sn1[r] - sm11[r];
                }
            }
        }
        #pragma unroll
        for (int m = 32; m >= 1; m >>= 1) cy &= __shfl_xor(cy, m, 64);
        if (lane == 0) part_c[wave] = cy;
        __syncthreads();

        #pragma unroll
        for (int r = 0; r < CB; ++r) {
            const int c = cnt[r];
            for (int t = 0; t < c; ++t) {
                const int j = jidx[r][t];
                const float d = jdel[r][t];
                const float2 wvv = *(const float2*)(w + (size_t)j * 512 + i0);
                h0[r] = fmaf(d, wvv.x, h0[r]);
                h1[r] = fmaf(d, wvv.y, h1[r]);
            }
        }
        float ep[CB];
        #pragma unroll
        for (int r = 0; r < CB; ++r) ep[r] = sn0[r] * h0[r] + sn1[r] * h1[r];
        #pragma unroll
        for (int m = 32; m >= 1; m >>= 1) {
            #pragma unroll
            for (int r = 0; r < CB; ++r) ep[r] += __shfl_xor(ep[r], m, 64);
        }
        if (lane == 0) {
            #pragma unroll
            for (int r = 0; r < CB; ++r) part_e[wave][r] = ep[r];
        }
        __syncthreads();

        if (tid < CB) {
            int r = tid;
            if (!donef[r]) {
                float e = -(part_e[0][r] + part_e[1][r] + part_e[2][r] + part_e[3][r]);
                int better = e < min_e[r];
                if (better) min_e[r] = e;
                copyf[r] = better;
                int fl = part_c[0] & part_c[1] & part_c[2] & part_c[3];
                int fixedp = (cnt[r] == 0);
                int cyc = (k >= 2) && ((fl >> r) & 1);
                if (fixedp || cyc) donef[r] = 1;
            } else {
                copyf[r] = 0;
            }
            cnt[r] = 0;
        }
        __syncthreads();

        int alldone = 1;
        #pragma unroll
        for (int r = 0; r < CB; ++r) {
            if (copyf[r]) { mins[r][i0] = sn0[r]; mins[r][i1] = sn1[r]; }
            alldone &= donef[r];
            sm20[r] = sm10[r]; sm21[r] = sm11[r];
            sm10[r] = sn0[r];  sm11[r] = sn1[r];
        }
        if (alldone) break;
    }
    __syncthreads();

    const int j = tid & 127, half = tid >> 7;
    for (int r = 0; r < CB; ++r) {
        const float4* rr = (const float4*)(rep + (size_t)j * 512 + half * 256);
        const float4* ms = (const float4*)(&mins[r][half * 256]);
        float p = 0.f;
        #pragma unroll 8
        for (int q = 0; q < 64; ++q) {
            float4 rv = rr[q], mv = ms[q];
            p += rv.x * mv.x + rv.y * mv.y + rv.z * mv.z + rv.w * mv.w;
        }
        red[tid] = p;
        __syncthreads();
        float v = 0.f;
        if (tid < 128) { v = fabsf(red[tid] + red[tid + 128]); red[tid] = v; }
        __syncthreads();
        for (int off = 64; off >= 1; off >>= 1) {
            if (tid < off) red[tid] = fmaxf(red[tid], red[tid + off]);
            __syncthreads();
        }
        float mx = red[0];
        __syncthreads();
        float ex = 0.f;
        if (tid < 128) { ex = expf(v - mx); red[tid] = ex; }
        __syncthreads();
        for (int off = 64; off >= 1; off >>= 1) {
            if (tid < off) red[tid] += red[tid + off];
            __syncthreads();
        }
        if (tid < 128) out[(size_t)(row0 + r) * 128 + tid] = ex / red[0];
        __syncthreads();
    }
}

extern "C" void kernel_launch(void* const* d_in, const int* in_sizes, int n_in,
                              void* d_out, int out_size, void* d_ws, size_t ws_size,
                              hipStream_t stream) {
    const float* image = (const float*)d_in[0];
    const float* limg  = (const float*)d_in[1];
    const float* c1w   = (const float*)d_in[2];
    const float* c1b   = (const float*)d_in[3];
    const float* c2w   = (const float*)d_in[4];
    const float* c2b   = (const float*)d_in[5];
    const float* f1w   = (const float*)d_in[6];
    const float* f1b   = (const float*)d_in[7];
    const float* fnw   = (const float*)d_in[8];
    const float* fnb   = (const float*)d_in[9];
    float* out = (float*)d_out;
    float* ws  = (float*)d_ws;

    float* o1p  = ws;                               // 1152*11520 f32 = 53.1MB
    unsigned short* out3 = (unsigned short*)(o1p + (size_t)NTOT * 11520);  // 3*ASTR
    float* lat  = (float*)(out3 + 3 * ASTR);        // 1024*512
    float* rep  = lat + (size_t)BATCH * 512;        // 128*512
    float* tT   = rep + (size_t)LABEL * 512;        // 512*128
    float* wmat = tT + (size_t)512 * 128;           // 512*512
    float* rho  = wmat + (size_t)512 * 512;         // 1 (+pad)
    unsigned short* Bw3   = (unsigned short*)(rho + 16);   // 3*BSTR bf16
    unsigned short* Bfrag = Bw3 + 3 * BSTR;                // 153,600 bf16
    float* part = o1p;                              // alias: o1p dead after conv2

    hipLaunchKernelGGL(bprep, dim3(200), dim3(256), 0, stream, c2w, Bfrag);
    hipLaunchKernelGGL(wprep, dim3(6272), dim3(256), 0, stream, f1w, Bw3);
    hipLaunchKernelGGL(conv1_pool, dim3(NTOT), dim3(256), 0, stream, image, limg, c1w, c1b, o1p);
    hipLaunchKernelGGL(conv2_mfma, dim3(NTOT), dim3(256), 0, stream, o1p, Bfrag, c2b, out3);
    hipLaunchKernelGGL(fc1_mfma, dim3(NTOT / 64, 512 / 64, 7), dim3(256), 0, stream,
                       out3, Bw3, part);
    hipLaunchKernelGGL(fc1_reduce, dim3(NTOT * 512 / 256), dim3(256), 0, stream,
                       part, f1b, lat, rep);
    hipLaunchKernelGGL(fcn_softmax, dim3(BATCH), dim3(128), 0, stream, lat, fnw, fnb,
                       out + (size_t)BATCH * LABEL);
    hipLaunchKernelGGL(rho_kernel, dim3(1), dim3(256), 0, stream, rep, rho);
    hipLaunchKernelGGL(t_kernel, dim3(256), dim3(256), 0, stream, rep, rho, tT);
    hipLaunchKernelGGL(w_kernel, dim3(1024), dim3(256), 0, stream, tT, wmat);
    hipLaunchKernelGGL(clustering, dim3(BATCH / CB), dim3(256), 0, stream, lat, wmat, rep, out);
}

// Round 9
// 515.655 us; speedup vs baseline: 3.7894x; 1.0064x over previous
//
#include <hip/hip_runtime.h>
#include <hip/hip_bf16.h>
#include <math.h>

#define BATCH 1024
#define LABEL 128
#define LATENT 512
#define NTOT 1152  // 1024 + 128

typedef short short8 __attribute__((ext_vector_type(8)));
typedef float f32x16 __attribute__((ext_vector_type(16)));

__device__ __forceinline__ unsigned short f2bf(float f) {
    __hip_bfloat16 h = __float2bfloat16(f);
    return *(unsigned short*)&h;
}
__device__ __forceinline__ float bf2f(unsigned short u) {
    __hip_bfloat16 h; *(unsigned short*)&h = u;
    return __bfloat162float(h);
}

// ---------------- conv1 (1->32, 5x5 SAME) + relu + 2x2 maxpool ----------------
// out: channel-last PADDED fp32 plane o1p[n][18*20][32] (2-halo zeroed).
__global__ __launch_bounds__(256) void conv1_pool(const float* __restrict__ image,
                                                  const float* __restrict__ limg,
                                                  const float* __restrict__ wt,
                                                  const float* __restrict__ bias,
                                                  float* __restrict__ o1p) {
    const int n = blockIdx.x;
    const float* in = (n < BATCH) ? (image + (size_t)n * 784)
                                  : (limg + (size_t)(n - BATCH) * 784);
    __shared__ float pin[32][32];
    __shared__ float wts[32 * 25];
    const int tid = threadIdx.x;
    float* ob = o1p + (size_t)n * 11520;
    float4 z4 = {0.f, 0.f, 0.f, 0.f};
    for (int i = tid; i < 2880; i += 256) ((float4*)ob)[i] = z4;
    for (int idx = tid; idx < 32 * 32; idx += 256) ((float*)pin)[idx] = 0.f;
    __syncthreads();
    for (int idx = tid; idx < 784; idx += 256) {
        int y = idx / 28, x = idx % 28;
        pin[y + 2][x + 2] = in[idx];
    }
    for (int idx = tid; idx < 800; idx += 256) wts[idx] = wt[idx];
    __syncthreads();
    const int oc = tid & 31;
    float wk[25];
    #pragma unroll
    for (int k = 0; k < 25; ++k) wk[k] = wts[oc * 25 + k];
    float b = bias[oc];
    for (int o = tid; o < 6272; o += 256) {
        int p = o >> 5, py = p / 14, px = p % 14;
        float win[6][6];
        #pragma unroll
        for (int r = 0; r < 6; ++r)
        #pragma unroll
        for (int c = 0; c < 6; ++c)
            win[r][c] = pin[2 * py + r][2 * px + c];
        float a00 = b, a01 = b, a10 = b, a11 = b;
        #pragma unroll
        for (int ky = 0; ky < 5; ++ky)
        #pragma unroll
        for (int kx = 0; kx < 5; ++kx) {
            float w = wk[ky * 5 + kx];
            a00 = fmaf(win[ky][kx], w, a00);
            a01 = fmaf(win[ky][kx + 1], w, a01);
            a10 = fmaf(win[ky + 1][kx], w, a10);
            a11 = fmaf(win[ky + 1][kx + 1], w, a11);
        }
        float m = fmaxf(fmaxf(a00, a01), fmaxf(a10, a11));
        ob[((py + 2) * 20 + (px + 2)) * 32 + oc] = fmaxf(m, 0.f);
    }
}

// ---------------- B fragment prep for conv2 (unchanged, r7 proven) ------------
__global__ __launch_bounds__(256) void bprep(const float* __restrict__ w,
                                             unsigned short* __restrict__ Bf) {
    int idx = blockIdx.x * 256 + threadIdx.x;   // 50*2*64*8 = 51200
    if (idx >= 51200) return;
    int j = idx & 7, lane = (idx >> 3) & 63, ocT = (idx >> 9) & 1, s = idx >> 10;
    int q = lane >> 5, nn = lane & 31;
    int k = 16 * s + 8 * q + j;
    int tap = k >> 5, ic = k & 31;
    int oc = 32 * ocT + nn;
    float v = w[oc * 800 + ic * 25 + tap];
    unsigned short b1 = f2bf(v);
    float r1 = v - bf2f(b1);
    unsigned short b2 = f2bf(r1);
    unsigned short b3 = f2bf(r1 - bf2f(b2));
    size_t base = ((size_t)(s * 2 + ocT) * 3) * 512 + lane * 8 + j;
    Bf[base] = b1; Bf[base + 512] = b2; Bf[base + 1024] = b3;
}

// ---------------- f1w prep: bf16x3 planes Bw3[pl][512][3136] ------------------
#define BSTR ((size_t)512 * 3136)
#define ASTR ((size_t)NTOT * 3136)
__global__ __launch_bounds__(256) void wprep(const float* __restrict__ w,
                                             unsigned short* __restrict__ B3) {
    int idx = blockIdx.x * 256 + threadIdx.x;   // 512*3136
    if (idx >= 512 * 3136) return;
    float v = w[idx];
    unsigned short b1 = f2bf(v);
    float r1 = v - bf2f(b1);
    unsigned short b2 = f2bf(r1);
    unsigned short b3 = f2bf(r1 - bf2f(b2));
    B3[idx] = b1; B3[BSTR + idx] = b2; B3[2 * BSTR + idx] = b3;
}

// ---------------- conv2 via MFMA (bf16x3), v3: CORRECT swizzle ----------------
// Bank math: A-frag granule = 4*pt + slot; mod 8 selects the bank-quad.
// r8's slot = g^(pt&3) gave 4(pt&1)+(g^(pt&3)) -> only 4 of 8 quads (2-way).
// v3: slot = (g ^ (pt>>1)) & 3 -> 4(pt&1)+((g^(pt>>1))&3) walks ALL 8 quads
// over 8 consecutive pixels -> 32 lanes uniform over 32 banks (conflict-free).
__global__ __launch_bounds__(256) void conv2_mfma(const float* __restrict__ in,
                                                  const unsigned short* __restrict__ Bf,
                                                  const float* __restrict__ bias,
                                                  unsigned short* __restrict__ out3) {
    const int n = blockIdx.x;
    __shared__ unsigned short pl[3 * 11520 + 8];   // 69.1KB; reused as accbuf/hx
    const int tid = threadIdx.x;
    const int lane = tid & 63, wv = tid >> 6;
    const int ocT = wv & 1, kh = wv >> 1;

    // ---- stage fp32 plane -> 3 swizzled bf16 planes ----
    const float2* src = (const float2*)(in + (size_t)n * 11520);
    unsigned int* d32 = (unsigned int*)pl;
    for (int i = tid; i < 5760; i += 256) {
        float2 v = src[i];
        int pp = i >> 4, cc = i & 15;
        int j = (pp << 4) + ((((cc >> 2) ^ (pp >> 1)) & 3) << 2) + (cc & 3);
        unsigned short xa1 = f2bf(v.x); float xr = v.x - bf2f(xa1);
        unsigned short xa2 = f2bf(xr);  unsigned short xa3 = f2bf(xr - bf2f(xa2));
        unsigned short ya1 = f2bf(v.y); float yr = v.y - bf2f(ya1);
        unsigned short ya2 = f2bf(yr);  unsigned short ya3 = f2bf(yr - bf2f(ya2));
        d32[j]         = (unsigned int)xa1 | ((unsigned int)ya1 << 16);
        d32[5760 + j]  = (unsigned int)xa2 | ((unsigned int)ya2 << 16);
        d32[11520 + j] = (unsigned int)xa3 | ((unsigned int)ya3 << 16);
    }
    __syncthreads();

    const int m_ = lane & 31, q = lane >> 5;
    int pix[7];
    #pragma unroll
    for (int t = 0; t < 7; ++t) {
        int m = 32 * t + m_;
        int y = m / 14; if (y > 13) y = 13;
        int x = m - 14 * y; if (x > 13) x = 13;
        pix[t] = y * 20 + x;
    }
    f32x16 acc[7];
    {
        float bs = (kh == 0) ? bias[32 * ocT + m_] : 0.f;   // bias added once
        #pragma unroll
        for (int t = 0; t < 7; ++t)
        #pragma unroll
        for (int r = 0; r < 16; ++r) acc[t][r] = bs;
    }

    for (int s = kh * 25; s < kh * 25 + 25; ++s) {
        const unsigned short* bp = Bf + ((size_t)(s * 2 + ocT) * 3) * 512 + lane * 8;
        short8 b1 = *(const short8*)(bp);
        short8 b2 = *(const short8*)(bp + 512);
        short8 b3 = *(const short8*)(bp + 1024);
        int kb = 16 * s + 8 * q;
        int tap = kb >> 5, ic0 = kb & 31, g = ic0 >> 3;
        int ky = (tap * 13) >> 6;       // exact /5 for tap<25
        int kx = tap - ky * 5;
        int pq = ky * 20 + kx;
        short8 a1[7], a2[7], a3[7];
        #pragma unroll
        for (int t = 0; t < 7; ++t) {
            int pt = pix[t] + pq;
            const unsigned short* ap = pl + (pt << 5) + (((g ^ (pt >> 1)) & 3) << 3);
            a1[t] = *(const short8*)(ap);
            a2[t] = *(const short8*)(ap + 11520);
            a3[t] = *(const short8*)(ap + 23040);
        }
        #pragma unroll
        for (int t = 0; t < 7; ++t)
            acc[t] = __builtin_amdgcn_mfma_f32_32x32x16_bf16(a1[t], b1, acc[t], 0, 0, 0);
        #pragma unroll
        for (int t = 0; t < 7; ++t)
            acc[t] = __builtin_amdgcn_mfma_f32_32x32x16_bf16(a1[t], b2, acc[t], 0, 0, 0);
        #pragma unroll
        for (int t = 0; t < 7; ++t)
            acc[t] = __builtin_amdgcn_mfma_f32_32x32x16_bf16(a2[t], b1, acc[t], 0, 0, 0);
        #pragma unroll
        for (int t = 0; t < 7; ++t)
            acc[t] = __builtin_amdgcn_mfma_f32_32x32x16_bf16(a2[t], b2, acc[t], 0, 0, 0);
        #pragma unroll
        for (int t = 0; t < 7; ++t)
            acc[t] = __builtin_amdgcn_mfma_f32_32x32x16_bf16(a1[t], b3, acc[t], 0, 0, 0);
        #pragma unroll
        for (int t = 0; t < 7; ++t)
            acc[t] = __builtin_amdgcn_mfma_f32_32x32x16_bf16(a3[t], b1, acc[t], 0, 0, 0);
    }
    __syncthreads();

    // ---- merge K halves through LDS ----
    float* accbuf = (float*)pl;    // 2*7*16*64 f32 = 57.3KB
    if (kh == 0) {
        #pragma unroll
        for (int t = 0; t < 7; ++t)
        #pragma unroll
        for (int r = 0; r < 16; ++r)
            accbuf[((ocT * 7 + t) * 16 + r) * 64 + lane] = acc[t][r];
    }
    __syncthreads();
    if (kh == 1) {
        #pragma unroll
        for (int t = 0; t < 7; ++t)
        #pragma unroll
        for (int r = 0; r < 16; ++r)
            acc[t][r] += accbuf[((ocT * 7 + t) * 16 + r) * 64 + lane];
    }
    __syncthreads();

    // ---- x-pool in-lane (kh=1 waves) -> hx[y][px][oc], stride 65 ----
    float* hx = (float*)pl;        // aliases accbuf, post-sync
    if (kh == 1) {
        const int oc = 32 * ocT + m_;
        #pragma unroll
        for (int t = 0; t < 7; ++t)
        #pragma unroll
        for (int e = 0; e < 8; ++e) {
            const int reg = 2 * e;
            const int r = (reg & 3) + 8 * (reg >> 2) + 4 * q;
            const int m = 32 * t + r;
            if (m < 196) {
                float xm = fmaxf(acc[t][reg], acc[t][reg + 1]);
                int y = (m * 2341) >> 15;        // /14
                int px = (m - 14 * y) >> 1;
                hx[(y * 7 + px) * 65 + oc] = xm;
            }
        }
    }
    __syncthreads();

    // ---- y-pool + relu + bf16x3 store ----
    const size_t OSTR = ASTR;
    for (int idx = tid; idx < 3136; idx += 256) {
        int oc2 = (idx * 2675) >> 17;        // /49
        int p = idx - 49 * oc2;
        int py = (p * 9363) >> 16;           // /7
        int px = p - 7 * py;
        float v = fmaxf(hx[(2 * py * 7 + px) * 65 + oc2],
                        hx[((2 * py + 1) * 7 + px) * 65 + oc2]);
        v = fmaxf(v, 0.f);
        unsigned short b1 = f2bf(v);
        float r1 = v - bf2f(b1);
        unsigned short b2 = f2bf(r1);
        unsigned short b3 = f2bf(r1 - bf2f(b2));
        size_t o = (size_t)n * 3136 + idx;
        out3[o] = b1; out3[OSTR + o] = b2; out3[2 * OSTR + o] = b3;
    }
}

// ---------------- fc1 via MFMA (bf16x3, 6 products), split-K=7 ----------------
__global__ __launch_bounds__(256) void fc1_mfma(const unsigned short* __restrict__ A3,
                                                const unsigned short* __restrict__ B3,
                                                float* __restrict__ part) {
    __shared__ unsigned short As[3][2048];
    __shared__ unsigned short Bs[3][2048];
    const int tid = threadIdx.x;
    const int n0 = blockIdx.x * 64, m0 = blockIdx.y * 64;
    const int koff = blockIdx.z * 448;
    const int lr = tid >> 2, g = tid & 3;
    const int slot = ((g ^ (lr & 3)) << 3);
    const int lane = tid & 63, wv = tid >> 6;
    const int nq = wv & 1, mq = wv >> 1;
    const int q = lane >> 5, l31 = lane & 31;
    const int rA = 32 * nq + l31, rB = 32 * mq + l31;
    f32x16 acc;
    #pragma unroll
    for (int r = 0; r < 16; ++r) acc[r] = 0.f;

    for (int bk = 0; bk < 448; bk += 32) {
        const size_t ka = (size_t)(koff + bk + (g << 3));
        short8 av[3], bv[3];
        #pragma unroll
        for (int p = 0; p < 3; ++p) {
            av[p] = *(const short8*)(A3 + p * ASTR + (size_t)(n0 + lr) * 3136 + ka);
            bv[p] = *(const short8*)(B3 + p * BSTR + (size_t)(m0 + lr) * 3136 + ka);
        }
        __syncthreads();
        #pragma unroll
        for (int p = 0; p < 3; ++p) {
            *(short8*)&As[p][(lr << 5) + slot] = av[p];
            *(short8*)&Bs[p][(lr << 5) + slot] = bv[p];
        }
        __syncthreads();
        #pragma unroll
        for (int s2 = 0; s2 < 32; s2 += 16) {
            const int gg = (s2 + (q << 3)) >> 3;
            const int sa = ((gg ^ (rA & 3)) << 3);
            const int sb = ((gg ^ (rB & 3)) << 3);
            short8 a1 = *(const short8*)&As[0][(rA << 5) + sa];
            short8 a2 = *(const short8*)&As[1][(rA << 5) + sa];
            short8 a3 = *(const short8*)&As[2][(rA << 5) + sa];
            short8 b1 = *(const short8*)&Bs[0][(rB << 5) + sb];
            short8 b2 = *(const short8*)&Bs[1][(rB << 5) + sb];
            short8 b3 = *(const short8*)&Bs[2][(rB << 5) + sb];
            acc = __builtin_amdgcn_mfma_f32_32x32x16_bf16(a1, b1, acc, 0, 0, 0);
            acc = __builtin_amdgcn_mfma_f32_32x32x16_bf16(a1, b2, acc, 0, 0, 0);
            acc = __builtin_amdgcn_mfma_f32_32x32x16_bf16(a2, b1, acc, 0, 0, 0);
            acc = __builtin_amdgcn_mfma_f32_32x32x16_bf16(a2, b2, acc, 0, 0, 0);
            acc = __builtin_amdgcn_mfma_f32_32x32x16_bf16(a1, b3, acc, 0, 0, 0);
            acc = __builtin_amdgcn_mfma_f32_32x32x16_bf16(a3, b1, acc, 0, 0, 0);
        }
    }
    float* pb = part + (size_t)blockIdx.z * NTOT * 512;
    #pragma unroll
    for (int reg = 0; reg < 16; ++reg) {
        int nn = n0 + 32 * nq + (reg & 3) + 8 * (reg >> 2) + 4 * q;
        int mm = m0 + 32 * mq + l31;
        pb[(size_t)nn * 512 + mm] = acc[reg];
    }
}

__global__ __launch_bounds__(256) void fc1_reduce(const float* __restrict__ part,
                                                  const float* __restrict__ bias,
                                                  float* __restrict__ lat,
                                                  float* __restrict__ rep) {
    int idx = blockIdx.x * 256 + threadIdx.x;
    int m = idx & 511;
    float v = bias[m];
    #pragma unroll
    for (int kz = 0; kz < 7; ++kz) v += part[(size_t)kz * NTOT * 512 + idx];
    if (idx < BATCH * 512) lat[idx] = v;
    else rep[idx - BATCH * 512] = tanhf(v);
}

// ---------------- label = softmax(lat @ fcn_w.T + fcn_b) ----------------
__global__ __launch_bounds__(128) void fcn_softmax(const float* __restrict__ lat,
                                                   const float* __restrict__ fw,
                                                   const float* __restrict__ fb,
                                                   float* __restrict__ out) {
    const int b = blockIdx.x;
    const int j = threadIdx.x;
    __shared__ float lrow[512];
    __shared__ float red[128];
    for (int i = j; i < 512; i += 128) lrow[i] = lat[b * 512 + i];
    __syncthreads();
    const float4* w4 = (const float4*)(fw + j * 512);
    float acc = fb[j];
    #pragma unroll 4
    for (int qq = 0; qq < 128; ++qq) {
        float4 a = ((const float4*)lrow)[qq];
        float4 w = w4[qq];
        acc += a.x * w.x + a.y * w.y + a.z * w.z + a.w * w.w;
    }
    red[j] = acc;
    __syncthreads();
    for (int off = 64; off >= 1; off >>= 1) {
        if (j < off) red[j] = fmaxf(red[j], red[j + off]);
        __syncthreads();
    }
    float mx = red[0];
    __syncthreads();
    float ex = expf(acc - mx);
    red[j] = ex;
    __syncthreads();
    for (int off = 64; off >= 1; off >>= 1) {
        if (j < off) red[j] += red[j + off];
        __syncthreads();
    }
    out[b * 128 + j] = ex / red[0];
}

// ---------------- rho / t / w ----------------
__global__ __launch_bounds__(256) void rho_kernel(const float* __restrict__ rep,
                                                  float* __restrict__ rho) {
    __shared__ float red[256];
    const int tid = threadIdx.x;
    float s = 0.f;
    for (int i = tid; i < LABEL * LATENT; i += 256) s += rep[i];
    red[tid] = s;
    __syncthreads();
    for (int off = 128; off >= 1; off >>= 1) {
        if (tid < off) red[tid] += red[tid + off];
        __syncthreads();
    }
    if (tid == 0) rho[0] = red[0] / (float)(LABEL * LATENT);
}

__global__ __launch_bounds__(256) void t_kernel(const float* __restrict__ rep,
                                                const float* __restrict__ rho,
                                                float* __restrict__ tT) {
    int idx = blockIdx.x * 256 + threadIdx.x;
    int i = idx / 128, k = idx % 128;
    tT[idx] = rep[k * 512 + i] - rho[0];
}

__global__ __launch_bounds__(256) void w_kernel(const float* __restrict__ tT,
                                                float* __restrict__ w) {
    int idx = blockIdx.x * 256 + threadIdx.x;
    int i = idx >> 9, j = idx & 511;
    const float4* a = (const float4*)(tT + i * 128);
    const float4* b = (const float4*)(tT + j * 128);
    float acc = 0.f;
    #pragma unroll 8
    for (int q = 0; q < 32; ++q) {
        float4 av = a[q], bv = b[q];
        acc += av.x * bv.x + av.y * bv.y + av.z * bv.z + av.w * bv.w;
    }
    w[idx] = (i == j) ? 0.f : acc * (1.f / 128.f);
}

// ---------------- clustering (r6 proven): incremental Hopfield ----------------
#define CB 4
__device__ __forceinline__ float sgnf(float x) {
    return (x > 0.f) ? 1.f : ((x < 0.f) ? -1.f : 0.f);
}

__global__ __launch_bounds__(256) void clustering(const float* __restrict__ lat,
                                                  const float* __restrict__ w,
                                                  const float* __restrict__ rep,
                                                  float* __restrict__ out) {
    const int tid = threadIdx.x;
    const int row0 = blockIdx.x * CB;
    __shared__ float sbuf[CB][512];
    __shared__ float mins[CB][512];
    __shared__ float red[256];
    __shared__ float part_e[4][CB];
    __shared__ int part_c[4];
    __shared__ float min_e[CB];
    __shared__ int copyf[CB];
    __shared__ int donef[CB];
    __shared__ int cnt[CB];
    __shared__ int jidx[CB][512];
    __shared__ float jdel[CB][512];
    const int i0 = 2 * tid, i1 = 2 * tid + 1;
    const int wave = tid >> 6, lane = tid & 63;

    float sm10[CB], sm11[CB], sm20[CB], sm21[CB], h0[CB], h1[CB];
    #pragma unroll
    for (int r = 0; r < CB; ++r) {
        float a = tanhf(lat[(row0 + r) * 512 + i0]);
        float b = tanhf(lat[(row0 + r) * 512 + i1]);
        sm10[r] = a; sm11[r] = b;
        sm20[r] = a; sm21[r] = b;
        sbuf[r][i0] = a; sbuf[r][i1] = b;
        h0[r] = 0.f; h1[r] = 0.f;
    }
    if (tid < CB) { min_e[tid] = INFINITY; donef[tid] = 0; cnt[tid] = 0; }
    __syncthreads();

    #pragma unroll 4
    for (int j = 0; j < 512; ++j) {
        float2 wvv = *(const float2*)(w + (size_t)j * 512 + i0);
        #pragma unroll
        for (int r = 0; r < CB; ++r) {
            float sj = sbuf[r][j];
            h0[r] = fmaf(sj, wvv.x, h0[r]);
            h1[r] = fmaf(sj, wvv.y, h1[r]);
        }
    }

    for (int k = 1; k <= 512; ++k) {
        float sn0[CB], sn1[CB];
        int cy = 0xF;
        #pragma unroll
        for (int r = 0; r < CB; ++r) {
            int dn = donef[r];
            if (dn) {
                sn0[r] = sm10[r]; sn1[r] = sm11[r];
            } else {
                sn0[r] = fabsf(sm10[r]) * sgnf(h0[r]);
                sn1[r] = fabsf(sm11[r]) * sgnf(h1[r]);
                if (!(sn0[r] == sm20[r] && sn1[r] == sm21[r])) cy &= ~(1 << r);
                if (sn0[r] != sm10[r]) {
                    int p = atomicAdd(&cnt[r], 1);
                    jidx[r][p] = i0; jdel[r][p] = sn0[r] - sm10[r];
                }
                if (sn1[r] != sm11[r]) {
                    int p = atomicAdd(&cnt[r], 1);
                    jidx[r][p] = i1; jdel[r][p] = sn1[r] - sm11[r];
                }
            }
        }
        #pragma unroll
        for (int m = 32; m >= 1; m >>= 1) cy &= __shfl_xor(cy, m, 64);
        if (lane == 0) part_c[wave] = cy;
        __syncthreads();

        #pragma unroll
        for (int r = 0; r < CB; ++r) {
            const int c = cnt[r];
            for (int t = 0; t < c; ++t) {
                const int j = jidx[r][t];
                const float d = jdel[r][t];
                const float2 wvv = *(const float2*)(w + (size_t)j * 512 + i0);
                h0[r] = fmaf(d, wvv.x, h0[r]);
                h1[r] = fmaf(d, wvv.y, h1[r]);
            }
        }
        float ep[CB];
        #pragma unroll
        for (int r = 0; r < CB; ++r) ep[r] = sn0[r] * h0[r] + sn1[r] * h1[r];
        #pragma unroll
        for (int m = 32; m >= 1; m >>= 1) {
            #pragma unroll
            for (int r = 0; r < CB; ++r) ep[r] += __shfl_xor(ep[r], m, 64);
        }
        if (lane == 0) {
            #pragma unroll
            for (int r = 0; r < CB; ++r) part_e[wave][r] = ep[r];
        }
        __syncthreads();

        if (tid < CB) {
            int r = tid;
            if (!donef[r]) {
                float e = -(part_e[0][r] + part_e[1][r] + part_e[2][r] + part_e[3][r]);
                int better = e < min_e[r];
                if (better) min_e[r] = e;
                copyf[r] = better;
                int fl = part_c[0] & part_c[1] & part_c[2] & part_c[3];
                int fixedp = (cnt[r] == 0);
                int cyc = (k >= 2) && ((fl >> r) & 1);
                if (fixedp || cyc) donef[r] = 1;
            } else {
                copyf[r] = 0;
            }
            cnt[r] = 0;
        }
        __syncthreads();

        int alldone = 1;
        #pragma unroll
        for (int r = 0; r < CB; ++r) {
            if (copyf[r]) { mins[r][i0] = sn0[r]; mins[r][i1] = sn1[r]; }
            alldone &= donef[r];
            sm20[r] = sm10[r]; sm21[r] = sm11[r];
            sm10[r] = sn0[r];  sm11[r] = sn1[r];
        }
        if (alldone) break;
    }
    __syncthreads();

    const int j = tid & 127, half = tid >> 7;
    for (int r = 0; r < CB; ++r) {
        const float4* rr = (const float4*)(rep + (size_t)j * 512 + half * 256);
        const float4* ms = (const float4*)(&mins[r][half * 256]);
        float p = 0.f;
        #pragma unroll 8
        for (int q = 0; q < 64; ++q) {
            float4 rv = rr[q], mv = ms[q];
            p += rv.x * mv.x + rv.y * mv.y + rv.z * mv.z + rv.w * mv.w;
        }
        red[tid] = p;
        __syncthreads();
        float v = 0.f;
        if (tid < 128) { v = fabsf(red[tid] + red[tid + 128]); red[tid] = v; }
        __syncthreads();
        for (int off = 64; off >= 1; off >>= 1) {
            if (tid < off) red[tid] = fmaxf(red[tid], red[tid + off]);
            __syncthreads();
        }
        float mx = red[0];
        __syncthreads();
        float ex = 0.f;
        if (tid < 128) { ex = expf(v - mx); red[tid] = ex; }
        __syncthreads();
        for (int off = 64; off >= 1; off >>= 1) {
            if (tid < off) red[tid] += red[tid + off];
            __syncthreads();
        }
        if (tid < 128) out[(size_t)(row0 + r) * 128 + tid] = ex / red[0];
        __syncthreads();
    }
}

extern "C" void kernel_launch(void* const* d_in, const int* in_sizes, int n_in,
                              void* d_out, int out_size, void* d_ws, size_t ws_size,
                              hipStream_t stream) {
    const float* image = (const float*)d_in[0];
    const float* limg  = (const float*)d_in[1];
    const float* c1w   = (const float*)d_in[2];
    const float* c1b   = (const float*)d_in[3];
    const float* c2w   = (const float*)d_in[4];
    const float* c2b   = (const float*)d_in[5];
    const float* f1w   = (const float*)d_in[6];
    const float* f1b   = (const float*)d_in[7];
    const float* fnw   = (const float*)d_in[8];
    const float* fnb   = (const float*)d_in[9];
    float* out = (float*)d_out;
    float* ws  = (float*)d_ws;

    float* o1p  = ws;                               // 1152*11520 f32 = 53.1MB
    unsigned short* out3 = (unsigned short*)(o1p + (size_t)NTOT * 11520);  // 3*ASTR
    float* lat  = (float*)(out3 + 3 * ASTR);        // 1024*512
    float* rep  = lat + (size_t)BATCH * 512;        // 128*512
    float* tT   = rep + (size_t)LABEL * 512;        // 512*128
    float* wmat = tT + (size_t)512 * 128;           // 512*512
    float* rho  = wmat + (size_t)512 * 512;         // 1 (+pad)
    unsigned short* Bw3   = (unsigned short*)(rho + 16);   // 3*BSTR bf16
    unsigned short* Bfrag = Bw3 + 3 * BSTR;                // 153,600 bf16
    float* part = o1p;                              // alias: o1p dead after conv2

    hipLaunchKernelGGL(bprep, dim3(200), dim3(256), 0, stream, c2w, Bfrag);
    hipLaunchKernelGGL(wprep, dim3(6272), dim3(256), 0, stream, f1w, Bw3);
    hipLaunchKernelGGL(conv1_pool, dim3(NTOT), dim3(256), 0, stream, image, limg, c1w, c1b, o1p);
    hipLaunchKernelGGL(conv2_mfma, dim3(NTOT), dim3(256), 0, stream, o1p, Bfrag, c2b, out3);
    hipLaunchKernelGGL(fc1_mfma, dim3(NTOT / 64, 512 / 64, 7), dim3(256), 0, stream,
                       out3, Bw3, part);
    hipLaunchKernelGGL(fc1_reduce, dim3(NTOT * 512 / 256), dim3(256), 0, stream,
                       part, f1b, lat, rep);
    hipLaunchKernelGGL(fcn_softmax, dim3(BATCH), dim3(128), 0, stream, lat, fnw, fnb,
                       out + (size_t)BATCH * LABEL);
    hipLaunchKernelGGL(rho_kernel, dim3(1), dim3(256), 0, stream, rep, rho);
    hipLaunchKernelGGL(t_kernel, dim3(256), dim3(256), 0, stream, rep, rho, tT);
    hipLaunchKernelGGL(w_kernel, dim3(1024), dim3(256), 0, stream, tT, wmat);
    hipLaunchKernelGGL(clustering, dim3(BATCH / CB), dim3(256), 0, stream, lat, wmat, rep, out);
}

// Round 10
// 496.402 us; speedup vs baseline: 3.9364x; 1.0388x over previous
//
#include <hip/hip_runtime.h>
#include <hip/hip_bf16.h>
#include <math.h>

#define BATCH 1024
#define LABEL 128
#define LATENT 512
#define NTOT 1152  // 1024 + 128

typedef short short8 __attribute__((ext_vector_type(8)));
typedef float f32x16 __attribute__((ext_vector_type(16)));

__device__ __forceinline__ unsigned short f2bf(float f) {
    __hip_bfloat16 h = __float2bfloat16(f);
    return *(unsigned short*)&h;
}
__device__ __forceinline__ float bf2f(unsigned short u) {
    __hip_bfloat16 h; *(unsigned short*)&h = u;
    return __bfloat162float(h);
}

// conv1 output layout (per image): 3 bf16 planes of 6400 ushorts (12800B each).
// Plane = 196 compact pixels (14x14) x 32ch, granule = 64B, slot-swizzled:
// off = p*32 + (((oc>>3) ^ (p>>1)) & 3)*8 + (oc&7).  Granules 196..199 zeroed
// (conv2's OOB-redirect target).  Image stride = 19200 ushorts.

// ---------------- conv1 (1->32, 5x5 SAME) + relu + 2x2 maxpool ----------------
__global__ __launch_bounds__(256) void conv1_pool(const float* __restrict__ image,
                                                  const float* __restrict__ limg,
                                                  const float* __restrict__ wt,
                                                  const float* __restrict__ bias,
                                                  unsigned short* __restrict__ o1b) {
    const int n = blockIdx.x;
    const float* in = (n < BATCH) ? (image + (size_t)n * 784)
                                  : (limg + (size_t)(n - BATCH) * 784);
    __shared__ float pin[32][32];
    __shared__ float wts[32 * 25];
    const int tid = threadIdx.x;
    unsigned short* ob = o1b + (size_t)n * 19200;
    for (int i = tid; i < 384; i += 256) {            // zero spare granules
        int pl_ = i >> 7, r = i & 127;
        ob[pl_ * 6400 + 6272 + r] = 0;
    }
    for (int idx = tid; idx < 32 * 32; idx += 256) ((float*)pin)[idx] = 0.f;
    __syncthreads();
    for (int idx = tid; idx < 784; idx += 256) {
        int y = idx / 28, x = idx % 28;
        pin[y + 2][x + 2] = in[idx];
    }
    for (int idx = tid; idx < 800; idx += 256) wts[idx] = wt[idx];
    __syncthreads();
    const int oc = tid & 31;
    float wk[25];
    #pragma unroll
    for (int k = 0; k < 25; ++k) wk[k] = wts[oc * 25 + k];
    float b = bias[oc];
    const int slot_lo = (oc & 7);
    const int gq = oc >> 3;
    for (int o = tid; o < 6272; o += 256) {
        int p = o >> 5, py = p / 14, px = p % 14;
        float win[6][6];
        #pragma unroll
        for (int r = 0; r < 6; ++r)
        #pragma unroll
        for (int c = 0; c < 6; ++c)
            win[r][c] = pin[2 * py + r][2 * px + c];
        float a00 = b, a01 = b, a10 = b, a11 = b;
        #pragma unroll
        for (int ky = 0; ky < 5; ++ky)
        #pragma unroll
        for (int kx = 0; kx < 5; ++kx) {
            float w = wk[ky * 5 + kx];
            a00 = fmaf(win[ky][kx], w, a00);
            a01 = fmaf(win[ky][kx + 1], w, a01);
            a10 = fmaf(win[ky + 1][kx], w, a10);
            a11 = fmaf(win[ky + 1][kx + 1], w, a11);
        }
        float v = fmaxf(fmaxf(fmaxf(a00, a01), fmaxf(a10, a11)), 0.f);
        unsigned short b1 = f2bf(v); float r1 = v - bf2f(b1);
        unsigned short b2 = f2bf(r1);
        unsigned short b3 = f2bf(r1 - bf2f(b2));
        int off = p * 32 + (((gq ^ (p >> 1)) & 3) << 3) + slot_lo;
        ob[off] = b1; ob[6400 + off] = b2; ob[12800 + off] = b3;
    }
}

// ---------------- B fragment prep for conv2 (unchanged, r7 proven) ------------
__global__ __launch_bounds__(256) void bprep(const float* __restrict__ w,
                                             unsigned short* __restrict__ Bf) {
    int idx = blockIdx.x * 256 + threadIdx.x;   // 50*2*64*8 = 51200
    if (idx >= 51200) return;
    int j = idx & 7, lane = (idx >> 3) & 63, ocT = (idx >> 9) & 1, s = idx >> 10;
    int q = lane >> 5, nn = lane & 31;
    int k = 16 * s + 8 * q + j;
    int tap = k >> 5, ic = k & 31;
    int oc = 32 * ocT + nn;
    float v = w[oc * 800 + ic * 25 + tap];
    unsigned short b1 = f2bf(v);
    float r1 = v - bf2f(b1);
    unsigned short b2 = f2bf(r1);
    unsigned short b3 = f2bf(r1 - bf2f(b2));
    size_t base = ((size_t)(s * 2 + ocT) * 3) * 512 + lane * 8 + j;
    Bf[base] = b1; Bf[base + 512] = b2; Bf[base + 1024] = b3;
}

// ---------------- f1w prep: bf16x3 planes Bw3[pl][512][3136] ------------------
#define BSTR ((size_t)512 * 3136)
#define ASTR ((size_t)NTOT * 3136)
__global__ __launch_bounds__(256) void wprep(const float* __restrict__ w,
                                             unsigned short* __restrict__ B3) {
    int idx = blockIdx.x * 256 + threadIdx.x;   // 512*3136
    if (idx >= 512 * 3136) return;
    float v = w[idx];
    unsigned short b1 = f2bf(v);
    float r1 = v - bf2f(b1);
    unsigned short b2 = f2bf(r1);
    unsigned short b3 = f2bf(r1 - bf2f(b2));
    B3[idx] = b1; B3[BSTR + idx] = b2; B3[2 * BSTR + idx] = b3;
}

// ---------------- conv2 via MFMA (bf16x3), v4: compact planes -----------------
// Planes pre-split + pre-swizzled by conv1 -> staging is a linear 38.4KB copy.
// Compact 14x14 layout: cpt consecutive across lanes -> swizzle covers all 8
// bank-quads exactly (the r9 residual came from 20-wide row-wrap jumps).
// OOB taps redirect to zeroed granule 196.  LDS 38.4KB -> 4 blocks/CU.
__global__ __launch_bounds__(256) void conv2_mfma(const unsigned short* __restrict__ o1b,
                                                  const unsigned short* __restrict__ Bf,
                                                  const float* __restrict__ bias,
                                                  unsigned short* __restrict__ out3) {
    const int n = blockIdx.x;
    __shared__ __align__(16) unsigned short pl[19200];   // 38,400B
    const int tid = threadIdx.x;
    const int lane = tid & 63, wv = tid >> 6;
    const int ocT = wv & 1, kh = wv >> 1;

    // ---- stage: linear copy (planes already split + swizzled) ----
    {
        const float4* src = (const float4*)(o1b + (size_t)n * 19200);
        float4* dst = (float4*)pl;
        for (int i = tid; i < 2400; i += 256) dst[i] = src[i];
    }
    __syncthreads();

    const int m_ = lane & 31, q = lane >> 5;
    int ym[7], xm[7], mm[7];
    #pragma unroll
    for (int t = 0; t < 7; ++t) {
        int m = 32 * t + m_;
        mm[t] = m;
        ym[t] = m / 14;
        xm[t] = m - 14 * ym[t];
    }
    f32x16 acc[7];
    {
        float bs = (kh == 0) ? bias[32 * ocT + m_] : 0.f;
        #pragma unroll
        for (int t = 0; t < 7; ++t)
        #pragma unroll
        for (int r = 0; r < 16; ++r) acc[t][r] = bs;
    }

    for (int s = kh * 25; s < kh * 25 + 25; ++s) {
        const unsigned short* bp = Bf + ((size_t)(s * 2 + ocT) * 3) * 512 + lane * 8;
        short8 b1 = *(const short8*)(bp);
        short8 b2 = *(const short8*)(bp + 512);
        short8 b3 = *(const short8*)(bp + 1024);
        int kb = 16 * s + 8 * q;
        int tap = kb >> 5, ic0 = kb & 31, g = ic0 >> 3;
        int ky = (tap * 13) >> 6;       // exact /5 for tap<25
        int kx = tap - ky * 5;
        int iyk = ky - 2, ixk = kx - 2;
        int pq2 = iyk * 14 + ixk;
        short8 a1[7], a2[7], a3[7];
        #pragma unroll
        for (int t = 0; t < 7; ++t) {
            int iy = ym[t] + iyk, ix = xm[t] + ixk;
            int valid = ((unsigned)iy < 14u) & ((unsigned)ix < 14u);
            int cpt = valid ? (mm[t] + pq2) : 196;
            int addr = cpt * 32 + (((g ^ (cpt >> 1)) & 3) << 3);
            a1[t] = *(const short8*)(pl + addr);
            a2[t] = *(const short8*)(pl + 6400 + addr);
            a3[t] = *(const short8*)(pl + 12800 + addr);
        }
        #pragma unroll
        for (int t = 0; t < 7; ++t)
            acc[t] = __builtin_amdgcn_mfma_f32_32x32x16_bf16(a1[t], b1, acc[t], 0, 0, 0);
        #pragma unroll
        for (int t = 0; t < 7; ++t)
            acc[t] = __builtin_amdgcn_mfma_f32_32x32x16_bf16(a1[t], b2, acc[t], 0, 0, 0);
        #pragma unroll
        for (int t = 0; t < 7; ++t)
            acc[t] = __builtin_amdgcn_mfma_f32_32x32x16_bf16(a2[t], b1, acc[t], 0, 0, 0);
        #pragma unroll
        for (int t = 0; t < 7; ++t)
            acc[t] = __builtin_amdgcn_mfma_f32_32x32x16_bf16(a2[t], b2, acc[t], 0, 0, 0);
        #pragma unroll
        for (int t = 0; t < 7; ++t)
            acc[t] = __builtin_amdgcn_mfma_f32_32x32x16_bf16(a1[t], b3, acc[t], 0, 0, 0);
        #pragma unroll
        for (int t = 0; t < 7; ++t)
            acc[t] = __builtin_amdgcn_mfma_f32_32x32x16_bf16(a3[t], b1, acc[t], 0, 0, 0);
    }
    __syncthreads();   // planes dead

    // ---- merge K halves through LDS, 2 phases (fits 38.4KB) ----
    float* accbuf = (float*)pl;
    if (kh == 0) {     // phase 1: t 0..3  (32KB)
        #pragma unroll
        for (int t = 0; t < 4; ++t)
        #pragma unroll
        for (int r = 0; r < 16; ++r)
            accbuf[((ocT * 4 + t) * 16 + r) * 64 + lane] = acc[t][r];
    }
    __syncthreads();
    if (kh == 1) {
        #pragma unroll
        for (int t = 0; t < 4; ++t)
        #pragma unroll
        for (int r = 0; r < 16; ++r)
            acc[t][r] += accbuf[((ocT * 4 + t) * 16 + r) * 64 + lane];
    }
    __syncthreads();
    if (kh == 0) {     // phase 2: t 4..6  (24KB)
        #pragma unroll
        for (int t = 4; t < 7; ++t)
        #pragma unroll
        for (int r = 0; r < 16; ++r)
            accbuf[((ocT * 3 + (t - 4)) * 16 + r) * 64 + lane] = acc[t][r];
    }
    __syncthreads();
    if (kh == 1) {
        #pragma unroll
        for (int t = 4; t < 7; ++t)
        #pragma unroll
        for (int r = 0; r < 16; ++r)
            acc[t][r] += accbuf[((ocT * 3 + (t - 4)) * 16 + r) * 64 + lane];
    }
    __syncthreads();

    // ---- x-pool in-lane (kh=1 waves) -> hx[y][px][oc], stride 65 ----
    float* hx = (float*)pl;        // 25.5KB, aliases accbuf (post-sync)
    if (kh == 1) {
        const int oc = 32 * ocT + m_;
        #pragma unroll
        for (int t = 0; t < 7; ++t)
        #pragma unroll
        for (int e = 0; e < 8; ++e) {
            const int reg = 2 * e;
            const int r = (reg & 3) + 8 * (reg >> 2) + 4 * q;
            const int m = 32 * t + r;
            if (m < 196) {
                float xm2 = fmaxf(acc[t][reg], acc[t][reg + 1]);
                int y = (m * 2341) >> 15;        // /14
                int px = (m - 14 * y) >> 1;
                hx[(y * 7 + px) * 65 + oc] = xm2;
            }
        }
    }
    __syncthreads();

    // ---- y-pool + relu + bf16x3 store ----
    const size_t OSTR = ASTR;
    for (int idx = tid; idx < 3136; idx += 256) {
        int oc2 = (idx * 2675) >> 17;        // /49
        int p = idx - 49 * oc2;
        int py = (p * 9363) >> 16;           // /7
        int px = p - 7 * py;
        float v = fmaxf(hx[(2 * py * 7 + px) * 65 + oc2],
                        hx[((2 * py + 1) * 7 + px) * 65 + oc2]);
        v = fmaxf(v, 0.f);
        unsigned short b1 = f2bf(v);
        float r1 = v - bf2f(b1);
        unsigned short b2 = f2bf(r1);
        unsigned short b3 = f2bf(r1 - bf2f(b2));
        size_t o = (size_t)n * 3136 + idx;
        out3[o] = b1; out3[OSTR + o] = b2; out3[2 * OSTR + o] = b3;
    }
}

// ---------------- fc1 via MFMA (bf16x3, 6 products), split-K=7 ----------------
// Swizzle corrected per r9 bank math: slot depends on row>>1, not row&3.
__global__ __launch_bounds__(256) void fc1_mfma(const unsigned short* __restrict__ A3,
                                                const unsigned short* __restrict__ B3,
                                                float* __restrict__ part) {
    __shared__ unsigned short As[3][2048];
    __shared__ unsigned short Bs[3][2048];
    const int tid = threadIdx.x;
    const int n0 = blockIdx.x * 64, m0 = blockIdx.y * 64;
    const int koff = blockIdx.z * 448;
    const int lr = tid >> 2, g = tid & 3;
    const int slot = (((g ^ (lr >> 1)) & 3) << 3);
    const int lane = tid & 63, wv = tid >> 6;
    const int nq = wv & 1, mq = wv >> 1;
    const int q = lane >> 5, l31 = lane & 31;
    const int rA = 32 * nq + l31, rB = 32 * mq + l31;
    f32x16 acc;
    #pragma unroll
    for (int r = 0; r < 16; ++r) acc[r] = 0.f;

    for (int bk = 0; bk < 448; bk += 32) {
        const size_t ka = (size_t)(koff + bk + (g << 3));
        short8 av[3], bv[3];
        #pragma unroll
        for (int p = 0; p < 3; ++p) {
            av[p] = *(const short8*)(A3 + p * ASTR + (size_t)(n0 + lr) * 3136 + ka);
            bv[p] = *(const short8*)(B3 + p * BSTR + (size_t)(m0 + lr) * 3136 + ka);
        }
        __syncthreads();
        #pragma unroll
        for (int p = 0; p < 3; ++p) {
            *(short8*)&As[p][(lr << 5) + slot] = av[p];
            *(short8*)&Bs[p][(lr << 5) + slot] = bv[p];
        }
        __syncthreads();
        #pragma unroll
        for (int s2 = 0; s2 < 32; s2 += 16) {
            const int gg = (s2 + (q << 3)) >> 3;
            const int sa = (((gg ^ (rA >> 1)) & 3) << 3);
            const int sb = (((gg ^ (rB >> 1)) & 3) << 3);
            short8 a1 = *(const short8*)&As[0][(rA << 5) + sa];
            short8 a2 = *(const short8*)&As[1][(rA << 5) + sa];
            short8 a3 = *(const short8*)&As[2][(rA << 5) + sa];
            short8 b1 = *(const short8*)&Bs[0][(rB << 5) + sb];
            short8 b2 = *(const short8*)&Bs[1][(rB << 5) + sb];
            short8 b3 = *(const short8*)&Bs[2][(rB << 5) + sb];
            acc = __builtin_amdgcn_mfma_f32_32x32x16_bf16(a1, b1, acc, 0, 0, 0);
            acc = __builtin_amdgcn_mfma_f32_32x32x16_bf16(a1, b2, acc, 0, 0, 0);
            acc = __builtin_amdgcn_mfma_f32_32x32x16_bf16(a2, b1, acc, 0, 0, 0);
            acc = __builtin_amdgcn_mfma_f32_32x32x16_bf16(a2, b2, acc, 0, 0, 0);
            acc = __builtin_amdgcn_mfma_f32_32x32x16_bf16(a1, b3, acc, 0, 0, 0);
            acc = __builtin_amdgcn_mfma_f32_32x32x16_bf16(a3, b1, acc, 0, 0, 0);
        }
    }
    float* pb = part + (size_t)blockIdx.z * NTOT * 512;
    #pragma unroll
    for (int reg = 0; reg < 16; ++reg) {
        int nn = n0 + 32 * nq + (reg & 3) + 8 * (reg >> 2) + 4 * q;
        int mmo = m0 + 32 * mq + l31;
        pb[(size_t)nn * 512 + mmo] = acc[reg];
    }
}

__global__ __launch_bounds__(256) void fc1_reduce(const float* __restrict__ part,
                                                  const float* __restrict__ bias,
                                                  float* __restrict__ lat,
                                                  float* __restrict__ rep) {
    int idx = blockIdx.x * 256 + threadIdx.x;
    int m = idx & 511;
    float v = bias[m];
    #pragma unroll
    for (int kz = 0; kz < 7; ++kz) v += part[(size_t)kz * NTOT * 512 + idx];
    if (idx < BATCH * 512) lat[idx] = v;
    else rep[idx - BATCH * 512] = tanhf(v);
}

// ---------------- label = softmax(lat @ fcn_w.T + fcn_b) ----------------
__global__ __launch_bounds__(128) void fcn_softmax(const float* __restrict__ lat,
                                                   const float* __restrict__ fw,
                                                   const float* __restrict__ fb,
                                                   float* __restrict__ out) {
    const int b = blockIdx.x;
    const int j = threadIdx.x;
    __shared__ float lrow[512];
    __shared__ float red[128];
    for (int i = j; i < 512; i += 128) lrow[i] = lat[b * 512 + i];
    __syncthreads();
    const float4* w4 = (const float4*)(fw + j * 512);
    float acc = fb[j];
    #pragma unroll 4
    for (int qq = 0; qq < 128; ++qq) {
        float4 a = ((const float4*)lrow)[qq];
        float4 w = w4[qq];
        acc += a.x * w.x + a.y * w.y + a.z * w.z + a.w * w.w;
    }
    red[j] = acc;
    __syncthreads();
    for (int off = 64; off >= 1; off >>= 1) {
        if (j < off) red[j] = fmaxf(red[j], red[j + off]);
        __syncthreads();
    }
    float mx = red[0];
    __syncthreads();
    float ex = expf(acc - mx);
    red[j] = ex;
    __syncthreads();
    for (int off = 64; off >= 1; off >>= 1) {
        if (j < off) red[j] += red[j + off];
        __syncthreads();
    }
    out[b * 128 + j] = ex / red[0];
}

// ---------------- rho / t / w ----------------
__global__ __launch_bounds__(256) void rho_kernel(const float* __restrict__ rep,
                                                  float* __restrict__ rho) {
    __shared__ float red[256];
    const int tid = threadIdx.x;
    float s = 0.f;
    for (int i = tid; i < LABEL * LATENT; i += 256) s += rep[i];
    red[tid] = s;
    __syncthreads();
    for (int off = 128; off >= 1; off >>= 1) {
        if (tid < off) red[tid] += red[tid + off];
        __syncthreads();
    }
    if (tid == 0) rho[0] = red[0] / (float)(LABEL * LATENT);
}

__global__ __launch_bounds__(256) void t_kernel(const float* __restrict__ rep,
                                                const float* __restrict__ rho,
                                                float* __restrict__ tT) {
    int idx = blockIdx.x * 256 + threadIdx.x;
    int i = idx / 128, k = idx % 128;
    tT[idx] = rep[k * 512 + i] - rho[0];
}

__global__ __launch_bounds__(256) void w_kernel(const float* __restrict__ tT,
                                                float* __restrict__ w) {
    int idx = blockIdx.x * 256 + threadIdx.x;
    int i = idx >> 9, j = idx & 511;
    const float4* a = (const float4*)(tT + i * 128);
    const float4* b = (const float4*)(tT + j * 128);
    float acc = 0.f;
    #pragma unroll 8
    for (int q = 0; q < 32; ++q) {
        float4 av = a[q], bv = b[q];
        acc += av.x * bv.x + av.y * bv.y + av.z * bv.z + av.w * bv.w;
    }
    w[idx] = (i == j) ? 0.f : acc * (1.f / 128.f);
}

// ---------------- clustering (r6 proven): incremental Hopfield ----------------
#define CB 4
__device__ __forceinline__ float sgnf(float x) {
    return (x > 0.f) ? 1.f : ((x < 0.f) ? -1.f : 0.f);
}

__global__ __launch_bounds__(256) void clustering(const float* __restrict__ lat,
                                                  const float* __restrict__ w,
                                                  const float* __restrict__ rep,
                                                  float* __restrict__ out) {
    const int tid = threadIdx.x;
    const int row0 = blockIdx.x * CB;
    __shared__ float sbuf[CB][512];
    __shared__ float mins[CB][512];
    __shared__ float red[256];
    __shared__ float part_e[4][CB];
    __shared__ int part_c[4];
    __shared__ float min_e[CB];
    __shared__ int copyf[CB];
    __shared__ int donef[CB];
    __shared__ int cnt[CB];
    __shared__ int jidx[CB][512];
    __shared__ float jdel[CB][512];
    const int i0 = 2 * tid, i1 = 2 * tid + 1;
    const int wave = tid >> 6, lane = tid & 63;

    float sm10[CB], sm11[CB], sm20[CB], sm21[CB], h0[CB], h1[CB];
    #pragma unroll
    for (int r = 0; r < CB; ++r) {
        float a = tanhf(lat[(row0 + r) * 512 + i0]);
        float b = tanhf(lat[(row0 + r) * 512 + i1]);
        sm10[r] = a; sm11[r] = b;
        sm20[r] = a; sm21[r] = b;
        sbuf[r][i0] = a; sbuf[r][i1] = b;
        h0[r] = 0.f; h1[r] = 0.f;
    }
    if (tid < CB) { min_e[tid] = INFINITY; donef[tid] = 0; cnt[tid] = 0; }
    __syncthreads();

    #pragma unroll 4
    for (int j = 0; j < 512; ++j) {
        float2 wvv = *(const float2*)(w + (size_t)j * 512 + i0);
        #pragma unroll
        for (int r = 0; r < CB; ++r) {
            float sj = sbuf[r][j];
            h0[r] = fmaf(sj, wvv.x, h0[r]);
            h1[r] = fmaf(sj, wvv.y, h1[r]);
        }
    }

    for (int k = 1; k <= 512; ++k) {
        float sn0[CB], sn1[CB];
        int cy = 0xF;
        #pragma unroll
        for (int r = 0; r < CB; ++r) {
            int dn = donef[r];
            if (dn) {
                sn0[r] = sm10[r]; sn1[r] = sm11[r];
            } else {
                sn0[r] = fabsf(sm10[r]) * sgnf(h0[r]);
                sn1[r] = fabsf(sm11[r]) * sgnf(h1[r]);
                if (!(sn0[r] == sm20[r] && sn1[r] == sm21[r])) cy &= ~(1 << r);
                if (sn0[r] != sm10[r]) {
                    int p = atomicAdd(&cnt[r], 1);
                    jidx[r][p] = i0; jdel[r][p] = sn0[r] - sm10[r];
                }
                if (sn1[r] != sm11[r]) {
                    int p = atomicAdd(&cnt[r], 1);
                    jidx[r][p] = i1; jdel[r][p] = sn1[r] - sm11[r];
                }
            }
        }
        #pragma unroll
        for (int m = 32; m >= 1; m >>= 1) cy &= __shfl_xor(cy, m, 64);
        if (lane == 0) part_c[wave] = cy;
        __syncthreads();

        #pragma unroll
        for (int r = 0; r < CB; ++r) {
            const int c = cnt[r];
            for (int t = 0; t < c; ++t) {
                const int j = jidx[r][t];
                const float d = jdel[r][t];
                const float2 wvv = *(const float2*)(w + (size_t)j * 512 + i0);
                h0[r] = fmaf(d, wvv.x, h0[r]);
                h1[r] = fmaf(d, wvv.y, h1[r]);
            }
        }
        float ep[CB];
        #pragma unroll
        for (int r = 0; r < CB; ++r) ep[r] = sn0[r] * h0[r] + sn1[r] * h1[r];
        #pragma unroll
        for (int m = 32; m >= 1; m >>= 1) {
            #pragma unroll
            for (int r = 0; r < CB; ++r) ep[r] += __shfl_xor(ep[r], m, 64);
        }
        if (lane == 0) {
            #pragma unroll
            for (int r = 0; r < CB; ++r) part_e[wave][r] = ep[r];
        }
        __syncthreads();

        if (tid < CB) {
            int r = tid;
            if (!donef[r]) {
                float e = -(part_e[0][r] + part_e[1][r] + part_e[2][r] + part_e[3][r]);
                int better = e < min_e[r];
                if (better) min_e[r] = e;
                copyf[r] = better;
                int fl = part_c[0] & part_c[1] & part_c[2] & part_c[3];
                int fixedp = (cnt[r] == 0);
                int cyc = (k >= 2) && ((fl >> r) & 1);
                if (fixedp || cyc) donef[r] = 1;
            } else {
                copyf[r] = 0;
            }
            cnt[r] = 0;
        }
        __syncthreads();

        int alldone = 1;
        #pragma unroll
        for (int r = 0; r < CB; ++r) {
            if (copyf[r]) { mins[r][i0] = sn0[r]; mins[r][i1] = sn1[r]; }
            alldone &= donef[r];
            sm20[r] = sm10[r]; sm21[r] = sm11[r];
            sm10[r] = sn0[r];  sm11[r] = sn1[r];
        }
        if (alldone) break;
    }
    __syncthreads();

    const int j = tid & 127, half = tid >> 7;
    for (int r = 0; r < CB; ++r) {
        const float4* rr = (const float4*)(rep + (size_t)j * 512 + half * 256);
        const float4* ms = (const float4*)(&mins[r][half * 256]);
        float p = 0.f;
        #pragma unroll 8
        for (int q = 0; q < 64; ++q) {
            float4 rv = rr[q], mv = ms[q];
            p += rv.x * mv.x + rv.y * mv.y + rv.z * mv.z + rv.w * mv.w;
        }
        red[tid] = p;
        __syncthreads();
        float v = 0.f;
        if (tid < 128) { v = fabsf(red[tid] + red[tid + 128]); red[tid] = v; }
        __syncthreads();
        for (int off = 64; off >= 1; off >>= 1) {
            if (tid < off) red[tid] = fmaxf(red[tid], red[tid + off]);
            __syncthreads();
        }
        float mx = red[0];
        __syncthreads();
        float ex = 0.f;
        if (tid < 128) { ex = expf(v - mx); red[tid] = ex; }
        __syncthreads();
        for (int off = 64; off >= 1; off >>= 1) {
            if (tid < off) red[tid] += red[tid + off];
            __syncthreads();
        }
        if (tid < 128) out[(size_t)(row0 + r) * 128 + tid] = ex / red[0];
        __syncthreads();
    }
}

extern "C" void kernel_launch(void* const* d_in, const int* in_sizes, int n_in,
                              void* d_out, int out_size, void* d_ws, size_t ws_size,
                              hipStream_t stream) {
    const float* image = (const float*)d_in[0];
    const float* limg  = (const float*)d_in[1];
    const float* c1w   = (const float*)d_in[2];
    const float* c1b   = (const float*)d_in[3];
    const float* c2w   = (const float*)d_in[4];
    const float* c2b   = (const float*)d_in[5];
    const float* f1w   = (const float*)d_in[6];
    const float* f1b   = (const float*)d_in[7];
    const float* fnw   = (const float*)d_in[8];
    const float* fnb   = (const float*)d_in[9];
    float* out = (float*)d_out;
    float* ws  = (float*)d_ws;

    unsigned short* o1b  = (unsigned short*)ws;        // 1152*19200 us = 44.2MB
    unsigned short* out3 = o1b + (size_t)NTOT * 19200; // 3*ASTR bf16
    float* lat  = (float*)(out3 + 3 * ASTR);           // 1024*512
    float* rep  = lat + (size_t)BATCH * 512;           // 128*512
    float* tT   = rep + (size_t)LABEL * 512;           // 512*128
    float* wmat = tT + (size_t)512 * 128;              // 512*512
    float* rho  = wmat + (size_t)512 * 512;            // 1 (+pad)
    unsigned short* Bw3   = (unsigned short*)(rho + 16);   // 3*BSTR bf16
    unsigned short* Bfrag = Bw3 + 3 * BSTR;                // 153,600 bf16
    float* part = (float*)ws;                          // alias o1b (dead after conv2)

    hipLaunchKernelGGL(bprep, dim3(200), dim3(256), 0, stream, c2w, Bfrag);
    hipLaunchKernelGGL(wprep, dim3(6272), dim3(256), 0, stream, f1w, Bw3);
    hipLaunchKernelGGL(conv1_pool, dim3(NTOT), dim3(256), 0, stream, image, limg, c1w, c1b, o1b);
    hipLaunchKernelGGL(conv2_mfma, dim3(NTOT), dim3(256), 0, stream, o1b, Bfrag, c2b, out3);
    hipLaunchKernelGGL(fc1_mfma, dim3(NTOT / 64, 512 / 64, 7), dim3(256), 0, stream,
                       out3, Bw3, part);
    hipLaunchKernelGGL(fc1_reduce, dim3(NTOT * 512 / 256), dim3(256), 0, stream,
                       part, f1b, lat, rep);
    hipLaunchKernelGGL(fcn_softmax, dim3(BATCH), dim3(128), 0, stream, lat, fnw, fnb,
                       out + (size_t)BATCH * LABEL);
    hipLaunchKernelGGL(rho_kernel, dim3(1), dim3(256), 0, stream, rep, rho);
    hipLaunchKernelGGL(t_kernel, dim3(256), dim3(256), 0, stream, rep, rho, tT);
    hipLaunchKernelGGL(w_kernel, dim3(1024), dim3(256), 0, stream, tT, wmat);
    hipLaunchKernelGGL(clustering, dim3(BATCH / CB), dim3(256), 0, stream, lat, wmat, rep, out);
}